// Round 1
// baseline (1020.421 us; speedup 1.0000x reference)
//
#include <hip/hip_runtime.h>

#define N_NODES 50000
#define F_IN 32
#define F_HID 16

// ---------------- utility ----------------
__global__ void k_zero(float* __restrict__ p, int n) {
    int i = blockIdx.x * blockDim.x + threadIdx.x;
    if (i < n) p[i] = 0.0f;
}

// deg counting: one thread per edge, float atomics (exact up to 2^24)
__global__ void k_deg(const int* __restrict__ src, const int* __restrict__ dst, int E,
                      float* __restrict__ deg_out, float* __restrict__ deg_in) {
    int i = blockIdx.x * blockDim.x + threadIdx.x;
    if (i < E) {
        atomicAdd(&deg_out[src[i]], 1.0f);
        atomicAdd(&deg_in[dst[i]], 1.0f);
    }
}

__global__ void k_rsqrt(float* __restrict__ p, int n) {
    int i = blockIdx.x * blockDim.x + threadIdx.x;
    if (i < n) p[i] = rsqrtf(fmaxf(p[i], 1.0f));
}

// h[n][j] = (sum_k x[n][k] * W[k][j]) * inv_out[n]   (16 nodes / 256-thread block)
__global__ void k_h1(const float* __restrict__ x, const float* __restrict__ inv_out,
                     const float* __restrict__ W, float* __restrict__ h) {
    __shared__ float sW[F_IN * F_HID];
    __shared__ float sx[16][F_IN];
    int t = threadIdx.x;
    for (int i = t; i < F_IN * F_HID; i += 256) sW[i] = W[i];
    int n0 = blockIdx.x * 16;
    for (int i = t; i < 16 * F_IN; i += 256) {
        int nn = i >> 5, kk = i & 31;
        int n = n0 + nn;
        sx[nn][kk] = (n < N_NODES) ? x[n * F_IN + kk] : 0.0f;
    }
    __syncthreads();
    int nn = t >> 4, j = t & 15;
    int n = n0 + nn;
    if (n < N_NODES) {
        float s = 0.0f;
#pragma unroll
        for (int k = 0; k < F_IN; k++) s += sx[nn][k] * sW[k * F_HID + j];
        h[n * F_HID + j] = s * inv_out[n];
    }
}

// agg[dst][j] += h[src][j] * inv_in[dst]   — thread per (edge, feature)
__global__ void k_agg1(const int* __restrict__ src, const int* __restrict__ dst, int E,
                       const float* __restrict__ h, const float* __restrict__ inv_in,
                       float* __restrict__ agg) {
    int idx = blockIdx.x * blockDim.x + threadIdx.x;
    int total = E * F_HID;
    if (idx < total) {
        int e = idx >> 4, j = idx & 15;
        int s = src[e], d = dst[e];
        float v = h[s * F_HID + j] * inv_in[d];
        atomicAdd(&agg[d * F_HID + j], v);
    }
}

// in-place: agg = relu(agg + sum_r b1[r])
__global__ void k_relu_bias(float* __restrict__ agg, const float* __restrict__ b1) {
    int i = blockIdx.x * blockDim.x + threadIdx.x;
    if (i < N_NODES * F_HID) {
        int j = i & 15;
        float b = b1[j] + b1[F_HID + j] + b1[2 * F_HID + j];
        agg[i] = fmaxf(agg[i] + b, 0.0f);
    }
}

// out[n] = sum_r b2[r]  (accumulation base)
__global__ void k_out_init(float* __restrict__ out, const float* __restrict__ b2) {
    int i = blockIdx.x * blockDim.x + threadIdx.x;
    if (i < N_NODES) out[i] = b2[0] + b2[1] + b2[2];
}

// hs[n] = dot(h1[n], W2r) * inv_out[n]
__global__ void k_h2(const float* __restrict__ h1, const float* __restrict__ inv_out,
                     const float* __restrict__ W2r, float* __restrict__ hs) {
    int n = blockIdx.x * blockDim.x + threadIdx.x;
    if (n < N_NODES) {
        const float4* hp = reinterpret_cast<const float4*>(h1 + (size_t)n * F_HID);
        float s = 0.0f;
#pragma unroll
        for (int q = 0; q < 4; q++) {
            float4 hv = hp[q];
            s += hv.x * W2r[q * 4 + 0] + hv.y * W2r[q * 4 + 1] +
                 hv.z * W2r[q * 4 + 2] + hv.w * W2r[q * 4 + 3];
        }
        hs[n] = s * inv_out[n];
    }
}

// out[dst] += hs[src] * inv_in[dst]  — thread per edge
__global__ void k_agg2(const int* __restrict__ src, const int* __restrict__ dst, int E,
                       const float* __restrict__ hs, const float* __restrict__ inv_in,
                       float* __restrict__ out) {
    int e = blockIdx.x * blockDim.x + threadIdx.x;
    if (e < E) {
        int s = src[e], d = dst[e];
        atomicAdd(&out[d], hs[s] * inv_in[d]);
    }
}

extern "C" void kernel_launch(void* const* d_in, const int* in_sizes, int n_in,
                              void* d_out, int out_size, void* d_ws, size_t ws_size,
                              hipStream_t stream) {
    const float* x  = (const float*)d_in[0];
    const int* src[3] = { (const int*)d_in[1], (const int*)d_in[3], (const int*)d_in[5] };
    const int* dst[3] = { (const int*)d_in[2], (const int*)d_in[4], (const int*)d_in[6] };
    const int  E[3]   = { in_sizes[1], in_sizes[3], in_sizes[5] };
    const float* W1 = (const float*)d_in[7];   // [3][32][16]
    const float* b1 = (const float*)d_in[8];   // [3][16]
    const float* W2 = (const float*)d_in[9];   // [3][16][1]
    const float* b2 = (const float*)d_in[10];  // [3]
    float* out = (float*)d_out;

    const int N = N_NODES;
    float* ws = (float*)d_ws;
    // layout (floats): invOut[3][N] @0, invIn[3][N] @3N, h @6N (16N), agg @22N (16N), hs @38N (N)
    float* invOut = ws;
    float* invIn  = ws + 3 * (size_t)N;
    float* h      = ws + 6 * (size_t)N;
    float* agg    = ws + 22 * (size_t)N;
    float* hs     = ws + 38 * (size_t)N;

    const int B = 256;
    // zero degree region (6N) and agg (16N)
    k_zero<<<(6 * N + B - 1) / B, B, 0, stream>>>(invOut, 6 * N);
    k_zero<<<(16 * N + B - 1) / B, B, 0, stream>>>(agg, 16 * N);

    // degrees per relation
    for (int r = 0; r < 3; r++)
        k_deg<<<(E[r] + B - 1) / B, B, 0, stream>>>(src[r], dst[r], E[r],
                                                    invOut + (size_t)r * N, invIn + (size_t)r * N);
    k_rsqrt<<<(6 * N + B - 1) / B, B, 0, stream>>>(invOut, 6 * N);

    // layer 1: per relation, project then scatter (scaled by inv_in[dst])
    for (int r = 0; r < 3; r++) {
        k_h1<<<(N + 15) / 16, B, 0, stream>>>(x, invOut + (size_t)r * N,
                                              W1 + (size_t)r * F_IN * F_HID, h);
        int total = E[r] * F_HID;
        k_agg1<<<(total + B - 1) / B, B, 0, stream>>>(src[r], dst[r], E[r], h,
                                                     invIn + (size_t)r * N, agg);
    }
    k_relu_bias<<<(N * F_HID + B - 1) / B, B, 0, stream>>>(agg, b1);

    // layer 2: out initialized to summed bias, then scalar scatter per relation
    k_out_init<<<(N + B - 1) / B, B, 0, stream>>>(out, b2);
    for (int r = 0; r < 3; r++) {
        k_h2<<<(N + B - 1) / B, B, 0, stream>>>(agg, invOut + (size_t)r * N,
                                                W2 + (size_t)r * F_HID, hs);
        k_agg2<<<(E[r] + B - 1) / B, B, 0, stream>>>(src[r], dst[r], E[r], hs,
                                                    invIn + (size_t)r * N, out);
    }
}

// Round 2
// 927.142 us; speedup vs baseline: 1.1006x; 1.1006x over previous
//
#include <hip/hip_runtime.h>

#define N_NODES 50000
#define FH 16
#define NBUK 98          // buckets of 512 nodes: bucket = dst >> 9
#define BSHIFT 9
#define NCH 16           // histogram chunks
#define NPASS 4          // histogram node-range passes
#define HRANGE 12500     // 4 * 12500 = 50000
#define TILE 4096        // passB reorder tile

// ---- ws layout (u32 words) ----
#define OFF_INVOUT   0u
#define OFF_INVIN    150000u
#define OFF_RAWIN    300000u
#define OFF_BSTART   450000u      // [3][128], entries 0..98 used
#define OFF_GCUR     450384u
#define OFF_HS       450768u      // [3][N]
#define OFF_HPROJ    600768u      // [3][N][16]
#define OFF_HISTP    3000768u     // [6][16][N]  (aliased with aggP — hist dead before aggP written)
#define OFF_AGGP     3000768u     // [6][N][16]
#define OFF_HOUT     7800768u     // [N][16]
#define OFF_PAIRS    8600768u     // 4.2M packed edges
#define OFF_OUTP     12800768u    // [6][N]
#define WS_WORDS     13100768u

// =============== new path kernels ===============

// 6 histograms (3 src -> deg_out, 3 dst -> deg_in), non-atomic partials.
__global__ __launch_bounds__(256) void k_hist(
    const int* p0, const int* p1, const int* p2,
    const int* p3, const int* p4, const int* p5,
    int E0, int E1, int E2, int E3, int E4, int E5,
    unsigned* __restrict__ histP) {
    __shared__ unsigned bins[HRANGE];
    int c = blockIdx.x, p = blockIdx.y, a = blockIdx.z;
    const int* arr = (a == 0) ? p0 : (a == 1) ? p1 : (a == 2) ? p2 : (a == 3) ? p3 : (a == 4) ? p4 : p5;
    int E = (a == 0) ? E0 : (a == 1) ? E1 : (a == 2) ? E2 : (a == 3) ? E3 : (a == 4) ? E4 : E5;
    for (int i = threadIdx.x; i < HRANGE; i += 256) bins[i] = 0u;
    __syncthreads();
    int lo = p * HRANGE;
    int chunk = (E + NCH - 1) / NCH;
    int s0 = c * chunk, s1 = min(s0 + chunk, E);
    for (int i = s0 + threadIdx.x; i < s1; i += 256) {
        unsigned v = (unsigned)(arr[i] - lo);
        if (v < (unsigned)HRANGE) atomicAdd(&bins[v], 1u);
    }
    __syncthreads();
    unsigned* out = histP + ((size_t)a * NCH + c) * N_NODES + lo;
    for (int i = threadIdx.x; i < HRANGE; i += 256) out[i] = bins[i];
}

__global__ void k_degreduce(const unsigned* __restrict__ histP, float* __restrict__ invOut,
                            float* __restrict__ invIn, unsigned* __restrict__ rawIn) {
    int n = blockIdx.x * 256 + threadIdx.x;
    int a = blockIdx.y;
    if (n >= N_NODES) return;
    const unsigned* p = histP + (size_t)a * NCH * N_NODES + n;
    unsigned s = 0;
#pragma unroll
    for (int c = 0; c < NCH; c++) s += p[(size_t)c * N_NODES];
    float inv = rsqrtf((float)(s ? s : 1u));
    if (a < 3) invOut[a * N_NODES + n] = inv;
    else { invIn[(a - 3) * N_NODES + n] = inv; rawIn[(a - 3) * N_NODES + n] = s; }
}

// per relation: bucket totals -> exclusive scan -> bstart (kept) + gcur (mutable cursors)
__global__ __launch_bounds__(256) void k_bucketScan(const unsigned* __restrict__ rawIn,
                                                    unsigned* __restrict__ bstart,
                                                    unsigned* __restrict__ gcur) {
    __shared__ unsigned tot[NBUK + 1];
    int r = blockIdx.x;
    const unsigned* raw = rawIn + (size_t)r * N_NODES;
    int wave = threadIdx.x >> 6, lane = threadIdx.x & 63;
    for (int b = wave; b < NBUK; b += 4) {
        unsigned s = 0;
        int base = b << BSHIFT;
#pragma unroll
        for (int k = 0; k < 8; k++) {
            int n = base + (k << 6) + lane;
            if (n < N_NODES) s += raw[n];
        }
#pragma unroll
        for (int o = 32; o; o >>= 1) s += __shfl_down(s, o);
        if (lane == 0) tot[b] = s;
    }
    __syncthreads();
    if (threadIdx.x == 0) {
        unsigned acc = 0;
        for (int b = 0; b < NBUK; b++) { unsigned t = tot[b]; tot[b] = acc; acc += t; }
        tot[NBUK] = acc;
    }
    __syncthreads();
    for (int i = threadIdx.x; i <= NBUK; i += 256) {
        bstart[r * 128 + i] = tot[i];
        gcur[r * 128 + i] = tot[i];
    }
}

// bucket-scatter with in-LDS tile reorder for coalesced writes. pair = (dst<<16)|src.
__global__ __launch_bounds__(256) void k_passB(
    const int* s0p, const int* s1p, const int* s2p,
    const int* d0p, const int* d1p, const int* d2p,
    int E0, int E1, int E2, int po0, int po1, int po2,
    unsigned* __restrict__ pairsAll, unsigned* __restrict__ gcurAll) {
    __shared__ unsigned cnt[NBUK];
    __shared__ unsigned off[NBUK];
    __shared__ unsigned gbase[NBUK];
    __shared__ unsigned spair[TILE];
    __shared__ unsigned saddr[TILE];
    int r = blockIdx.z;
    const int* src = (r == 0) ? s0p : (r == 1) ? s1p : s2p;
    const int* dst = (r == 0) ? d0p : (r == 1) ? d1p : d2p;
    int E = (r == 0) ? E0 : (r == 1) ? E1 : E2;
    unsigned* pairs = pairsAll + ((r == 0) ? po0 : (r == 1) ? po1 : po2);
    unsigned* gcur = gcurAll + r * 128;
    int nb = gridDim.x;
    int chunk = (E + nb - 1) / nb;
    int c0 = blockIdx.x * chunk;
    int c1 = min(c0 + chunk, E);
    for (int t0 = c0; t0 < c1; t0 += TILE) {
        int tn = min(TILE, c1 - t0);
        for (int i = threadIdx.x; i < NBUK; i += 256) cnt[i] = 0u;
        __syncthreads();
        unsigned pk[16], bk[16], sl[16];
#pragma unroll
        for (int k = 0; k < 16; k++) {
            int ii = k * 256 + (int)threadIdx.x;
            bk[k] = 0xFFFFFFFFu;
            if (ii < tn) {
                int i = t0 + ii;
                unsigned s = (unsigned)src[i], d = (unsigned)dst[i];
                pk[k] = (d << 16) | s;
                unsigned b = d >> BSHIFT;
                bk[k] = b;
                sl[k] = atomicAdd(&cnt[b], 1u);
            }
        }
        __syncthreads();
        if (threadIdx.x == 0) {
            unsigned acc = 0;
            for (int b = 0; b < NBUK; b++) { unsigned t = cnt[b]; off[b] = acc; acc += t; }
        }
        __syncthreads();
        if (threadIdx.x < NBUK) {
            unsigned c = cnt[threadIdx.x];
            if (c) gbase[threadIdx.x] = atomicAdd(&gcur[threadIdx.x], c);
        }
        __syncthreads();
#pragma unroll
        for (int k = 0; k < 16; k++) {
            if (bk[k] != 0xFFFFFFFFu) {
                unsigned idx = off[bk[k]] + sl[k];
                spair[idx] = pk[k];
                saddr[idx] = gbase[bk[k]] + sl[k];
            }
        }
        __syncthreads();
#pragma unroll
        for (int k = 0; k < 16; k++) {
            int ii = k * 256 + (int)threadIdx.x;
            if (ii < tn) pairs[saddr[ii]] = spair[ii];
        }
        __syncthreads();
    }
}

// h_r[n][j] = (x[n,:] . W1[r][:,j]) * invOut_r[n]
__global__ __launch_bounds__(256) void k_h1(const float* __restrict__ x, const float* __restrict__ invOut,
                                            const float* __restrict__ W1, float* __restrict__ hproj) {
    __shared__ float sW[32 * FH];
    __shared__ float sx[16][32];
    int r = blockIdx.y;
    const float* W = W1 + r * 32 * FH;
    int t = threadIdx.x;
    for (int i = t; i < 32 * FH; i += 256) sW[i] = W[i];
    int n0 = blockIdx.x * 16;
    for (int i = t; i < 16 * 32; i += 256) {
        int nn = i >> 5, kk = i & 31;
        int n = n0 + nn;
        sx[nn][kk] = (n < N_NODES) ? x[n * 32 + kk] : 0.0f;
    }
    __syncthreads();
    int nn = t >> 4, j = t & 15;
    int n = n0 + nn;
    if (n < N_NODES) {
        float s = 0.f;
#pragma unroll
        for (int k = 0; k < 32; k++) s += sx[nn][k] * sW[k * FH + j];
        hproj[((size_t)r * N_NODES + n) * FH + j] = s * invOut[r * N_NODES + n];
    }
}

// layer-1 bucket aggregate: LDS acc over 512 nodes x 16 feats, 16 lanes per edge.
__global__ __launch_bounds__(256) void k_passC1(const unsigned* __restrict__ pairsAll,
                                                int po0, int po1, int po2,
                                                const unsigned* __restrict__ bstartAll,
                                                const float* __restrict__ hproj,
                                                float* __restrict__ aggP) {
    __shared__ float acc[512 * FH];
    int r = blockIdx.z, sub = blockIdx.y, b = blockIdx.x;
    int S = (r == 0) ? 3 : (r == 1) ? 2 : 1;
    if (sub >= S) return;
    int slab = (r == 0) ? 0 : (r == 1) ? 3 : 5;
    const unsigned* bstart = bstartAll + r * 128;
    const unsigned* pairs = pairsAll + ((r == 0) ? po0 : (r == 1) ? po1 : po2);
    const float* h = hproj + (size_t)r * N_NODES * FH;
    unsigned e0 = bstart[b], e1 = bstart[b + 1];
    unsigned len = e1 - e0;
    unsigned q0 = e0 + (unsigned)((unsigned long long)len * (unsigned)sub / (unsigned)S);
    unsigned q1 = e0 + (unsigned)((unsigned long long)len * (unsigned)(sub + 1) / (unsigned)S);
    for (int i = threadIdx.x; i < 512 * FH; i += 256) acc[i] = 0.f;
    __syncthreads();
    int d0 = b << BSHIFT;
    int j = threadIdx.x & 15;
    unsigned e = q0 + (threadIdx.x >> 4);
    for (; e + 48 < q1; e += 64) {
        unsigned pA = pairs[e], pB = pairs[e + 16], pC = pairs[e + 32], pD = pairs[e + 48];
        float vA = h[(pA & 0xFFFFu) * FH + j];
        float vB = h[(pB & 0xFFFFu) * FH + j];
        float vC = h[(pC & 0xFFFFu) * FH + j];
        float vD = h[(pD & 0xFFFFu) * FH + j];
        atomicAdd(&acc[(((pA >> 16) - d0) << 4) + j], vA);
        atomicAdd(&acc[(((pB >> 16) - d0) << 4) + j], vB);
        atomicAdd(&acc[(((pC >> 16) - d0) << 4) + j], vC);
        atomicAdd(&acc[(((pD >> 16) - d0) << 4) + j], vD);
    }
    for (; e < q1; e += 16) {
        unsigned p = pairs[e];
        float v = h[(p & 0xFFFFu) * FH + j];
        atomicAdd(&acc[(((p >> 16) - d0) << 4) + j], v);
    }
    __syncthreads();
    int nmax = min(512, N_NODES - d0);
    float* outp = aggP + (size_t)(slab + sub) * (N_NODES * FH) + (size_t)d0 * FH;
    for (int i = threadIdx.x; i < nmax * FH; i += 256) outp[i] = acc[i];
}

__global__ void k_relu(const float* __restrict__ aggP, const float* __restrict__ invIn,
                       const float* __restrict__ b1, float* __restrict__ hout) {
    int i = blockIdx.x * 256 + threadIdx.x;
    if (i >= N_NODES * FH) return;
    int n = i >> 4, j = i & 15;
    const size_t SL = (size_t)N_NODES * FH;
    float s0 = aggP[i] + aggP[SL + i] + aggP[2 * SL + i];
    float s1 = aggP[3 * SL + i] + aggP[4 * SL + i];
    float s2 = aggP[5 * SL + i];
    float v = s0 * invIn[n] + s1 * invIn[N_NODES + n] + s2 * invIn[2 * N_NODES + n]
            + b1[j] + b1[FH + j] + b1[2 * FH + j];
    hout[i] = fmaxf(v, 0.f);
}

__global__ void k_h2(const float* __restrict__ hout, const float* __restrict__ invOut,
                     const float* __restrict__ W2, float* __restrict__ hs) {
    int n = blockIdx.x * 256 + threadIdx.x;
    int r = blockIdx.y;
    if (n >= N_NODES) return;
    const float4* hp = (const float4*)(hout + (size_t)n * FH);
    const float* w = W2 + r * FH;
    float s = 0.f;
#pragma unroll
    for (int q = 0; q < 4; q++) {
        float4 hv = hp[q];
        s += hv.x * w[q * 4 + 0] + hv.y * w[q * 4 + 1] + hv.z * w[q * 4 + 2] + hv.w * w[q * 4 + 3];
    }
    hs[r * N_NODES + n] = s * invOut[r * N_NODES + n];
}

// layer-2 bucket aggregate: scalar LDS acc.
__global__ __launch_bounds__(256) void k_passC2(const unsigned* __restrict__ pairsAll,
                                                int po0, int po1, int po2,
                                                const unsigned* __restrict__ bstartAll,
                                                const float* __restrict__ hsAll,
                                                float* __restrict__ outP) {
    __shared__ float acc[512];
    int r = blockIdx.z, sub = blockIdx.y, b = blockIdx.x;
    int S = (r == 0) ? 3 : (r == 1) ? 2 : 1;
    if (sub >= S) return;
    int slab = (r == 0) ? 0 : (r == 1) ? 3 : 5;
    const unsigned* bstart = bstartAll + r * 128;
    const unsigned* pairs = pairsAll + ((r == 0) ? po0 : (r == 1) ? po1 : po2);
    const float* hs = hsAll + (size_t)r * N_NODES;
    unsigned e0 = bstart[b], e1 = bstart[b + 1];
    unsigned len = e1 - e0;
    unsigned q0 = e0 + (unsigned)((unsigned long long)len * (unsigned)sub / (unsigned)S);
    unsigned q1 = e0 + (unsigned)((unsigned long long)len * (unsigned)(sub + 1) / (unsigned)S);
    for (int i = threadIdx.x; i < 512; i += 256) acc[i] = 0.f;
    __syncthreads();
    int d0 = b << BSHIFT;
    unsigned e = q0 + threadIdx.x;
    for (; e + 768 < q1; e += 1024) {
        unsigned pA = pairs[e], pB = pairs[e + 256], pC = pairs[e + 512], pD = pairs[e + 768];
        float vA = hs[pA & 0xFFFFu], vB = hs[pB & 0xFFFFu];
        float vC = hs[pC & 0xFFFFu], vD = hs[pD & 0xFFFFu];
        atomicAdd(&acc[(pA >> 16) - d0], vA);
        atomicAdd(&acc[(pB >> 16) - d0], vB);
        atomicAdd(&acc[(pC >> 16) - d0], vC);
        atomicAdd(&acc[(pD >> 16) - d0], vD);
    }
    for (; e < q1; e += 256) {
        unsigned p = pairs[e];
        atomicAdd(&acc[(p >> 16) - d0], hs[p & 0xFFFFu]);
    }
    __syncthreads();
    int nmax = min(512, N_NODES - d0);
    float* op = outP + (size_t)(slab + sub) * N_NODES + d0;
    for (int i = threadIdx.x; i < nmax; i += 256) op[i] = acc[i];
}

__global__ void k_final(const float* __restrict__ outP, const float* __restrict__ invIn,
                        const float* __restrict__ b2, float* __restrict__ out) {
    int n = blockIdx.x * 256 + threadIdx.x;
    if (n >= N_NODES) return;
    float s0 = outP[n] + outP[N_NODES + n] + outP[2 * N_NODES + n];
    float s1 = outP[3 * N_NODES + n] + outP[4 * N_NODES + n];
    float s2 = outP[5 * N_NODES + n];
    out[n] = s0 * invIn[n] + s1 * invIn[N_NODES + n] + s2 * invIn[2 * N_NODES + n]
           + b2[0] + b2[1] + b2[2];
}

// =============== fallback (round-1) kernels ===============

__global__ void f_zero(float* __restrict__ p, int n) {
    int i = blockIdx.x * blockDim.x + threadIdx.x;
    if (i < n) p[i] = 0.0f;
}
__global__ void f_deg(const int* __restrict__ src, const int* __restrict__ dst, int E,
                      float* __restrict__ dout, float* __restrict__ din) {
    int i = blockIdx.x * blockDim.x + threadIdx.x;
    if (i < E) { atomicAdd(&dout[src[i]], 1.0f); atomicAdd(&din[dst[i]], 1.0f); }
}
__global__ void f_rsqrt(float* __restrict__ p, int n) {
    int i = blockIdx.x * blockDim.x + threadIdx.x;
    if (i < n) p[i] = rsqrtf(fmaxf(p[i], 1.0f));
}
__global__ void f_agg1(const int* __restrict__ src, const int* __restrict__ dst, int E,
                       const float* __restrict__ h, const float* __restrict__ invin,
                       float* __restrict__ agg) {
    int idx = blockIdx.x * blockDim.x + threadIdx.x;
    if (idx < E * FH) {
        int e = idx >> 4, j = idx & 15;
        atomicAdd(&agg[dst[e] * FH + j], h[src[e] * FH + j] * invin[dst[e]]);
    }
}
__global__ void f_relu(float* __restrict__ agg, const float* __restrict__ b1) {
    int i = blockIdx.x * blockDim.x + threadIdx.x;
    if (i < N_NODES * FH) {
        int j = i & 15;
        agg[i] = fmaxf(agg[i] + b1[j] + b1[FH + j] + b1[2 * FH + j], 0.0f);
    }
}
__global__ void f_outinit(float* __restrict__ out, const float* __restrict__ b2) {
    int i = blockIdx.x * blockDim.x + threadIdx.x;
    if (i < N_NODES) out[i] = b2[0] + b2[1] + b2[2];
}
__global__ void f_h2(const float* __restrict__ h1, const float* __restrict__ invout,
                     const float* __restrict__ W2r, float* __restrict__ hsv) {
    int n = blockIdx.x * blockDim.x + threadIdx.x;
    if (n < N_NODES) {
        const float4* hp = (const float4*)(h1 + (size_t)n * FH);
        float s = 0.0f;
#pragma unroll
        for (int q = 0; q < 4; q++) {
            float4 hv = hp[q];
            s += hv.x * W2r[q * 4] + hv.y * W2r[q * 4 + 1] + hv.z * W2r[q * 4 + 2] + hv.w * W2r[q * 4 + 3];
        }
        hsv[n] = s * invout[n];
    }
}
__global__ void f_agg2(const int* __restrict__ src, const int* __restrict__ dst, int E,
                       const float* __restrict__ hsv, const float* __restrict__ invin,
                       float* __restrict__ out) {
    int e = blockIdx.x * blockDim.x + threadIdx.x;
    if (e < E) atomicAdd(&out[dst[e]], hsv[src[e]] * invin[dst[e]]);
}

// =============== host ===============

extern "C" void kernel_launch(void* const* d_in, const int* in_sizes, int n_in,
                              void* d_out, int out_size, void* d_ws, size_t ws_size,
                              hipStream_t stream) {
    const float* x = (const float*)d_in[0];
    const int* srcs[3] = { (const int*)d_in[1], (const int*)d_in[3], (const int*)d_in[5] };
    const int* dsts[3] = { (const int*)d_in[2], (const int*)d_in[4], (const int*)d_in[6] };
    int E[3] = { in_sizes[1], in_sizes[3], in_sizes[5] };
    const float* W1 = (const float*)d_in[7];
    const float* b1 = (const float*)d_in[8];
    const float* W2 = (const float*)d_in[9];
    const float* b2 = (const float*)d_in[10];
    float* out = (float*)d_out;
    const int N = N_NODES;
    const int B = 256;

    if (ws_size >= (size_t)WS_WORDS * 4u) {
        unsigned* ws = (unsigned*)d_ws;
        float* invOut = (float*)(ws + OFF_INVOUT);
        float* invIn  = (float*)(ws + OFF_INVIN);
        unsigned* rawIn = ws + OFF_RAWIN;
        unsigned* bstart = ws + OFF_BSTART;
        unsigned* gcur = ws + OFF_GCUR;
        float* hs = (float*)(ws + OFF_HS);
        float* hproj = (float*)(ws + OFF_HPROJ);
        unsigned* histP = ws + OFF_HISTP;
        float* aggP = (float*)(ws + OFF_AGGP);
        float* hout = (float*)(ws + OFF_HOUT);
        unsigned* pairs = ws + OFF_PAIRS;
        float* outP = (float*)(ws + OFF_OUTP);
        int po[3] = { 0, E[0], E[0] + E[1] };

        k_hist<<<dim3(NCH, NPASS, 6), B, 0, stream>>>(
            srcs[0], srcs[1], srcs[2], dsts[0], dsts[1], dsts[2],
            E[0], E[1], E[2], E[0], E[1], E[2], histP);
        k_degreduce<<<dim3((N + B - 1) / B, 6), B, 0, stream>>>(histP, invOut, invIn, rawIn);
        k_bucketScan<<<3, B, 0, stream>>>(rawIn, bstart, gcur);
        k_passB<<<dim3(256, 1, 3), B, 0, stream>>>(
            srcs[0], srcs[1], srcs[2], dsts[0], dsts[1], dsts[2],
            E[0], E[1], E[2], po[0], po[1], po[2], pairs, gcur);
        k_h1<<<dim3((N + 15) / 16, 3), B, 0, stream>>>(x, invOut, W1, hproj);
        k_passC1<<<dim3(NBUK, 3, 3), B, 0, stream>>>(pairs, po[0], po[1], po[2], bstart, hproj, aggP);
        k_relu<<<(N * FH + B - 1) / B, B, 0, stream>>>(aggP, invIn, b1, hout);
        k_h2<<<dim3((N + B - 1) / B, 3), B, 0, stream>>>(hout, invOut, W2, hs);
        k_passC2<<<dim3(NBUK, 3, 3), B, 0, stream>>>(pairs, po[0], po[1], po[2], bstart, hs, outP);
        k_final<<<(N + B - 1) / B, B, 0, stream>>>(outP, invIn, b2, out);
    } else {
        // fallback: round-1 atomic path (ws < 52.4 MB)
        float* ws = (float*)d_ws;
        float* invOut = ws;
        float* invIn = ws + 3 * (size_t)N;
        float* h = ws + 6 * (size_t)N;
        float* agg = ws + 22 * (size_t)N;
        float* hsv = ws + 38 * (size_t)N;
        f_zero<<<(6 * N + B - 1) / B, B, 0, stream>>>(invOut, 6 * N);
        f_zero<<<(16 * N + B - 1) / B, B, 0, stream>>>(agg, 16 * N);
        for (int r = 0; r < 3; r++)
            f_deg<<<(E[r] + B - 1) / B, B, 0, stream>>>(srcs[r], dsts[r], E[r],
                                                        invOut + (size_t)r * N, invIn + (size_t)r * N);
        f_rsqrt<<<(6 * N + B - 1) / B, B, 0, stream>>>(invOut, 6 * N);
        for (int r = 0; r < 3; r++) {
            k_h1<<<dim3((N + 15) / 16, 1), B, 0, stream>>>(x, invOut + (size_t)r * N,
                                                           W1 + (size_t)r * 32 * FH, h);
            f_agg1<<<(E[r] * FH + B - 1) / B, B, 0, stream>>>(srcs[r], dsts[r], E[r], h,
                                                              invIn + (size_t)r * N, agg);
        }
        f_relu<<<(N * FH + B - 1) / B, B, 0, stream>>>(agg, b1);
        f_outinit<<<(N + B - 1) / B, B, 0, stream>>>(out, b2);
        for (int r = 0; r < 3; r++) {
            f_h2<<<(N + B - 1) / B, B, 0, stream>>>(agg, invOut + (size_t)r * N,
                                                    W2 + (size_t)r * FH, hsv);
            f_agg2<<<(E[r] + B - 1) / B, B, 0, stream>>>(srcs[r], dsts[r], E[r], hsv,
                                                         invIn + (size_t)r * N, out);
        }
    }
}

// Round 3
// 739.928 us; speedup vs baseline: 1.3791x; 1.2530x over previous
//
#include <hip/hip_runtime.h>

#define N_NODES 50000
#define FH 16
#define NBUK 391         // buckets of 128 nodes: bucket = dst >> 7
#define BSHIFT 7
#define TILE 4096        // passB reorder tile
#define NCH 32           // src-histogram chunks

// ---- ws layout (u32 words) ----
#define OFF_INVOUT   0u           // [3][N]
#define OFF_INVIN    150000u      // [3][N]
#define OFF_BUKCNT   300000u      // [3][400]
#define OFF_BSTART   301200u      // [3][400]
#define OFF_GCUR     302400u      // [3][400]
#define OFF_CNTP     303600u      // [6][N] u32
#define OFF_HPROJ    603600u      // [3][N][16] f32
#define OFF_HOUT     3003600u     // [N][16] f32
#define OFF_AGGP     3803600u     // [6][N][16] f32
#define OFF_SRCHIST  3803600u     // [3][32][25000] u32 (alias: dead before aggP written)
#define OFF_HS       3803600u     // [3][N] f32 (alias: written after aggP dead)
#define OFF_OUTP     3953600u     // [6][N] f32 (alias: written after aggP dead)
#define OFF_PAIRS    8603600u     // E_total packed edges
// ws need = OFF_PAIRS + E_total  (~12.8M words = 51.2 MB)

__global__ void k_zero_u32(unsigned* __restrict__ p, int n) {
    int i = blockIdx.x * 256 + threadIdx.x;
    if (i < n) p[i] = 0u;
}

// packed src histogram: bins[n>>1] += (n&1) ? 1<<16 : 1   (counts < 65536 per chunk)
__global__ __launch_bounds__(256) void k_srcHist(const int* s0, const int* s1, const int* s2,
                                                 int E0, int E1, int E2,
                                                 unsigned* __restrict__ histP) {
    __shared__ unsigned bins[25000];
    int c = blockIdx.x, r = blockIdx.y;
    const int* arr = (r == 0) ? s0 : (r == 1) ? s1 : s2;
    int E = (r == 0) ? E0 : (r == 1) ? E1 : E2;
    for (int i = threadIdx.x; i < 25000; i += 256) bins[i] = 0u;
    __syncthreads();
    int chunk = (E + NCH - 1) / NCH;
    int a0 = c * chunk, a1 = min(a0 + chunk, E);
    for (int i = a0 + threadIdx.x; i < a1; i += 256) {
        unsigned v = (unsigned)arr[i];
        atomicAdd(&bins[v >> 1], (v & 1u) ? 65536u : 1u);
    }
    __syncthreads();
    unsigned* out = histP + ((size_t)r * NCH + c) * 25000;
    for (int i = threadIdx.x; i < 25000; i += 256) out[i] = bins[i];
}

__global__ void k_degreduceOut(const unsigned* __restrict__ histP, float* __restrict__ invOut) {
    int n = blockIdx.x * 256 + threadIdx.x;
    int r = blockIdx.y;
    if (n >= N_NODES) return;
    const unsigned* p = histP + (size_t)r * NCH * 25000 + (n >> 1);
    unsigned s = 0;
#pragma unroll
    for (int c = 0; c < NCH; c++) {
        unsigned w = p[(size_t)c * 25000];
        s += (n & 1) ? (w >> 16) : (w & 0xFFFFu);
    }
    invOut[r * N_NODES + n] = rsqrtf((float)(s ? s : 1u));
}

// per-(relation,bucket) dst counts
__global__ __launch_bounds__(256) void k_bukCount(const int* d0p, const int* d1p, const int* d2p,
                                                  int E0, int E1, int E2,
                                                  unsigned* __restrict__ bukCnt) {
    __shared__ unsigned bins[NBUK];
    int c = blockIdx.x, r = blockIdx.y;
    const int* arr = (r == 0) ? d0p : (r == 1) ? d1p : d2p;
    int E = (r == 0) ? E0 : (r == 1) ? E1 : E2;
    for (int i = threadIdx.x; i < NBUK; i += 256) bins[i] = 0u;
    __syncthreads();
    int nb = gridDim.x;
    int chunk = (E + nb - 1) / nb;
    int a0 = c * chunk, a1 = min(a0 + chunk, E);
    for (int i = a0 + threadIdx.x; i < a1; i += 256)
        atomicAdd(&bins[((unsigned)arr[i]) >> BSHIFT], 1u);
    __syncthreads();
    for (int b = threadIdx.x; b < NBUK; b += 256)
        if (bins[b]) atomicAdd(&bukCnt[r * 400 + b], bins[b]);
}

__global__ void k_bucketScan(const unsigned* __restrict__ bukCnt, unsigned* __restrict__ bstart,
                             unsigned* __restrict__ gcur) {
    int r = blockIdx.x;
    if (threadIdx.x == 0) {
        unsigned acc = 0;
        for (int b = 0; b < NBUK; b++) { bstart[r * 400 + b] = acc; acc += bukCnt[r * 400 + b]; }
        bstart[r * 400 + NBUK] = acc;
    }
    __syncthreads();
    for (int i = threadIdx.x; i <= NBUK; i += 256) gcur[r * 400 + i] = bstart[r * 400 + i];
}

// bucket-scatter with in-LDS tile reorder. pair = (dst<<16)|src.
__global__ __launch_bounds__(256) void k_passB(
    const int* s0p, const int* s1p, const int* s2p,
    const int* d0p, const int* d1p, const int* d2p,
    int E0, int E1, int E2, int po0, int po1, int po2,
    unsigned* __restrict__ pairsAll, unsigned* __restrict__ gcurAll) {
    __shared__ unsigned cnt[NBUK];
    __shared__ unsigned off[NBUK];
    __shared__ unsigned gbase[NBUK];
    __shared__ unsigned spair[TILE];
    __shared__ unsigned saddr[TILE];
    int r = blockIdx.z;
    const int* src = (r == 0) ? s0p : (r == 1) ? s1p : s2p;
    const int* dst = (r == 0) ? d0p : (r == 1) ? d1p : d2p;
    int E = (r == 0) ? E0 : (r == 1) ? E1 : E2;
    unsigned* pairs = pairsAll + ((r == 0) ? po0 : (r == 1) ? po1 : po2);
    unsigned* gcur = gcurAll + r * 400;
    int nb = gridDim.x;
    int chunk = (E + nb - 1) / nb;
    int c0 = blockIdx.x * chunk;
    int c1 = min(c0 + chunk, E);
    for (int t0 = c0; t0 < c1; t0 += TILE) {
        int tn = min(TILE, c1 - t0);
        for (int i = threadIdx.x; i < NBUK; i += 256) cnt[i] = 0u;
        __syncthreads();
        unsigned pk[16], bk[16], sl[16];
#pragma unroll
        for (int k = 0; k < 16; k++) {
            int ii = k * 256 + (int)threadIdx.x;
            bk[k] = 0xFFFFFFFFu;
            if (ii < tn) {
                int i = t0 + ii;
                unsigned s = (unsigned)src[i], d = (unsigned)dst[i];
                pk[k] = (d << 16) | s;
                unsigned b = d >> BSHIFT;
                bk[k] = b;
                sl[k] = atomicAdd(&cnt[b], 1u);
            }
        }
        __syncthreads();
        if (threadIdx.x == 0) {
            unsigned acc = 0;
            for (int b = 0; b < NBUK; b++) { unsigned t = cnt[b]; off[b] = acc; acc += t; }
        }
        __syncthreads();
        for (int b = threadIdx.x; b < NBUK; b += 256) {
            unsigned c = cnt[b];
            if (c) gbase[b] = atomicAdd(&gcur[b], c);
        }
        __syncthreads();
#pragma unroll
        for (int k = 0; k < 16; k++) {
            if (bk[k] != 0xFFFFFFFFu) {
                unsigned idx = off[bk[k]] + sl[k];
                spair[idx] = pk[k];
                saddr[idx] = gbase[bk[k]] + sl[k];
            }
        }
        __syncthreads();
#pragma unroll
        for (int k = 0; k < 16; k++) {
            int ii = k * 256 + (int)threadIdx.x;
            if (ii < tn) pairs[saddr[ii]] = spair[ii];
        }
        __syncthreads();
    }
}

// h_r[n][j] = (x[n,:] . W1[r][:,j]) * invOut_r[n]
__global__ __launch_bounds__(256) void k_h1(const float* __restrict__ x, const float* __restrict__ invOut,
                                            const float* __restrict__ W1, float* __restrict__ hproj) {
    __shared__ float sW[32 * FH];
    __shared__ float sx[16][32];
    int r = blockIdx.y;
    const float* W = W1 + r * 32 * FH;
    int t = threadIdx.x;
    for (int i = t; i < 32 * FH; i += 256) sW[i] = W[i];
    int n0 = blockIdx.x * 16;
    for (int i = t; i < 16 * 32; i += 256) {
        int nn = i >> 5, kk = i & 31;
        int n = n0 + nn;
        sx[nn][kk] = (n < N_NODES) ? x[n * 32 + kk] : 0.0f;
    }
    __syncthreads();
    int nn = t >> 4, j = t & 15;
    int n = n0 + nn;
    if (n < N_NODES) {
        float s = 0.f;
#pragma unroll
        for (int k = 0; k < 32; k++) s += sx[nn][k] * sW[k * FH + j];
        hproj[((size_t)r * N_NODES + n) * FH + j] = s * invOut[r * N_NODES + n];
    }
}

// layer-1 bucket aggregate: 128-node window, 16-lane groups, 16-deep gather pipeline.
__global__ __launch_bounds__(256) void k_passC1(const unsigned* __restrict__ pairsAll,
                                                int po0, int po1, int po2,
                                                const unsigned* __restrict__ bstartAll,
                                                const float* __restrict__ hproj,
                                                float* __restrict__ aggP,
                                                unsigned* __restrict__ cntP) {
    __shared__ float acc[128 * FH];
    __shared__ unsigned cnt[128];
    int r = blockIdx.z, sub = blockIdx.y, b = blockIdx.x;
    int S = (r == 0) ? 3 : (r == 1) ? 2 : 1;
    if (sub >= S) return;
    int slab = ((r == 0) ? 0 : (r == 1) ? 3 : 5) + sub;
    const unsigned* bstart = bstartAll + r * 400;
    const unsigned* pairs = pairsAll + ((r == 0) ? po0 : (r == 1) ? po1 : po2);
    const float* h = hproj + (size_t)r * N_NODES * FH;
    unsigned e0 = bstart[b], e1 = bstart[b + 1];
    unsigned len = e1 - e0;
    unsigned q0 = e0 + (unsigned)((unsigned long long)len * (unsigned)sub / (unsigned)S);
    unsigned q1 = e0 + (unsigned)((unsigned long long)len * (unsigned)(sub + 1) / (unsigned)S);
    for (int i = threadIdx.x; i < 128 * FH; i += 256) acc[i] = 0.f;
    if (threadIdx.x < 128) cnt[threadIdx.x] = 0u;
    __syncthreads();
    int d0 = b << BSHIFT;
    int g = threadIdx.x >> 4, j = threadIdx.x & 15;
    unsigned glen = q1 - q0;
    unsigned gq0 = q0 + (unsigned)((unsigned long long)glen * (unsigned)g / 16u);
    unsigned gq1 = q0 + (unsigned)((unsigned long long)glen * (unsigned)(g + 1) / 16u);
    unsigned e = gq0;
    for (; e + 16 <= gq1; e += 16) {
        unsigned pj = pairs[e + j];              // coalesced: 16 consecutive words per group
        atomicAdd(&cnt[(pj >> 16) - d0], 1u);    // deg_in partial (one per edge, full lanes)
        unsigned pk[16];
#pragma unroll
        for (int k = 0; k < 16; k++) pk[k] = __shfl(pj, k, 16);
        float v[16];
#pragma unroll
        for (int k = 0; k < 16; k++) v[k] = h[(pk[k] & 0xFFFFu) * FH + j];
#pragma unroll
        for (int k = 0; k < 16; k++)
            atomicAdd(&acc[((pk[k] >> 16) - d0) * FH + j], v[k]);
    }
    for (; e < gq1; e++) {
        unsigned p = pairs[e];
        if (j == 0) atomicAdd(&cnt[(p >> 16) - d0], 1u);
        float v = h[(p & 0xFFFFu) * FH + j];
        atomicAdd(&acc[((p >> 16) - d0) * FH + j], v);
    }
    __syncthreads();
    int nmax = min(128, N_NODES - d0);
    float* outp = aggP + (size_t)slab * ((size_t)N_NODES * FH) + (size_t)d0 * FH;
    for (int i = threadIdx.x; i < nmax * FH; i += 256) outp[i] = acc[i];
    if (threadIdx.x < nmax) cntP[(size_t)slab * N_NODES + d0 + threadIdx.x] = cnt[threadIdx.x];
}

__global__ void k_invIn(const unsigned* __restrict__ cntP, float* __restrict__ invIn) {
    int n = blockIdx.x * 256 + threadIdx.x;
    if (n >= N_NODES) return;
    unsigned c0 = cntP[n] + cntP[N_NODES + n] + cntP[2 * N_NODES + n];
    unsigned c1 = cntP[3 * (size_t)N_NODES + n] + cntP[4 * (size_t)N_NODES + n];
    unsigned c2 = cntP[5 * (size_t)N_NODES + n];
    invIn[n] = rsqrtf((float)(c0 ? c0 : 1u));
    invIn[N_NODES + n] = rsqrtf((float)(c1 ? c1 : 1u));
    invIn[2 * N_NODES + n] = rsqrtf((float)(c2 ? c2 : 1u));
}

__global__ void k_relu(const float* __restrict__ aggP, const float* __restrict__ invIn,
                       const float* __restrict__ b1, float* __restrict__ hout) {
    int i = blockIdx.x * 256 + threadIdx.x;
    if (i >= N_NODES * FH) return;
    int n = i >> 4, j = i & 15;
    const size_t SL = (size_t)N_NODES * FH;
    float s0 = aggP[i] + aggP[SL + i] + aggP[2 * SL + i];
    float s1 = aggP[3 * SL + i] + aggP[4 * SL + i];
    float s2 = aggP[5 * SL + i];
    float v = s0 * invIn[n] + s1 * invIn[N_NODES + n] + s2 * invIn[2 * N_NODES + n]
            + b1[j] + b1[FH + j] + b1[2 * FH + j];
    hout[i] = fmaxf(v, 0.f);
}

__global__ void k_h2(const float* __restrict__ hout, const float* __restrict__ invOut,
                     const float* __restrict__ W2, float* __restrict__ hs) {
    int n = blockIdx.x * 256 + threadIdx.x;
    int r = blockIdx.y;
    if (n >= N_NODES) return;
    const float4* hp = (const float4*)(hout + (size_t)n * FH);
    const float* w = W2 + r * FH;
    float s = 0.f;
#pragma unroll
    for (int q = 0; q < 4; q++) {
        float4 hv = hp[q];
        s += hv.x * w[q * 4 + 0] + hv.y * w[q * 4 + 1] + hv.z * w[q * 4 + 2] + hv.w * w[q * 4 + 3];
    }
    hs[r * N_NODES + n] = s * invOut[r * N_NODES + n];
}

// layer-2 bucket aggregate: scalar LDS acc, 8-deep pipeline.
__global__ __launch_bounds__(256) void k_passC2(const unsigned* __restrict__ pairsAll,
                                                int po0, int po1, int po2,
                                                const unsigned* __restrict__ bstartAll,
                                                const float* __restrict__ hsAll,
                                                float* __restrict__ outP) {
    __shared__ float acc[128];
    int r = blockIdx.z, sub = blockIdx.y, b = blockIdx.x;
    int S = (r == 0) ? 3 : (r == 1) ? 2 : 1;
    if (sub >= S) return;
    int slab = ((r == 0) ? 0 : (r == 1) ? 3 : 5) + sub;
    const unsigned* bstart = bstartAll + r * 400;
    const unsigned* pairs = pairsAll + ((r == 0) ? po0 : (r == 1) ? po1 : po2);
    const float* hs = hsAll + (size_t)r * N_NODES;
    unsigned e0 = bstart[b], e1 = bstart[b + 1];
    unsigned len = e1 - e0;
    unsigned q0 = e0 + (unsigned)((unsigned long long)len * (unsigned)sub / (unsigned)S);
    unsigned q1 = e0 + (unsigned)((unsigned long long)len * (unsigned)(sub + 1) / (unsigned)S);
    if (threadIdx.x < 128) acc[threadIdx.x] = 0.f;
    __syncthreads();
    int d0 = b << BSHIFT;
    unsigned e = q0 + threadIdx.x;
    for (; e + 1792 < q1; e += 2048) {
        unsigned p[8];
#pragma unroll
        for (int k = 0; k < 8; k++) p[k] = pairs[e + k * 256];
        float v[8];
#pragma unroll
        for (int k = 0; k < 8; k++) v[k] = hs[p[k] & 0xFFFFu];
#pragma unroll
        for (int k = 0; k < 8; k++) atomicAdd(&acc[(p[k] >> 16) - d0], v[k]);
    }
    for (; e < q1; e += 256) {
        unsigned p = pairs[e];
        atomicAdd(&acc[(p >> 16) - d0], hs[p & 0xFFFFu]);
    }
    __syncthreads();
    int nmax = min(128, N_NODES - d0);
    if (threadIdx.x < nmax)
        outP[(size_t)slab * N_NODES + d0 + threadIdx.x] = acc[threadIdx.x];
}

__global__ void k_final(const float* __restrict__ outP, const float* __restrict__ invIn,
                        const float* __restrict__ b2, float* __restrict__ out) {
    int n = blockIdx.x * 256 + threadIdx.x;
    if (n >= N_NODES) return;
    float s0 = outP[n] + outP[N_NODES + n] + outP[2 * (size_t)N_NODES + n];
    float s1 = outP[3 * (size_t)N_NODES + n] + outP[4 * (size_t)N_NODES + n];
    float s2 = outP[5 * (size_t)N_NODES + n];
    out[n] = s0 * invIn[n] + s1 * invIn[N_NODES + n] + s2 * invIn[2 * N_NODES + n]
           + b2[0] + b2[1] + b2[2];
}

// =============== fallback (round-1) kernels ===============

__global__ void f_zero(float* __restrict__ p, int n) {
    int i = blockIdx.x * blockDim.x + threadIdx.x;
    if (i < n) p[i] = 0.0f;
}
__global__ void f_deg(const int* __restrict__ src, const int* __restrict__ dst, int E,
                      float* __restrict__ dout, float* __restrict__ din) {
    int i = blockIdx.x * blockDim.x + threadIdx.x;
    if (i < E) { atomicAdd(&dout[src[i]], 1.0f); atomicAdd(&din[dst[i]], 1.0f); }
}
__global__ void f_rsqrt(float* __restrict__ p, int n) {
    int i = blockIdx.x * blockDim.x + threadIdx.x;
    if (i < n) p[i] = rsqrtf(fmaxf(p[i], 1.0f));
}
__global__ void f_agg1(const int* __restrict__ src, const int* __restrict__ dst, int E,
                       const float* __restrict__ h, const float* __restrict__ invin,
                       float* __restrict__ agg) {
    int idx = blockIdx.x * blockDim.x + threadIdx.x;
    if (idx < E * FH) {
        int e = idx >> 4, j = idx & 15;
        atomicAdd(&agg[dst[e] * FH + j], h[src[e] * FH + j] * invin[dst[e]]);
    }
}
__global__ void f_relu(float* __restrict__ agg, const float* __restrict__ b1) {
    int i = blockIdx.x * blockDim.x + threadIdx.x;
    if (i < N_NODES * FH) {
        int j = i & 15;
        agg[i] = fmaxf(agg[i] + b1[j] + b1[FH + j] + b1[2 * FH + j], 0.0f);
    }
}
__global__ void f_outinit(float* __restrict__ out, const float* __restrict__ b2) {
    int i = blockIdx.x * blockDim.x + threadIdx.x;
    if (i < N_NODES) out[i] = b2[0] + b2[1] + b2[2];
}
__global__ void f_h2(const float* __restrict__ h1, const float* __restrict__ invout,
                     const float* __restrict__ W2r, float* __restrict__ hsv) {
    int n = blockIdx.x * blockDim.x + threadIdx.x;
    if (n < N_NODES) {
        const float4* hp = (const float4*)(h1 + (size_t)n * FH);
        float s = 0.0f;
#pragma unroll
        for (int q = 0; q < 4; q++) {
            float4 hv = hp[q];
            s += hv.x * W2r[q * 4] + hv.y * W2r[q * 4 + 1] + hv.z * W2r[q * 4 + 2] + hv.w * W2r[q * 4 + 3];
        }
        hsv[n] = s * invout[n];
    }
}
__global__ void f_agg2(const int* __restrict__ src, const int* __restrict__ dst, int E,
                       const float* __restrict__ hsv, const float* __restrict__ invin,
                       float* __restrict__ out) {
    int e = blockIdx.x * blockDim.x + threadIdx.x;
    if (e < E) atomicAdd(&out[dst[e]], hsv[src[e]] * invin[dst[e]]);
}

// =============== host ===============

extern "C" void kernel_launch(void* const* d_in, const int* in_sizes, int n_in,
                              void* d_out, int out_size, void* d_ws, size_t ws_size,
                              hipStream_t stream) {
    const float* x = (const float*)d_in[0];
    const int* srcs[3] = { (const int*)d_in[1], (const int*)d_in[3], (const int*)d_in[5] };
    const int* dsts[3] = { (const int*)d_in[2], (const int*)d_in[4], (const int*)d_in[6] };
    int E[3] = { in_sizes[1], in_sizes[3], in_sizes[5] };
    const float* W1 = (const float*)d_in[7];
    const float* b1 = (const float*)d_in[8];
    const float* W2 = (const float*)d_in[9];
    const float* b2 = (const float*)d_in[10];
    float* out = (float*)d_out;
    const int N = N_NODES;
    const int B = 256;
    size_t Etot = (size_t)E[0] + E[1] + E[2];
    size_t need = ((size_t)OFF_PAIRS + Etot) * 4u;

    if (ws_size >= need) {
        unsigned* ws = (unsigned*)d_ws;
        float* invOut = (float*)(ws + OFF_INVOUT);
        float* invIn  = (float*)(ws + OFF_INVIN);
        unsigned* bukCnt = ws + OFF_BUKCNT;
        unsigned* bstart = ws + OFF_BSTART;
        unsigned* gcur   = ws + OFF_GCUR;
        unsigned* cntP   = ws + OFF_CNTP;
        float* hproj = (float*)(ws + OFF_HPROJ);
        float* hout  = (float*)(ws + OFF_HOUT);
        float* aggP  = (float*)(ws + OFF_AGGP);
        unsigned* srcHist = ws + OFF_SRCHIST;
        float* hs    = (float*)(ws + OFF_HS);
        float* outP  = (float*)(ws + OFF_OUTP);
        unsigned* pairs = ws + OFF_PAIRS;
        int po[3] = { 0, E[0], E[0] + E[1] };

        k_zero_u32<<<(1200 + B - 1) / B, B, 0, stream>>>(bukCnt, 1200);
        k_srcHist<<<dim3(NCH, 3), B, 0, stream>>>(srcs[0], srcs[1], srcs[2], E[0], E[1], E[2], srcHist);
        k_degreduceOut<<<dim3((N + B - 1) / B, 3), B, 0, stream>>>(srcHist, invOut);
        k_bukCount<<<dim3(64, 3), B, 0, stream>>>(dsts[0], dsts[1], dsts[2], E[0], E[1], E[2], bukCnt);
        k_bucketScan<<<3, B, 0, stream>>>(bukCnt, bstart, gcur);
        k_passB<<<dim3(256, 1, 3), B, 0, stream>>>(
            srcs[0], srcs[1], srcs[2], dsts[0], dsts[1], dsts[2],
            E[0], E[1], E[2], po[0], po[1], po[2], pairs, gcur);
        k_h1<<<dim3((N + 15) / 16, 3), B, 0, stream>>>(x, invOut, W1, hproj);
        k_passC1<<<dim3(NBUK, 3, 3), B, 0, stream>>>(pairs, po[0], po[1], po[2], bstart, hproj, aggP, cntP);
        k_invIn<<<(N + B - 1) / B, B, 0, stream>>>(cntP, invIn);
        k_relu<<<(N * FH + B - 1) / B, B, 0, stream>>>(aggP, invIn, b1, hout);
        k_h2<<<dim3((N + B - 1) / B, 3), B, 0, stream>>>(hout, invOut, W2, hs);
        k_passC2<<<dim3(NBUK, 3, 3), B, 0, stream>>>(pairs, po[0], po[1], po[2], bstart, hs, outP);
        k_final<<<(N + B - 1) / B, B, 0, stream>>>(outP, invIn, b2, out);
    } else {
        // fallback: round-1 atomic path
        float* wsf = (float*)d_ws;
        float* invOut = wsf;
        float* invIn = wsf + 3 * (size_t)N;
        float* h = wsf + 6 * (size_t)N;
        float* agg = wsf + 22 * (size_t)N;
        float* hsv = wsf + 38 * (size_t)N;
        f_zero<<<(6 * N + B - 1) / B, B, 0, stream>>>(invOut, 6 * N);
        f_zero<<<(16 * N + B - 1) / B, B, 0, stream>>>(agg, 16 * N);
        for (int r = 0; r < 3; r++)
            f_deg<<<(E[r] + B - 1) / B, B, 0, stream>>>(srcs[r], dsts[r], E[r],
                                                        invOut + (size_t)r * N, invIn + (size_t)r * N);
        f_rsqrt<<<(6 * N + B - 1) / B, B, 0, stream>>>(invOut, 6 * N);
        for (int r = 0; r < 3; r++) {
            k_h1<<<dim3((N + 15) / 16, 1), B, 0, stream>>>(x, invOut + (size_t)r * N,
                                                           W1 + (size_t)r * 32 * FH, h);
            f_agg1<<<(E[r] * FH + B - 1) / B, B, 0, stream>>>(srcs[r], dsts[r], E[r], h,
                                                              invIn + (size_t)r * N, agg);
        }
        f_relu<<<(N * FH + B - 1) / B, B, 0, stream>>>(agg, b1);
        f_outinit<<<(N + B - 1) / B, B, 0, stream>>>(out, b2);
        for (int r = 0; r < 3; r++) {
            f_h2<<<(N + B - 1) / B, B, 0, stream>>>(agg, invOut + (size_t)r * N,
                                                    W2 + (size_t)r * FH, hsv);
            f_agg2<<<(E[r] + B - 1) / B, B, 0, stream>>>(srcs[r], dsts[r], E[r], hsv,
                                                         invIn + (size_t)r * N, out);
        }
    }
}

// Round 5
// 672.039 us; speedup vs baseline: 1.5184x; 1.1010x over previous
//
#include <hip/hip_runtime.h>

#define N_NODES 50000
#define FH 16
#define NBUK 782          // 64-node buckets: bucket = dst >> 6
#define BSHIFT 6
#define BSTRIDE 800
#define TILE 4096
#define NCH 16            // src-histogram chunks

// ---- ws layout (u32 words) ----
#define OFF_INVOUT   0u           // [3][N] f32
#define OFF_INVIN    150000u      // [3][N] f32
#define OFF_BUKCNT   300000u      // [3][800]
#define OFF_BSTART   302400u      // [3][800]
#define OFF_GCUR     304800u      // [3][800]
#define OFF_ROWPTR   307200u      // [3][N+1] u32 (absolute into srcSorted)
#define OFF_HPROJ    457216u      // [3][N][16] f32
#define OFF_HOUT     2857216u     // [N][16] f32
#define OFF_AGGP     3657216u     // [3][N][16] f32 (scaled by invIn already)
#define OFF_SRCHIST  3657216u     // [3][16][25000] u32 (alias: dead before aggP)
#define OFF_HS       6057216u     // [3][N] f32
#define OFF_OUTP     6207216u     // [3][N] f32
#define OFF_PAIRS    6357216u     // Etot u32 packed (dst<<16 | src)
#define OFF_SRCSORT  10557216u    // Etot u16
// need = (OFF_SRCSORT + ceil(Etot/2)) * 4  ~= 50.6 MB

__global__ void k_zero_u32(unsigned* __restrict__ p, int n) {
    int i = blockIdx.x * 256 + threadIdx.x;
    if (i < n) p[i] = 0u;
}

// packed src histogram: bins[n>>1] += (n&1) ? 1<<16 : 1
__global__ __launch_bounds__(256) void k_srcHist(const int* s0, const int* s1, const int* s2,
                                                 int E0, int E1, int E2,
                                                 unsigned* __restrict__ histP) {
    __shared__ unsigned bins[25000];
    int c = blockIdx.x, r = blockIdx.y;
    const int* arr = (r == 0) ? s0 : (r == 1) ? s1 : s2;
    int E = (r == 0) ? E0 : (r == 1) ? E1 : E2;
    for (int i = threadIdx.x; i < 25000; i += 256) bins[i] = 0u;
    __syncthreads();
    int chunk = (E + NCH - 1) / NCH;
    int a0 = c * chunk, a1 = min(a0 + chunk, E);
    for (int i = a0 + threadIdx.x; i < a1; i += 256) {
        unsigned v = (unsigned)arr[i];
        atomicAdd(&bins[v >> 1], (v & 1u) ? 65536u : 1u);
    }
    __syncthreads();
    unsigned* out = histP + ((size_t)r * NCH + c) * 25000;
    for (int i = threadIdx.x; i < 25000; i += 256) out[i] = bins[i];
}

__global__ void k_degreduceOut(const unsigned* __restrict__ histP, float* __restrict__ invOut) {
    int n = blockIdx.x * 256 + threadIdx.x;
    int r = blockIdx.y;
    if (n >= N_NODES) return;
    const unsigned* p = histP + (size_t)r * NCH * 25000 + (n >> 1);
    unsigned s = 0;
#pragma unroll
    for (int c = 0; c < NCH; c++) {
        unsigned w = p[(size_t)c * 25000];
        s += (n & 1) ? (w >> 16) : (w & 0xFFFFu);
    }
    invOut[r * N_NODES + n] = rsqrtf((float)(s ? s : 1u));
}

// per-(relation,bucket) dst counts
__global__ __launch_bounds__(256) void k_bukCount(const int* d0p, const int* d1p, const int* d2p,
                                                  int E0, int E1, int E2,
                                                  unsigned* __restrict__ bukCnt) {
    __shared__ unsigned bins[NBUK];
    int c = blockIdx.x, r = blockIdx.y;
    const int* arr = (r == 0) ? d0p : (r == 1) ? d1p : d2p;
    int E = (r == 0) ? E0 : (r == 1) ? E1 : E2;
    for (int i = threadIdx.x; i < NBUK; i += 256) bins[i] = 0u;
    __syncthreads();
    int nb = gridDim.x;
    int chunk = (E + nb - 1) / nb;
    int a0 = c * chunk, a1 = min(a0 + chunk, E);
    for (int i = a0 + threadIdx.x; i < a1; i += 256)
        atomicAdd(&bins[((unsigned)arr[i]) >> BSHIFT], 1u);
    __syncthreads();
    for (int b = threadIdx.x; b < NBUK; b += 256)
        if (bins[b]) atomicAdd(&bukCnt[r * BSTRIDE + b], bins[b]);
}

__global__ void k_bucketScan(const unsigned* __restrict__ bukCnt, unsigned* __restrict__ bstart,
                             unsigned* __restrict__ gcur) {
    int r = blockIdx.x;
    if (threadIdx.x == 0) {
        unsigned acc = 0;
        for (int b = 0; b < NBUK; b++) { bstart[r * BSTRIDE + b] = acc; acc += bukCnt[r * BSTRIDE + b]; }
        bstart[r * BSTRIDE + NBUK] = acc;
    }
    __syncthreads();
    for (int i = threadIdx.x; i <= NBUK; i += 256) gcur[r * BSTRIDE + i] = bstart[r * BSTRIDE + i];
}

// bucket-scatter with in-LDS tile reorder. pair = (dst<<16)|src.
__global__ __launch_bounds__(256) void k_passB(
    const int* s0p, const int* s1p, const int* s2p,
    const int* d0p, const int* d1p, const int* d2p,
    int E0, int E1, int E2, int po0, int po1, int po2,
    unsigned* __restrict__ pairsAll, unsigned* __restrict__ gcurAll) {
    __shared__ unsigned cnt[NBUK];
    __shared__ unsigned off[NBUK];
    __shared__ unsigned gbase[NBUK];
    __shared__ unsigned spair[TILE];
    __shared__ unsigned saddr[TILE];
    int r = blockIdx.z;
    const int* src = (r == 0) ? s0p : (r == 1) ? s1p : s2p;
    const int* dst = (r == 0) ? d0p : (r == 1) ? d1p : d2p;
    int E = (r == 0) ? E0 : (r == 1) ? E1 : E2;
    unsigned* pairs = pairsAll + ((r == 0) ? po0 : (r == 1) ? po1 : po2);
    unsigned* gcur = gcurAll + r * BSTRIDE;
    int nb = gridDim.x;
    int chunk = (E + nb - 1) / nb;
    int c0 = blockIdx.x * chunk;
    int c1 = min(c0 + chunk, E);
    for (int t0 = c0; t0 < c1; t0 += TILE) {
        int tn = min(TILE, c1 - t0);
        for (int i = threadIdx.x; i < NBUK; i += 256) cnt[i] = 0u;
        __syncthreads();
        unsigned pk[16], bk[16], sl[16];
#pragma unroll
        for (int k = 0; k < 16; k++) {
            int ii = k * 256 + (int)threadIdx.x;
            bk[k] = 0xFFFFFFFFu;
            if (ii < tn) {
                int i = t0 + ii;
                unsigned s = (unsigned)src[i], d = (unsigned)dst[i];
                pk[k] = (d << 16) | s;
                unsigned b = d >> BSHIFT;
                bk[k] = b;
                sl[k] = atomicAdd(&cnt[b], 1u);
            }
        }
        __syncthreads();
        if (threadIdx.x == 0) {
            unsigned acc = 0;
            for (int b = 0; b < NBUK; b++) { unsigned t = cnt[b]; off[b] = acc; acc += t; }
        }
        __syncthreads();
        for (int b = threadIdx.x; b < NBUK; b += 256) {
            unsigned c = cnt[b];
            if (c) gbase[b] = atomicAdd(&gcur[b], c);
        }
        __syncthreads();
#pragma unroll
        for (int k = 0; k < 16; k++) {
            if (bk[k] != 0xFFFFFFFFu) {
                unsigned idx = off[bk[k]] + sl[k];
                spair[idx] = pk[k];
                saddr[idx] = gbase[bk[k]] + sl[k];
            }
        }
        __syncthreads();
#pragma unroll
        for (int k = 0; k < 16; k++) {
            int ii = k * 256 + (int)threadIdx.x;
            if (ii < tn) pairs[saddr[ii]] = spair[ii];
        }
        __syncthreads();
    }
}

// h_r[n][j] = (x[n,:] . W1[r][:,j]) * invOut_r[n]
__global__ __launch_bounds__(256) void k_h1(const float* __restrict__ x, const float* __restrict__ invOut,
                                            const float* __restrict__ W1, float* __restrict__ hproj) {
    __shared__ float sW[32 * FH];
    __shared__ float sx[16][32];
    int r = blockIdx.y;
    const float* W = W1 + r * 32 * FH;
    int t = threadIdx.x;
    for (int i = t; i < 32 * FH; i += 256) sW[i] = W[i];
    int n0 = blockIdx.x * 16;
    for (int i = t; i < 16 * 32; i += 256) {
        int nn = i >> 5, kk = i & 31;
        int n = n0 + nn;
        sx[nn][kk] = (n < N_NODES) ? x[n * 32 + kk] : 0.0f;
    }
    __syncthreads();
    int nn = t >> 4, j = t & 15;
    int n = n0 + nn;
    if (n < N_NODES) {
        float s = 0.f;
#pragma unroll
        for (int k = 0; k < 32; k++) s += sx[nn][k] * sW[k * FH + j];
        hproj[((size_t)r * N_NODES + n) * FH + j] = s * invOut[r * N_NODES + n];
    }
}

// layer-1 per-bucket: LDS counting sort by dst -> segmented float4 register accumulation.
// Writes aggP slab (scaled by invIn), invIn, rowptr (absolute), srcSorted (persisted).
__global__ __launch_bounds__(256) void k_passC1(
    const unsigned* __restrict__ pairs, const unsigned* __restrict__ bstart,
    const float4* __restrict__ h4, float4* __restrict__ out4,
    unsigned short* __restrict__ srcG, unsigned* __restrict__ rowptr,
    float* __restrict__ invIn, int po, int cap) {
    extern __shared__ unsigned sm[];
    unsigned* cnt = sm;                                   // 64
    unsigned* off = sm + 64;                              // 65
    unsigned* cur = sm + 129;                             // 64
    unsigned short* srcS = (unsigned short*)(sm + 194);   // cap u16
    int b = blockIdx.x, t = threadIdx.x;
    unsigned e0 = bstart[b], e1 = bstart[b + 1];
    if (e1 - e0 > (unsigned)cap) e1 = e0 + (unsigned)cap;   // statistically impossible
    int d0 = b << BSHIFT;
    if (t < 64) cnt[t] = 0u;
    __syncthreads();
    // 1) histogram (exact deg_in per node)
    for (unsigned i = e0 + t; i < e1; i += 256)
        atomicAdd(&cnt[(pairs[i] >> 16) - (unsigned)d0], 1u);
    __syncthreads();
    // 2) scan
    if (t == 0) {
        unsigned acc = 0;
        for (int d = 0; d < 64; d++) { off[d] = acc; acc += cnt[d]; }
        off[64] = acc;
    }
    __syncthreads();
    if (t < 64) {
        cur[t] = off[t];
        int n = d0 + t;
        if (n < N_NODES) {
            rowptr[n] = (unsigned)po + e0 + off[t];
            unsigned dg = cnt[t];
            invIn[n] = rsqrtf((float)(dg ? dg : 1u));
        }
    }
    if (b == NBUK - 1 && t == 0) rowptr[N_NODES] = (unsigned)po + e1;
    __syncthreads();
    // 3) scatter src (u16) sorted by dst
    for (unsigned i = e0 + t; i < e1; i += 256) {
        unsigned p = pairs[i];
        unsigned d = (p >> 16) - (unsigned)d0;
        unsigned pos = atomicAdd(&cur[d], 1u);
        srcS[pos] = (unsigned short)(p & 0xFFFFu);
    }
    __syncthreads();
    // 3b) persist sorted src list for layer-2 (THE R4 BUG: this write was missing)
    {
        unsigned len = e1 - e0;
        for (unsigned i = t; i < len; i += 256) srcG[e0 + i] = srcS[i];
    }
    // 4) segmented aggregation: 16-lane unit, 4 lanes/edge, float4 gathers, register acc
    int unit = t >> 4, p = t & 15, k = p >> 2, fq = p & 3;
    for (int nd = unit; nd < 64; nd += 16) {
        unsigned o0 = off[nd], o1 = off[nd + 1];
        float ax = 0.f, ay = 0.f, az = 0.f, aw = 0.f;
        unsigned base = o0;
        for (; base + 8 <= o1; base += 8) {
            int s0 = srcS[base + k], s1 = srcS[base + 4 + k];
            float4 v0 = h4[(size_t)s0 * 4 + fq];
            float4 v1 = h4[(size_t)s1 * 4 + fq];
            ax += v0.x + v1.x; ay += v0.y + v1.y; az += v0.z + v1.z; aw += v0.w + v1.w;
        }
        for (; base < o1; base += 4) {
            unsigned idx = base + (unsigned)k;
            if (idx < o1) {
                int s = srcS[idx];
                float4 v = h4[(size_t)s * 4 + fq];
                ax += v.x; ay += v.y; az += v.z; aw += v.w;
            }
        }
        ax += __shfl_xor(ax, 4, 16); ay += __shfl_xor(ay, 4, 16);
        az += __shfl_xor(az, 4, 16); aw += __shfl_xor(aw, 4, 16);
        ax += __shfl_xor(ax, 8, 16); ay += __shfl_xor(ay, 8, 16);
        az += __shfl_xor(az, 8, 16); aw += __shfl_xor(aw, 8, 16);
        int n = d0 + nd;
        if (k == 0 && n < N_NODES) {
            unsigned dg = o1 - o0;
            float sc = rsqrtf((float)(dg ? dg : 1u));
            float4 res; res.x = ax * sc; res.y = ay * sc; res.z = az * sc; res.w = aw * sc;
            out4[(size_t)n * 4 + fq] = res;
        }
    }
}

__global__ void k_relu(const float* __restrict__ aggP, const float* __restrict__ b1,
                       float* __restrict__ hout) {
    int i = blockIdx.x * 256 + threadIdx.x;
    if (i >= N_NODES * FH) return;
    int j = i & 15;
    const size_t SL = (size_t)N_NODES * FH;
    float v = aggP[i] + aggP[SL + i] + aggP[2 * SL + i]
            + b1[j] + b1[FH + j] + b1[2 * FH + j];
    hout[i] = fmaxf(v, 0.f);
}

__global__ void k_h2(const float* __restrict__ hout, const float* __restrict__ invOut,
                     const float* __restrict__ W2, float* __restrict__ hs) {
    int n = blockIdx.x * 256 + threadIdx.x;
    int r = blockIdx.y;
    if (n >= N_NODES) return;
    const float4* hp = (const float4*)(hout + (size_t)n * FH);
    const float* w = W2 + r * FH;
    float s = 0.f;
#pragma unroll
    for (int q = 0; q < 4; q++) {
        float4 hv = hp[q];
        s += hv.x * w[q * 4 + 0] + hv.y * w[q * 4 + 1] + hv.z * w[q * 4 + 2] + hv.w * w[q * 4 + 3];
    }
    hs[r * N_NODES + n] = s * invOut[r * N_NODES + n];
}

// layer-2: segmented sum over sorted src lists; one 16-lane unit per (r, node).
__global__ __launch_bounds__(256) void k_passC2(
    const unsigned short* __restrict__ srcG, const unsigned* __restrict__ rowptr,
    const float* __restrict__ hsAll, const float* __restrict__ invIn,
    float* __restrict__ outP) {
    int t = threadIdx.x;
    int unit = t >> 4, p = t & 15;
    int gid = blockIdx.x * 16 + unit;
    if (gid >= 3 * N_NODES) return;
    int r = gid / N_NODES;
    int n = gid - r * N_NODES;
    unsigned o0 = rowptr[r * (N_NODES + 1) + n];
    unsigned o1 = rowptr[r * (N_NODES + 1) + n + 1];
    const float* hs = hsAll + (size_t)r * N_NODES;
    float s = 0.f;
    for (unsigned i = o0 + (unsigned)p; i < o1; i += 16) s += hs[srcG[i]];
    s += __shfl_xor(s, 1, 16); s += __shfl_xor(s, 2, 16);
    s += __shfl_xor(s, 4, 16); s += __shfl_xor(s, 8, 16);
    if (p == 0) outP[(size_t)r * N_NODES + n] = s * invIn[r * N_NODES + n];
}

__global__ void k_final(const float* __restrict__ outP, const float* __restrict__ b2,
                        float* __restrict__ out) {
    int n = blockIdx.x * 256 + threadIdx.x;
    if (n >= N_NODES) return;
    out[n] = outP[n] + outP[N_NODES + n] + outP[2 * (size_t)N_NODES + n]
           + b2[0] + b2[1] + b2[2];
}

// =============== fallback (round-1) kernels ===============

__global__ void f_zero(float* __restrict__ p, int n) {
    int i = blockIdx.x * blockDim.x + threadIdx.x;
    if (i < n) p[i] = 0.0f;
}
__global__ void f_deg(const int* __restrict__ src, const int* __restrict__ dst, int E,
                      float* __restrict__ dout, float* __restrict__ din) {
    int i = blockIdx.x * blockDim.x + threadIdx.x;
    if (i < E) { atomicAdd(&dout[src[i]], 1.0f); atomicAdd(&din[dst[i]], 1.0f); }
}
__global__ void f_rsqrt(float* __restrict__ p, int n) {
    int i = blockIdx.x * blockDim.x + threadIdx.x;
    if (i < n) p[i] = rsqrtf(fmaxf(p[i], 1.0f));
}
__global__ void f_agg1(const int* __restrict__ src, const int* __restrict__ dst, int E,
                       const float* __restrict__ h, const float* __restrict__ invin,
                       float* __restrict__ agg) {
    int idx = blockIdx.x * blockDim.x + threadIdx.x;
    if (idx < E * FH) {
        int e = idx >> 4, j = idx & 15;
        atomicAdd(&agg[dst[e] * FH + j], h[src[e] * FH + j] * invin[dst[e]]);
    }
}
__global__ void f_relu(float* __restrict__ agg, const float* __restrict__ b1) {
    int i = blockIdx.x * blockDim.x + threadIdx.x;
    if (i < N_NODES * FH) {
        int j = i & 15;
        agg[i] = fmaxf(agg[i] + b1[j] + b1[FH + j] + b1[2 * FH + j], 0.0f);
    }
}
__global__ void f_outinit(float* __restrict__ out, const float* __restrict__ b2) {
    int i = blockIdx.x * blockDim.x + threadIdx.x;
    if (i < N_NODES) out[i] = b2[0] + b2[1] + b2[2];
}
__global__ void f_h2(const float* __restrict__ h1, const float* __restrict__ invout,
                     const float* __restrict__ W2r, float* __restrict__ hsv) {
    int n = blockIdx.x * blockDim.x + threadIdx.x;
    if (n < N_NODES) {
        const float4* hp = (const float4*)(h1 + (size_t)n * FH);
        float s = 0.0f;
#pragma unroll
        for (int q = 0; q < 4; q++) {
            float4 hv = hp[q];
            s += hv.x * W2r[q * 4] + hv.y * W2r[q * 4 + 1] + hv.z * W2r[q * 4 + 2] + hv.w * W2r[q * 4 + 3];
        }
        hsv[n] = s * invout[n];
    }
}
__global__ void f_agg2(const int* __restrict__ src, const int* __restrict__ dst, int E,
                       const float* __restrict__ hsv, const float* __restrict__ invin,
                       float* __restrict__ out) {
    int e = blockIdx.x * blockDim.x + threadIdx.x;
    if (e < E) atomicAdd(&out[dst[e]], hsv[src[e]] * invin[dst[e]]);
}

// =============== host ===============

extern "C" void kernel_launch(void* const* d_in, const int* in_sizes, int n_in,
                              void* d_out, int out_size, void* d_ws, size_t ws_size,
                              hipStream_t stream) {
    const float* x = (const float*)d_in[0];
    const int* srcs[3] = { (const int*)d_in[1], (const int*)d_in[3], (const int*)d_in[5] };
    const int* dsts[3] = { (const int*)d_in[2], (const int*)d_in[4], (const int*)d_in[6] };
    int E[3] = { in_sizes[1], in_sizes[3], in_sizes[5] };
    const float* W1 = (const float*)d_in[7];
    const float* b1 = (const float*)d_in[8];
    const float* W2 = (const float*)d_in[9];
    const float* b2 = (const float*)d_in[10];
    float* out = (float*)d_out;
    const int N = N_NODES;
    const int B = 256;
    size_t Etot = (size_t)E[0] + E[1] + E[2];
    size_t need = ((size_t)OFF_SRCSORT + (Etot + 1) / 2) * 4u;

    if (ws_size >= need) {
        unsigned* ws = (unsigned*)d_ws;
        float* invOut = (float*)(ws + OFF_INVOUT);
        float* invIn  = (float*)(ws + OFF_INVIN);
        unsigned* bukCnt = ws + OFF_BUKCNT;
        unsigned* bstart = ws + OFF_BSTART;
        unsigned* gcur   = ws + OFF_GCUR;
        unsigned* rowptr = ws + OFF_ROWPTR;
        float* hproj = (float*)(ws + OFF_HPROJ);
        float* hout  = (float*)(ws + OFF_HOUT);
        float* aggP  = (float*)(ws + OFF_AGGP);
        unsigned* srcHist = ws + OFF_SRCHIST;
        float* hs    = (float*)(ws + OFF_HS);
        float* outP  = (float*)(ws + OFF_OUTP);
        unsigned* pairs = ws + OFF_PAIRS;
        unsigned short* srcSort = (unsigned short*)(ws + OFF_SRCSORT);
        int po[3] = { 0, E[0], E[0] + E[1] };
        int cap[3] = { 4608, 1792, 768 };   // ~12-30 sigma above Poisson bucket means

        k_zero_u32<<<(3 * BSTRIDE + B - 1) / B, B, 0, stream>>>(bukCnt, 3 * BSTRIDE);
        k_srcHist<<<dim3(NCH, 3), B, 0, stream>>>(srcs[0], srcs[1], srcs[2], E[0], E[1], E[2], srcHist);
        k_degreduceOut<<<dim3((N + B - 1) / B, 3), B, 0, stream>>>(srcHist, invOut);
        k_bukCount<<<dim3(64, 3), B, 0, stream>>>(dsts[0], dsts[1], dsts[2], E[0], E[1], E[2], bukCnt);
        k_bucketScan<<<3, B, 0, stream>>>(bukCnt, bstart, gcur);
        k_passB<<<dim3(256, 1, 3), B, 0, stream>>>(
            srcs[0], srcs[1], srcs[2], dsts[0], dsts[1], dsts[2],
            E[0], E[1], E[2], po[0], po[1], po[2], pairs, gcur);
        k_h1<<<dim3((N + 15) / 16, 3), B, 0, stream>>>(x, invOut, W1, hproj);
        for (int r = 0; r < 3; r++) {
            size_t shb = 194 * 4 + (size_t)cap[r] * 2 + 8;
            k_passC1<<<NBUK, B, shb, stream>>>(
                pairs + po[r], bstart + r * BSTRIDE,
                (const float4*)(hproj + (size_t)r * N * FH),
                (float4*)(aggP + (size_t)r * N * FH),
                srcSort + po[r], rowptr + (size_t)r * (N + 1),
                invIn + (size_t)r * N, po[r], cap[r]);
        }
        k_relu<<<(N * FH + B - 1) / B, B, 0, stream>>>(aggP, b1, hout);
        k_h2<<<dim3((N + B - 1) / B, 3), B, 0, stream>>>(hout, invOut, W2, hs);
        k_passC2<<<(3 * N + 15) / 16, B, 0, stream>>>(srcSort, rowptr, hs, invIn, outP);
        k_final<<<(N + B - 1) / B, B, 0, stream>>>(outP, b2, out);
    } else {
        // fallback: round-1 atomic path
        float* wsf = (float*)d_ws;
        float* invOut = wsf;
        float* invIn = wsf + 3 * (size_t)N;
        float* h = wsf + 6 * (size_t)N;
        float* agg = wsf + 22 * (size_t)N;
        float* hsv = wsf + 38 * (size_t)N;
        f_zero<<<(6 * N + B - 1) / B, B, 0, stream>>>(invOut, 6 * N);
        f_zero<<<(16 * N + B - 1) / B, B, 0, stream>>>(agg, 16 * N);
        for (int r = 0; r < 3; r++)
            f_deg<<<(E[r] + B - 1) / B, B, 0, stream>>>(srcs[r], dsts[r], E[r],
                                                        invOut + (size_t)r * N, invIn + (size_t)r * N);
        f_rsqrt<<<(6 * N + B - 1) / B, B, 0, stream>>>(invOut, 6 * N);
        for (int r = 0; r < 3; r++) {
            k_h1<<<dim3((N + 15) / 16, 1), B, 0, stream>>>(x, invOut + (size_t)r * N,
                                                           W1 + (size_t)r * 32 * FH, h);
            f_agg1<<<(E[r] * FH + B - 1) / B, B, 0, stream>>>(srcs[r], dsts[r], E[r], h,
                                                              invIn + (size_t)r * N, agg);
        }
        f_relu<<<(N * FH + B - 1) / B, B, 0, stream>>>(agg, b1);
        f_outinit<<<(N + B - 1) / B, B, 0, stream>>>(out, b2);
        for (int r = 0; r < 3; r++) {
            f_h2<<<(N + B - 1) / B, B, 0, stream>>>(agg, invOut + (size_t)r * N,
                                                    W2 + (size_t)r * FH, hsv);
            f_agg2<<<(E[r] + B - 1) / B, B, 0, stream>>>(srcs[r], dsts[r], E[r], hsv,
                                                         invIn + (size_t)r * N, out);
        }
    }
}

// Round 8
// 294.543 us; speedup vs baseline: 3.4644x; 2.2816x over previous
//
#include <hip/hip_runtime.h>

#define N_NODES 50000
#define FH 16
#define NBUK 782          // 64-node buckets: bucket = dst >> 6
#define BSHIFT 6
#define BSTRIDE 800
#define TILE 4096
#define NCH2 32           // src-deg chunks
#define NRNG 4            // src-deg node ranges
#define RNGSZ 12500       // nodes per range (even)

// ---- ws layout (u32 words) ----
#define OFF_INVOUT   0u           // [3][N] f32
#define OFF_INVIN    150000u      // [3][N] f32
#define OFF_BUKCNT   300000u      // [3][800]
#define OFF_BSTART   302400u      // [3][800]
#define OFF_GCUR     304800u      // [3][800]
#define OFF_ROWPTR   307200u      // [3][N+1] u32 (absolute into srcSorted)
#define OFF_HPROJ    457216u      // [3][N][16] f32
#define OFF_HOUT     2857216u     // [N][16] f32
#define OFF_AGGP     3657216u     // [3][N][16] f32 (scaled by invIn already)
#define OFF_SRCHIST  3657216u     // [3][32][25000] u32 = 2.4M words (alias: dead before aggP)
#define OFF_HS       6057216u     // [3][N] f32
#define OFF_OUTP     6207216u     // [3][N] f32
#define OFF_PAIRS    6357216u     // Etot u32 packed (dst<<16 | src)
#define OFF_SRCSORT  10557216u    // Etot u16
// need = (OFF_SRCSORT + ceil(Etot/2)) * 4  ~= 50.6 MB

__global__ void k_zero_u32(unsigned* __restrict__ p, int n) {
    int i = blockIdx.x * 256 + threadIdx.x;
    if (i < n) p[i] = 0u;
}

// src degree histogram: (chunk, range, rel) decomposition, packed u16 bins, int4 loads.
__global__ __launch_bounds__(256) void k_srcDeg(const int* s0, const int* s1, const int* s2,
                                                int E0, int E1, int E2,
                                                unsigned* __restrict__ histP) {
    __shared__ unsigned bins[RNGSZ / 2];
    int c = blockIdx.x, rg = blockIdx.y, r = blockIdx.z;
    const int* arr = (r == 0) ? s0 : (r == 1) ? s1 : s2;
    int E = (r == 0) ? E0 : (r == 1) ? E1 : E2;
    for (int i = threadIdx.x; i < RNGSZ / 2; i += 256) bins[i] = 0u;
    __syncthreads();
    int lo = rg * RNGSZ;
    int per = (((E + NCH2 - 1) / NCH2) + 3) & ~3;
    int a0 = c * per, a1 = min(a0 + per, E);
    for (int i = a0 + (int)threadIdx.x * 4; i < a1; i += 1024) {
        if (i + 4 <= a1) {
            int4 v = *reinterpret_cast<const int4*>(arr + i);
            unsigned d0 = (unsigned)(v.x - lo), d1 = (unsigned)(v.y - lo);
            unsigned d2 = (unsigned)(v.z - lo), d3 = (unsigned)(v.w - lo);
            if (d0 < (unsigned)RNGSZ) atomicAdd(&bins[d0 >> 1], (d0 & 1u) ? 65536u : 1u);
            if (d1 < (unsigned)RNGSZ) atomicAdd(&bins[d1 >> 1], (d1 & 1u) ? 65536u : 1u);
            if (d2 < (unsigned)RNGSZ) atomicAdd(&bins[d2 >> 1], (d2 & 1u) ? 65536u : 1u);
            if (d3 < (unsigned)RNGSZ) atomicAdd(&bins[d3 >> 1], (d3 & 1u) ? 65536u : 1u);
        } else {
            for (int k2 = i; k2 < a1; k2++) {
                unsigned d = (unsigned)(arr[k2] - lo);
                if (d < (unsigned)RNGSZ) atomicAdd(&bins[d >> 1], (d & 1u) ? 65536u : 1u);
            }
        }
    }
    __syncthreads();
    unsigned* out = histP + ((size_t)r * NCH2 + c) * 25000 + rg * (RNGSZ / 2);
    for (int i = threadIdx.x; i < RNGSZ / 2; i += 256) out[i] = bins[i];
}

__global__ void k_degreduceOut(const unsigned* __restrict__ histP, float* __restrict__ invOut) {
    int n = blockIdx.x * 256 + threadIdx.x;
    int r = blockIdx.y;
    if (n >= N_NODES) return;
    const unsigned* p = histP + (size_t)r * NCH2 * 25000 + (n >> 1);
    unsigned s = 0;
#pragma unroll
    for (int c = 0; c < NCH2; c++) {
        unsigned w = p[(size_t)c * 25000];
        s += (n & 1) ? (w >> 16) : (w & 0xFFFFu);
    }
    invOut[r * N_NODES + n] = rsqrtf((float)(s ? s : 1u));
}

// per-(relation,bucket) dst counts, int4 loads
__global__ __launch_bounds__(256) void k_bukCount(const int* d0p, const int* d1p, const int* d2p,
                                                  int E0, int E1, int E2,
                                                  unsigned* __restrict__ bukCnt) {
    __shared__ unsigned bins[NBUK];
    int c = blockIdx.x, r = blockIdx.y;
    const int* arr = (r == 0) ? d0p : (r == 1) ? d1p : d2p;
    int E = (r == 0) ? E0 : (r == 1) ? E1 : E2;
    for (int i = threadIdx.x; i < NBUK; i += 256) bins[i] = 0u;
    __syncthreads();
    int nb = gridDim.x;
    int per = (((E + nb - 1) / nb) + 3) & ~3;
    int a0 = c * per, a1 = min(a0 + per, E);
    for (int i = a0 + (int)threadIdx.x * 4; i < a1; i += 1024) {
        if (i + 4 <= a1) {
            int4 v = *reinterpret_cast<const int4*>(arr + i);
            atomicAdd(&bins[((unsigned)v.x) >> BSHIFT], 1u);
            atomicAdd(&bins[((unsigned)v.y) >> BSHIFT], 1u);
            atomicAdd(&bins[((unsigned)v.z) >> BSHIFT], 1u);
            atomicAdd(&bins[((unsigned)v.w) >> BSHIFT], 1u);
        } else {
            for (int k2 = i; k2 < a1; k2++)
                atomicAdd(&bins[((unsigned)arr[k2]) >> BSHIFT], 1u);
        }
    }
    __syncthreads();
    for (int b = threadIdx.x; b < NBUK; b += 256)
        if (bins[b]) atomicAdd(&bukCnt[r * BSTRIDE + b], bins[b]);
}

// parallel exclusive scan of bucket counts (256 threads x 4 bins, Hillis-Steele)
__global__ __launch_bounds__(256) void k_bucketScan(const unsigned* __restrict__ bukCnt,
                                                    unsigned* __restrict__ bstart,
                                                    unsigned* __restrict__ gcur) {
    __shared__ unsigned part[256];
    int r = blockIdx.x, t = threadIdx.x;
    unsigned loc[4]; unsigned s = 0;
#pragma unroll
    for (int k = 0; k < 4; k++) {
        int idx = 4 * t + k;
        loc[k] = (idx < NBUK) ? bukCnt[r * BSTRIDE + idx] : 0u;
        s += loc[k];
    }
    part[t] = s;
    __syncthreads();
    for (int d = 1; d < 256; d <<= 1) {
        unsigned v = (t >= d) ? part[t - d] : 0u;
        __syncthreads();
        part[t] += v;
        __syncthreads();
    }
    unsigned run = part[t] - s;  // exclusive prefix
#pragma unroll
    for (int k = 0; k < 4; k++) {
        int idx = 4 * t + k;
        if (idx <= NBUK) { bstart[r * BSTRIDE + idx] = run; gcur[r * BSTRIDE + idx] = run; }
        run += loc[k];
    }
}

// bucket-scatter with in-LDS tile reorder. pair = (dst<<16)|src.
__global__ __launch_bounds__(256) void k_passB(
    const int* s0p, const int* s1p, const int* s2p,
    const int* d0p, const int* d1p, const int* d2p,
    int E0, int E1, int E2, int po0, int po1, int po2,
    unsigned* __restrict__ pairsAll, unsigned* __restrict__ gcurAll) {
    __shared__ unsigned cnt[NBUK];
    __shared__ unsigned off[NBUK];
    __shared__ unsigned gbase[NBUK];
    __shared__ unsigned part[256];
    __shared__ unsigned spair[TILE];
    __shared__ unsigned saddr[TILE];
    int r = blockIdx.z;
    const int* src = (r == 0) ? s0p : (r == 1) ? s1p : s2p;
    const int* dst = (r == 0) ? d0p : (r == 1) ? d1p : d2p;
    int E = (r == 0) ? E0 : (r == 1) ? E1 : E2;
    unsigned* pairs = pairsAll + ((r == 0) ? po0 : (r == 1) ? po1 : po2);
    unsigned* gcur = gcurAll + r * BSTRIDE;
    int nb = gridDim.x;
    int chunk = (E + nb - 1) / nb;
    int c0 = blockIdx.x * chunk;
    int c1 = min(c0 + chunk, E);
    for (int t0 = c0; t0 < c1; t0 += TILE) {
        int tn = min(TILE, c1 - t0);
        for (int i = threadIdx.x; i < NBUK; i += 256) cnt[i] = 0u;
        __syncthreads();
        unsigned pk[16], bk[16], sl[16];
#pragma unroll
        for (int k = 0; k < 16; k++) {
            int ii = k * 256 + (int)threadIdx.x;
            bk[k] = 0xFFFFFFFFu;
            if (ii < tn) {
                int i = t0 + ii;
                unsigned s = (unsigned)src[i], d = (unsigned)dst[i];
                pk[k] = (d << 16) | s;
                unsigned b = d >> BSHIFT;
                bk[k] = b;
                sl[k] = atomicAdd(&cnt[b], 1u);
            }
        }
        __syncthreads();
        // parallel exclusive scan cnt -> off
        {
            int t = threadIdx.x;
            unsigned loc[4]; unsigned sloc = 0;
#pragma unroll
            for (int k2 = 0; k2 < 4; k2++) {
                int idx = 4 * t + k2;
                loc[k2] = (idx < NBUK) ? cnt[idx] : 0u;
                sloc += loc[k2];
            }
            part[t] = sloc;
            __syncthreads();
            for (int d = 1; d < 256; d <<= 1) {
                unsigned v = (t >= d) ? part[t - d] : 0u;
                __syncthreads();
                part[t] += v;
                __syncthreads();
            }
            unsigned run = part[t] - sloc;
#pragma unroll
            for (int k2 = 0; k2 < 4; k2++) {
                int idx = 4 * t + k2;
                if (idx < NBUK) off[idx] = run;
                run += loc[k2];
            }
        }
        __syncthreads();
        for (int b = threadIdx.x; b < NBUK; b += 256) {
            unsigned c = cnt[b];
            if (c) gbase[b] = atomicAdd(&gcur[b], c);
        }
        __syncthreads();
#pragma unroll
        for (int k = 0; k < 16; k++) {
            if (bk[k] != 0xFFFFFFFFu) {
                unsigned idx = off[bk[k]] + sl[k];
                spair[idx] = pk[k];
                saddr[idx] = gbase[bk[k]] + sl[k];
            }
        }
        __syncthreads();
#pragma unroll
        for (int k = 0; k < 16; k++) {
            int ii = k * 256 + (int)threadIdx.x;
            if (ii < tn) pairs[saddr[ii]] = spair[ii];
        }
        __syncthreads();
    }
}

// h_r[n][j] = (x[n,:] . W1[r][:,j]) * invOut_r[n]
__global__ __launch_bounds__(256) void k_h1(const float* __restrict__ x, const float* __restrict__ invOut,
                                            const float* __restrict__ W1, float* __restrict__ hproj) {
    __shared__ float sW[32 * FH];
    __shared__ float sx[16][32];
    int r = blockIdx.y;
    const float* W = W1 + r * 32 * FH;
    int t = threadIdx.x;
    for (int i = t; i < 32 * FH; i += 256) sW[i] = W[i];
    int n0 = blockIdx.x * 16;
    for (int i = t; i < 16 * 32; i += 256) {
        int nn = i >> 5, kk = i & 31;
        int n = n0 + nn;
        sx[nn][kk] = (n < N_NODES) ? x[n * 32 + kk] : 0.0f;
    }
    __syncthreads();
    int nn = t >> 4, j = t & 15;
    int n = n0 + nn;
    if (n < N_NODES) {
        float s = 0.f;
#pragma unroll
        for (int k = 0; k < 32; k++) s += sx[nn][k] * sW[k * FH + j];
        hproj[((size_t)r * N_NODES + n) * FH + j] = s * invOut[r * N_NODES + n];
    }
}

// layer-1 per-bucket: LDS counting sort by dst -> segmented float4 register accumulation.
__global__ __launch_bounds__(256) void k_passC1(
    const unsigned* __restrict__ pairs, const unsigned* __restrict__ bstart,
    const float4* __restrict__ h4, float4* __restrict__ out4,
    unsigned short* __restrict__ srcG, unsigned* __restrict__ rowptr,
    float* __restrict__ invIn, int po, int cap) {
    extern __shared__ unsigned sm[];
    unsigned* cnt = sm;                                   // 64
    unsigned* off = sm + 64;                              // 65
    unsigned* cur = sm + 129;                             // 64
    unsigned short* srcS = (unsigned short*)(sm + 194);   // cap u16
    int b = blockIdx.x, t = threadIdx.x;
    unsigned e0 = bstart[b], e1 = bstart[b + 1];
    if (e1 - e0 > (unsigned)cap) e1 = e0 + (unsigned)cap;   // statistically impossible
    int d0 = b << BSHIFT;
    if (t < 64) cnt[t] = 0u;
    __syncthreads();
    // 1) histogram (exact deg_in per node)
    for (unsigned i = e0 + t; i < e1; i += 256)
        atomicAdd(&cnt[(pairs[i] >> 16) - (unsigned)d0], 1u);
    __syncthreads();
    // 2) wave-0 shfl scan over 64 bins
    if (t < 64) {
        unsigned cv = cnt[t];
        unsigned sc = cv;
#pragma unroll
        for (int d = 1; d < 64; d <<= 1) {
            unsigned v = __shfl_up(sc, d, 64);
            if (t >= d) sc += v;
        }
        off[t] = sc - cv;
        if (t == 63) off[64] = sc;
    }
    __syncthreads();
    if (t < 64) {
        cur[t] = off[t];
        int n = d0 + t;
        if (n < N_NODES) {
            rowptr[n] = (unsigned)po + e0 + off[t];
            unsigned dg = cnt[t];
            invIn[n] = rsqrtf((float)(dg ? dg : 1u));
        }
    }
    if (b == NBUK - 1 && t == 0) rowptr[N_NODES] = (unsigned)po + e1;
    __syncthreads();
    // 3) scatter src (u16) sorted by dst
    for (unsigned i = e0 + t; i < e1; i += 256) {
        unsigned p = pairs[i];
        unsigned d = (p >> 16) - (unsigned)d0;
        unsigned pos = atomicAdd(&cur[d], 1u);
        srcS[pos] = (unsigned short)(p & 0xFFFFu);
    }
    __syncthreads();
    // 3b) persist sorted src list for layer-2
    {
        unsigned len = e1 - e0;
        for (unsigned i = t; i < len; i += 256) srcG[e0 + i] = srcS[i];
    }
    // 4) segmented aggregation: 16-lane unit, 4 lanes/edge, float4 gathers, register acc
    int unit = t >> 4, p = t & 15, k = p >> 2, fq = p & 3;
    for (int nd = unit; nd < 64; nd += 16) {
        unsigned o0 = off[nd], o1 = off[nd + 1];
        float ax = 0.f, ay = 0.f, az = 0.f, aw = 0.f;
        unsigned base = o0;
        for (; base + 8 <= o1; base += 8) {
            int s0 = srcS[base + k], s1 = srcS[base + 4 + k];
            float4 v0 = h4[(size_t)s0 * 4 + fq];
            float4 v1 = h4[(size_t)s1 * 4 + fq];
            ax += v0.x + v1.x; ay += v0.y + v1.y; az += v0.z + v1.z; aw += v0.w + v1.w;
        }
        for (; base < o1; base += 4) {
            unsigned idx = base + (unsigned)k;
            if (idx < o1) {
                int s = srcS[idx];
                float4 v = h4[(size_t)s * 4 + fq];
                ax += v.x; ay += v.y; az += v.z; aw += v.w;
            }
        }
        ax += __shfl_xor(ax, 4, 16); ay += __shfl_xor(ay, 4, 16);
        az += __shfl_xor(az, 4, 16); aw += __shfl_xor(aw, 4, 16);
        ax += __shfl_xor(ax, 8, 16); ay += __shfl_xor(ay, 8, 16);
        az += __shfl_xor(az, 8, 16); aw += __shfl_xor(aw, 8, 16);
        int n = d0 + nd;
        if (k == 0 && n < N_NODES) {
            unsigned dg = o1 - o0;
            float sc = rsqrtf((float)(dg ? dg : 1u));
            float4 res; res.x = ax * sc; res.y = ay * sc; res.z = az * sc; res.w = aw * sc;
            out4[(size_t)n * 4 + fq] = res;
        }
    }
}

__global__ void k_relu(const float* __restrict__ aggP, const float* __restrict__ b1,
                       float* __restrict__ hout) {
    int i = blockIdx.x * 256 + threadIdx.x;
    if (i >= N_NODES * FH) return;
    int j = i & 15;
    const size_t SL = (size_t)N_NODES * FH;
    float v = aggP[i] + aggP[SL + i] + aggP[2 * SL + i]
            + b1[j] + b1[FH + j] + b1[2 * FH + j];
    hout[i] = fmaxf(v, 0.f);
}

__global__ void k_h2(const float* __restrict__ hout, const float* __restrict__ invOut,
                     const float* __restrict__ W2, float* __restrict__ hs) {
    int n = blockIdx.x * 256 + threadIdx.x;
    int r = blockIdx.y;
    if (n >= N_NODES) return;
    const float4* hp = (const float4*)(hout + (size_t)n * FH);
    const float* w = W2 + r * FH;
    float s = 0.f;
#pragma unroll
    for (int q = 0; q < 4; q++) {
        float4 hv = hp[q];
        s += hv.x * w[q * 4 + 0] + hv.y * w[q * 4 + 1] + hv.z * w[q * 4 + 2] + hv.w * w[q * 4 + 3];
    }
    hs[r * N_NODES + n] = s * invOut[r * N_NODES + n];
}

// layer-2: segmented sum over sorted src lists; one 16-lane unit per (r, node).
__global__ __launch_bounds__(256) void k_passC2(
    const unsigned short* __restrict__ srcG, const unsigned* __restrict__ rowptr,
    const float* __restrict__ hsAll, const float* __restrict__ invIn,
    float* __restrict__ outP) {
    int t = threadIdx.x;
    int unit = t >> 4, p = t & 15;
    int gid = blockIdx.x * 16 + unit;
    if (gid >= 3 * N_NODES) return;
    int r = gid / N_NODES;
    int n = gid - r * N_NODES;
    unsigned o0 = rowptr[r * (N_NODES + 1) + n];
    unsigned o1 = rowptr[r * (N_NODES + 1) + n + 1];
    const float* hs = hsAll + (size_t)r * N_NODES;
    float s = 0.f;
    for (unsigned i = o0 + (unsigned)p; i < o1; i += 16) s += hs[srcG[i]];
    s += __shfl_xor(s, 1, 16); s += __shfl_xor(s, 2, 16);
    s += __shfl_xor(s, 4, 16); s += __shfl_xor(s, 8, 16);
    if (p == 0) outP[(size_t)r * N_NODES + n] = s * invIn[r * N_NODES + n];
}

__global__ void k_final(const float* __restrict__ outP, const float* __restrict__ b2,
                        float* __restrict__ out) {
    int n = blockIdx.x * 256 + threadIdx.x;
    if (n >= N_NODES) return;
    out[n] = outP[n] + outP[N_NODES + n] + outP[2 * (size_t)N_NODES + n]
           + b2[0] + b2[1] + b2[2];
}

// =============== fallback (round-1) kernels ===============

__global__ void f_zero(float* __restrict__ p, int n) {
    int i = blockIdx.x * blockDim.x + threadIdx.x;
    if (i < n) p[i] = 0.0f;
}
__global__ void f_deg(const int* __restrict__ src, const int* __restrict__ dst, int E,
                      float* __restrict__ dout, float* __restrict__ din) {
    int i = blockIdx.x * blockDim.x + threadIdx.x;
    if (i < E) { atomicAdd(&dout[src[i]], 1.0f); atomicAdd(&din[dst[i]], 1.0f); }
}
__global__ void f_rsqrt(float* __restrict__ p, int n) {
    int i = blockIdx.x * blockDim.x + threadIdx.x;
    if (i < n) p[i] = rsqrtf(fmaxf(p[i], 1.0f));
}
__global__ void f_agg1(const int* __restrict__ src, const int* __restrict__ dst, int E,
                       const float* __restrict__ h, const float* __restrict__ invin,
                       float* __restrict__ agg) {
    int idx = blockIdx.x * blockDim.x + threadIdx.x;
    if (idx < E * FH) {
        int e = idx >> 4, j = idx & 15;
        atomicAdd(&agg[dst[e] * FH + j], h[src[e] * FH + j] * invin[dst[e]]);
    }
}
__global__ void f_relu(float* __restrict__ agg, const float* __restrict__ b1) {
    int i = blockIdx.x * blockDim.x + threadIdx.x;
    if (i < N_NODES * FH) {
        int j = i & 15;
        agg[i] = fmaxf(agg[i] + b1[j] + b1[FH + j] + b1[2 * FH + j], 0.0f);
    }
}
__global__ void f_outinit(float* __restrict__ out, const float* __restrict__ b2) {
    int i = blockIdx.x * blockDim.x + threadIdx.x;
    if (i < N_NODES) out[i] = b2[0] + b2[1] + b2[2];
}
__global__ void f_h2(const float* __restrict__ h1, const float* __restrict__ invout,
                     const float* __restrict__ W2r, float* __restrict__ hsv) {
    int n = blockIdx.x * blockDim.x + threadIdx.x;
    if (n < N_NODES) {
        const float4* hp = (const float4*)(h1 + (size_t)n * FH);
        float s = 0.0f;
#pragma unroll
        for (int q = 0; q < 4; q++) {
            float4 hv = hp[q];
            s += hv.x * W2r[q * 4] + hv.y * W2r[q * 4 + 1] + hv.z * W2r[q * 4 + 2] + hv.w * W2r[q * 4 + 3];
        }
        hsv[n] = s * invout[n];
    }
}
__global__ void f_agg2(const int* __restrict__ src, const int* __restrict__ dst, int E,
                       const float* __restrict__ hsv, const float* __restrict__ invin,
                       float* __restrict__ out) {
    int e = blockIdx.x * blockDim.x + threadIdx.x;
    if (e < E) atomicAdd(&out[dst[e]], hsv[src[e]] * invin[dst[e]]);
}

// =============== host ===============

extern "C" void kernel_launch(void* const* d_in, const int* in_sizes, int n_in,
                              void* d_out, int out_size, void* d_ws, size_t ws_size,
                              hipStream_t stream) {
    const float* x = (const float*)d_in[0];
    const int* srcs[3] = { (const int*)d_in[1], (const int*)d_in[3], (const int*)d_in[5] };
    const int* dsts[3] = { (const int*)d_in[2], (const int*)d_in[4], (const int*)d_in[6] };
    int E[3] = { in_sizes[1], in_sizes[3], in_sizes[5] };
    const float* W1 = (const float*)d_in[7];
    const float* b1 = (const float*)d_in[8];
    const float* W2 = (const float*)d_in[9];
    const float* b2 = (const float*)d_in[10];
    float* out = (float*)d_out;
    const int N = N_NODES;
    const int B = 256;
    size_t Etot = (size_t)E[0] + E[1] + E[2];
    size_t need = ((size_t)OFF_SRCSORT + (Etot + 1) / 2) * 4u;

    if (ws_size >= need) {
        unsigned* ws = (unsigned*)d_ws;
        float* invOut = (float*)(ws + OFF_INVOUT);
        float* invIn  = (float*)(ws + OFF_INVIN);
        unsigned* bukCnt = ws + OFF_BUKCNT;
        unsigned* bstart = ws + OFF_BSTART;
        unsigned* gcur   = ws + OFF_GCUR;
        unsigned* rowptr = ws + OFF_ROWPTR;
        float* hproj = (float*)(ws + OFF_HPROJ);
        float* hout  = (float*)(ws + OFF_HOUT);
        float* aggP  = (float*)(ws + OFF_AGGP);
        unsigned* srcHist = ws + OFF_SRCHIST;
        float* hs    = (float*)(ws + OFF_HS);
        float* outP  = (float*)(ws + OFF_OUTP);
        unsigned* pairs = ws + OFF_PAIRS;
        unsigned short* srcSort = (unsigned short*)(ws + OFF_SRCSORT);
        int po[3] = { 0, E[0], E[0] + E[1] };
        int cap[3] = { 4608, 1792, 768 };   // ~12-30 sigma above Poisson bucket means

        k_zero_u32<<<(3 * BSTRIDE + B - 1) / B, B, 0, stream>>>(bukCnt, 3 * BSTRIDE);
        k_srcDeg<<<dim3(NCH2, NRNG, 3), B, 0, stream>>>(srcs[0], srcs[1], srcs[2],
                                                        E[0], E[1], E[2], srcHist);
        k_degreduceOut<<<dim3((N + B - 1) / B, 3), B, 0, stream>>>(srcHist, invOut);
        k_bukCount<<<dim3(64, 3), B, 0, stream>>>(dsts[0], dsts[1], dsts[2], E[0], E[1], E[2], bukCnt);
        k_bucketScan<<<3, B, 0, stream>>>(bukCnt, bstart, gcur);
        k_passB<<<dim3(256, 1, 3), B, 0, stream>>>(
            srcs[0], srcs[1], srcs[2], dsts[0], dsts[1], dsts[2],
            E[0], E[1], E[2], po[0], po[1], po[2], pairs, gcur);
        k_h1<<<dim3((N + 15) / 16, 3), B, 0, stream>>>(x, invOut, W1, hproj);
        for (int r = 0; r < 3; r++) {
            size_t shb = 194 * 4 + (size_t)cap[r] * 2 + 8;
            k_passC1<<<NBUK, B, shb, stream>>>(
                pairs + po[r], bstart + r * BSTRIDE,
                (const float4*)(hproj + (size_t)r * N * FH),
                (float4*)(aggP + (size_t)r * N * FH),
                srcSort + po[r], rowptr + (size_t)r * (N + 1),
                invIn + (size_t)r * N, po[r], cap[r]);
        }
        k_relu<<<(N * FH + B - 1) / B, B, 0, stream>>>(aggP, b1, hout);
        k_h2<<<dim3((N + B - 1) / B, 3), B, 0, stream>>>(hout, invOut, W2, hs);
        k_passC2<<<(3 * N + 15) / 16, B, 0, stream>>>(srcSort, rowptr, hs, invIn, outP);
        k_final<<<(N + B - 1) / B, B, 0, stream>>>(outP, b2, out);
    } else {
        // fallback: round-1 atomic path
        float* wsf = (float*)d_ws;
        float* invOut = wsf;
        float* invIn = wsf + 3 * (size_t)N;
        float* h = wsf + 6 * (size_t)N;
        float* agg = wsf + 22 * (size_t)N;
        float* hsv = wsf + 38 * (size_t)N;
        f_zero<<<(6 * N + B - 1) / B, B, 0, stream>>>(invOut, 6 * N);
        f_zero<<<(16 * N + B - 1) / B, B, 0, stream>>>(agg, 16 * N);
        for (int r = 0; r < 3; r++)
            f_deg<<<(E[r] + B - 1) / B, B, 0, stream>>>(srcs[r], dsts[r], E[r],
                                                        invOut + (size_t)r * N, invIn + (size_t)r * N);
        f_rsqrt<<<(6 * N + B - 1) / B, B, 0, stream>>>(invOut, 6 * N);
        for (int r = 0; r < 3; r++) {
            k_h1<<<dim3((N + 15) / 16, 1), B, 0, stream>>>(x, invOut + (size_t)r * N,
                                                           W1 + (size_t)r * 32 * FH, h);
            f_agg1<<<(E[r] * FH + B - 1) / B, B, 0, stream>>>(srcs[r], dsts[r], E[r], h,
                                                              invIn + (size_t)r * N, agg);
        }
        f_relu<<<(N * FH + B - 1) / B, B, 0, stream>>>(agg, b1);
        f_outinit<<<(N + B - 1) / B, B, 0, stream>>>(out, b2);
        for (int r = 0; r < 3; r++) {
            f_h2<<<(N + B - 1) / B, B, 0, stream>>>(agg, invOut + (size_t)r * N,
                                                    W2 + (size_t)r * FH, hsv);
            f_agg2<<<(E[r] + B - 1) / B, B, 0, stream>>>(srcs[r], dsts[r], E[r], hsv,
                                                         invIn + (size_t)r * N, out);
        }
    }
}

// Round 9
// 279.042 us; speedup vs baseline: 3.6569x; 1.0556x over previous
//
#include <hip/hip_runtime.h>

#define N_NODES 50000
#define FH 16
#define NBUK 782          // 64-node buckets: bucket = dst >> 6
#define BSHIFT 6
#define BSTRIDE 800
#define TILE 4096
#define NCH2 32           // src-deg chunks
#define NRNG 8            // src-deg node ranges
#define RNGSZ 6250        // nodes per range (even)
#define C1CAP 4608        // passC1 max bucket size (u16 LDS)

// ---- ws layout (u32 words) ----
#define OFF_INVOUT   0u           // [3][N] f32
#define OFF_INVIN    150000u      // [3][N] f32
#define OFF_BUKCNT   300000u      // [3][800]
#define OFF_BSTART   302400u      // [3][800]
#define OFF_GCUR     304800u      // [3][800]
#define OFF_ROWPTR   307200u      // [3][N+1] u32 (absolute into srcSorted)
#define OFF_HPROJ    457216u      // [3][N][16] f32
#define OFF_HOUT     2857216u     // [N][16] f32
#define OFF_AGGP     3657216u     // [3][N][16] f32 (scaled by invIn already)
#define OFF_SRCHIST  3657216u     // [3][32][25000] u32 = 2.4M words (alias: dead before aggP)
#define OFF_HS       6057216u     // [3][N] f32
#define OFF_OUTP     6207216u     // [3][N] f32
#define OFF_PAIRS    6357216u     // Etot u32 packed (dst<<16 | src)
#define OFF_SRCSORT  10557216u    // Etot u16
// need = (OFF_SRCSORT + ceil(Etot/2)) * 4  ~= 50.6 MB

__global__ void k_zero_u32(unsigned* __restrict__ p, int n) {
    int i = blockIdx.x * 256 + threadIdx.x;
    if (i < n) p[i] = 0u;
}

// src degree histogram: (chunk, range, rel) decomposition, packed u16 bins, int4 loads.
__global__ __launch_bounds__(256) void k_srcDeg(const int* s0, const int* s1, const int* s2,
                                                int E0, int E1, int E2,
                                                unsigned* __restrict__ histP) {
    __shared__ unsigned bins[RNGSZ / 2];
    int c = blockIdx.x, rg = blockIdx.y, r = blockIdx.z;
    const int* arr = (r == 0) ? s0 : (r == 1) ? s1 : s2;
    int E = (r == 0) ? E0 : (r == 1) ? E1 : E2;
    for (int i = threadIdx.x; i < RNGSZ / 2; i += 256) bins[i] = 0u;
    __syncthreads();
    int lo = rg * RNGSZ;
    int per = (((E + NCH2 - 1) / NCH2) + 3) & ~3;
    int a0 = c * per, a1 = min(a0 + per, E);
    for (int i = a0 + (int)threadIdx.x * 4; i < a1; i += 1024) {
        if (i + 4 <= a1) {
            int4 v = *reinterpret_cast<const int4*>(arr + i);
            unsigned d0 = (unsigned)(v.x - lo), d1 = (unsigned)(v.y - lo);
            unsigned d2 = (unsigned)(v.z - lo), d3 = (unsigned)(v.w - lo);
            if (d0 < (unsigned)RNGSZ) atomicAdd(&bins[d0 >> 1], (d0 & 1u) ? 65536u : 1u);
            if (d1 < (unsigned)RNGSZ) atomicAdd(&bins[d1 >> 1], (d1 & 1u) ? 65536u : 1u);
            if (d2 < (unsigned)RNGSZ) atomicAdd(&bins[d2 >> 1], (d2 & 1u) ? 65536u : 1u);
            if (d3 < (unsigned)RNGSZ) atomicAdd(&bins[d3 >> 1], (d3 & 1u) ? 65536u : 1u);
        } else {
            for (int k2 = i; k2 < a1; k2++) {
                unsigned d = (unsigned)(arr[k2] - lo);
                if (d < (unsigned)RNGSZ) atomicAdd(&bins[d >> 1], (d & 1u) ? 65536u : 1u);
            }
        }
    }
    __syncthreads();
    unsigned* out = histP + ((size_t)r * NCH2 + c) * 25000 + rg * (RNGSZ / 2);
    for (int i = threadIdx.x; i < RNGSZ / 2; i += 256) out[i] = bins[i];
}

__global__ void k_degreduceOut(const unsigned* __restrict__ histP, float* __restrict__ invOut) {
    int n = blockIdx.x * 256 + threadIdx.x;
    int r = blockIdx.y;
    if (n >= N_NODES) return;
    const unsigned* p = histP + (size_t)r * NCH2 * 25000 + (n >> 1);
    unsigned s = 0;
#pragma unroll
    for (int c = 0; c < NCH2; c++) {
        unsigned w = p[(size_t)c * 25000];
        s += (n & 1) ? (w >> 16) : (w & 0xFFFFu);
    }
    invOut[r * N_NODES + n] = rsqrtf((float)(s ? s : 1u));
}

// per-(relation,bucket) dst counts, int4 loads
__global__ __launch_bounds__(256) void k_bukCount(const int* d0p, const int* d1p, const int* d2p,
                                                  int E0, int E1, int E2,
                                                  unsigned* __restrict__ bukCnt) {
    __shared__ unsigned bins[NBUK];
    int c = blockIdx.x, r = blockIdx.y;
    const int* arr = (r == 0) ? d0p : (r == 1) ? d1p : d2p;
    int E = (r == 0) ? E0 : (r == 1) ? E1 : E2;
    for (int i = threadIdx.x; i < NBUK; i += 256) bins[i] = 0u;
    __syncthreads();
    int nb = gridDim.x;
    int per = (((E + nb - 1) / nb) + 3) & ~3;
    int a0 = c * per, a1 = min(a0 + per, E);
    for (int i = a0 + (int)threadIdx.x * 4; i < a1; i += 1024) {
        if (i + 4 <= a1) {
            int4 v = *reinterpret_cast<const int4*>(arr + i);
            atomicAdd(&bins[((unsigned)v.x) >> BSHIFT], 1u);
            atomicAdd(&bins[((unsigned)v.y) >> BSHIFT], 1u);
            atomicAdd(&bins[((unsigned)v.z) >> BSHIFT], 1u);
            atomicAdd(&bins[((unsigned)v.w) >> BSHIFT], 1u);
        } else {
            for (int k2 = i; k2 < a1; k2++)
                atomicAdd(&bins[((unsigned)arr[k2]) >> BSHIFT], 1u);
        }
    }
    __syncthreads();
    for (int b = threadIdx.x; b < NBUK; b += 256)
        if (bins[b]) atomicAdd(&bukCnt[r * BSTRIDE + b], bins[b]);
}

// parallel exclusive scan of bucket counts (256 threads x 4 bins, Hillis-Steele)
__global__ __launch_bounds__(256) void k_bucketScan(const unsigned* __restrict__ bukCnt,
                                                    unsigned* __restrict__ bstart,
                                                    unsigned* __restrict__ gcur) {
    __shared__ unsigned part[256];
    int r = blockIdx.x, t = threadIdx.x;
    unsigned loc[4]; unsigned s = 0;
#pragma unroll
    for (int k = 0; k < 4; k++) {
        int idx = 4 * t + k;
        loc[k] = (idx < NBUK) ? bukCnt[r * BSTRIDE + idx] : 0u;
        s += loc[k];
    }
    part[t] = s;
    __syncthreads();
    for (int d = 1; d < 256; d <<= 1) {
        unsigned v = (t >= d) ? part[t - d] : 0u;
        __syncthreads();
        part[t] += v;
        __syncthreads();
    }
    unsigned run = part[t] - s;  // exclusive prefix
#pragma unroll
    for (int k = 0; k < 4; k++) {
        int idx = 4 * t + k;
        if (idx <= NBUK) { bstart[r * BSTRIDE + idx] = run; gcur[r * BSTRIDE + idx] = run; }
        run += loc[k];
    }
}

// bucket-scatter with in-LDS tile reorder. pair = (dst<<16)|src.
__global__ __launch_bounds__(256) void k_passB(
    const int* s0p, const int* s1p, const int* s2p,
    const int* d0p, const int* d1p, const int* d2p,
    int E0, int E1, int E2, int po0, int po1, int po2,
    unsigned* __restrict__ pairsAll, unsigned* __restrict__ gcurAll) {
    __shared__ unsigned cnt[NBUK];
    __shared__ unsigned off[NBUK];
    __shared__ unsigned gbase[NBUK];
    __shared__ unsigned part[256];
    __shared__ unsigned spair[TILE];
    __shared__ unsigned saddr[TILE];
    int r = blockIdx.z;
    const int* src = (r == 0) ? s0p : (r == 1) ? s1p : s2p;
    const int* dst = (r == 0) ? d0p : (r == 1) ? d1p : d2p;
    int E = (r == 0) ? E0 : (r == 1) ? E1 : E2;
    unsigned* pairs = pairsAll + ((r == 0) ? po0 : (r == 1) ? po1 : po2);
    unsigned* gcur = gcurAll + r * BSTRIDE;
    int nb = gridDim.x;
    int chunk = (E + nb - 1) / nb;
    int c0 = blockIdx.x * chunk;
    int c1 = min(c0 + chunk, E);
    for (int t0 = c0; t0 < c1; t0 += TILE) {
        int tn = min(TILE, c1 - t0);
        for (int i = threadIdx.x; i < NBUK; i += 256) cnt[i] = 0u;
        __syncthreads();
        unsigned pk[16], bk[16], sl[16];
#pragma unroll
        for (int k = 0; k < 16; k++) {
            int ii = k * 256 + (int)threadIdx.x;
            bk[k] = 0xFFFFFFFFu;
            if (ii < tn) {
                int i = t0 + ii;
                unsigned s = (unsigned)src[i], d = (unsigned)dst[i];
                pk[k] = (d << 16) | s;
                unsigned b = d >> BSHIFT;
                bk[k] = b;
                sl[k] = atomicAdd(&cnt[b], 1u);
            }
        }
        __syncthreads();
        // parallel exclusive scan cnt -> off
        {
            int t = threadIdx.x;
            unsigned loc[4]; unsigned sloc = 0;
#pragma unroll
            for (int k2 = 0; k2 < 4; k2++) {
                int idx = 4 * t + k2;
                loc[k2] = (idx < NBUK) ? cnt[idx] : 0u;
                sloc += loc[k2];
            }
            part[t] = sloc;
            __syncthreads();
            for (int d = 1; d < 256; d <<= 1) {
                unsigned v = (t >= d) ? part[t - d] : 0u;
                __syncthreads();
                part[t] += v;
                __syncthreads();
            }
            unsigned run = part[t] - sloc;
#pragma unroll
            for (int k2 = 0; k2 < 4; k2++) {
                int idx = 4 * t + k2;
                if (idx < NBUK) off[idx] = run;
                run += loc[k2];
            }
        }
        __syncthreads();
        for (int b = threadIdx.x; b < NBUK; b += 256) {
            unsigned c = cnt[b];
            if (c) gbase[b] = atomicAdd(&gcur[b], c);
        }
        __syncthreads();
#pragma unroll
        for (int k = 0; k < 16; k++) {
            if (bk[k] != 0xFFFFFFFFu) {
                unsigned idx = off[bk[k]] + sl[k];
                spair[idx] = pk[k];
                saddr[idx] = gbase[bk[k]] + sl[k];
            }
        }
        __syncthreads();
#pragma unroll
        for (int k = 0; k < 16; k++) {
            int ii = k * 256 + (int)threadIdx.x;
            if (ii < tn) pairs[saddr[ii]] = spair[ii];
        }
        __syncthreads();
    }
}

// h_r[n][j] = (x[n,:] . W1[r][:,j]) * invOut_r[n]
__global__ __launch_bounds__(256) void k_h1(const float* __restrict__ x, const float* __restrict__ invOut,
                                            const float* __restrict__ W1, float* __restrict__ hproj) {
    __shared__ float sW[32 * FH];
    __shared__ float sx[16][32];
    int r = blockIdx.y;
    const float* W = W1 + r * 32 * FH;
    int t = threadIdx.x;
    for (int i = t; i < 32 * FH; i += 256) sW[i] = W[i];
    int n0 = blockIdx.x * 16;
    for (int i = t; i < 16 * 32; i += 256) {
        int nn = i >> 5, kk = i & 31;
        int n = n0 + nn;
        sx[nn][kk] = (n < N_NODES) ? x[n * 32 + kk] : 0.0f;
    }
    __syncthreads();
    int nn = t >> 4, j = t & 15;
    int n = n0 + nn;
    if (n < N_NODES) {
        float s = 0.f;
#pragma unroll
        for (int k = 0; k < 32; k++) s += sx[nn][k] * sW[k * FH + j];
        hproj[((size_t)r * N_NODES + n) * FH + j] = s * invOut[r * N_NODES + n];
    }
}

// layer-1 per-bucket (all 3 relations in one launch, z = relation):
// LDS counting sort by dst -> segmented float4 register accumulation.
__global__ __launch_bounds__(256) void k_passC1(
    const unsigned* __restrict__ pairsAll, int po1, int po2,
    const unsigned* __restrict__ bstartAll,
    const float4* __restrict__ h4All, float4* __restrict__ out4All,
    unsigned short* __restrict__ srcGAll, unsigned* __restrict__ rowptrAll,
    float* __restrict__ invInAll) {
    __shared__ unsigned cnt[64];
    __shared__ unsigned off[65];
    __shared__ unsigned cur[64];
    __shared__ unsigned short srcS[C1CAP];
    int b = blockIdx.x, t = threadIdx.x, r = blockIdx.z;
    int po = (r == 0) ? 0 : (r == 1) ? po1 : po2;
    const unsigned* pairs = pairsAll + po;
    const unsigned* bstart = bstartAll + r * BSTRIDE;
    const float4* h4 = h4All + (size_t)r * N_NODES * 4;
    float4* out4 = out4All + (size_t)r * N_NODES * 4;
    unsigned short* srcG = srcGAll + po;
    unsigned* rowptr = rowptrAll + (size_t)r * (N_NODES + 1);
    float* invIn = invInAll + (size_t)r * N_NODES;
    unsigned e0 = bstart[b], e1 = bstart[b + 1];
    if (e1 - e0 > (unsigned)C1CAP) e1 = e0 + (unsigned)C1CAP;   // statistically impossible
    int d0 = b << BSHIFT;
    if (t < 64) cnt[t] = 0u;
    __syncthreads();
    // 1) histogram (exact deg_in per node)
    for (unsigned i = e0 + t; i < e1; i += 256)
        atomicAdd(&cnt[(pairs[i] >> 16) - (unsigned)d0], 1u);
    __syncthreads();
    // 2) wave-0 shfl scan over 64 bins
    if (t < 64) {
        unsigned cv = cnt[t];
        unsigned sc = cv;
#pragma unroll
        for (int d = 1; d < 64; d <<= 1) {
            unsigned v = __shfl_up(sc, d, 64);
            if (t >= d) sc += v;
        }
        off[t] = sc - cv;
        if (t == 63) off[64] = sc;
    }
    __syncthreads();
    if (t < 64) {
        cur[t] = off[t];
        int n = d0 + t;
        if (n < N_NODES) {
            rowptr[n] = (unsigned)po + e0 + off[t];
            unsigned dg = cnt[t];
            invIn[n] = rsqrtf((float)(dg ? dg : 1u));
        }
    }
    if (b == NBUK - 1 && t == 0) rowptr[N_NODES] = (unsigned)po + e1;
    __syncthreads();
    // 3) scatter src (u16) sorted by dst
    for (unsigned i = e0 + t; i < e1; i += 256) {
        unsigned p = pairs[i];
        unsigned d = (p >> 16) - (unsigned)d0;
        unsigned pos = atomicAdd(&cur[d], 1u);
        srcS[pos] = (unsigned short)(p & 0xFFFFu);
    }
    __syncthreads();
    // 3b) persist sorted src list for layer-2
    {
        unsigned len = e1 - e0;
        for (unsigned i = t; i < len; i += 256) srcG[e0 + i] = srcS[i];
    }
    // 4) segmented aggregation: 16-lane unit, 4 lanes/edge, float4 gathers, register acc
    int unit = t >> 4, p = t & 15, k = p >> 2, fq = p & 3;
    for (int nd = unit; nd < 64; nd += 16) {
        unsigned o0 = off[nd], o1 = off[nd + 1];
        float ax = 0.f, ay = 0.f, az = 0.f, aw = 0.f;
        unsigned base = o0;
        for (; base + 8 <= o1; base += 8) {
            int s0 = srcS[base + k], s1 = srcS[base + 4 + k];
            float4 v0 = h4[(size_t)s0 * 4 + fq];
            float4 v1 = h4[(size_t)s1 * 4 + fq];
            ax += v0.x + v1.x; ay += v0.y + v1.y; az += v0.z + v1.z; aw += v0.w + v1.w;
        }
        for (; base < o1; base += 4) {
            unsigned idx = base + (unsigned)k;
            if (idx < o1) {
                int s = srcS[idx];
                float4 v = h4[(size_t)s * 4 + fq];
                ax += v.x; ay += v.y; az += v.z; aw += v.w;
            }
        }
        ax += __shfl_xor(ax, 4, 16); ay += __shfl_xor(ay, 4, 16);
        az += __shfl_xor(az, 4, 16); aw += __shfl_xor(aw, 4, 16);
        ax += __shfl_xor(ax, 8, 16); ay += __shfl_xor(ay, 8, 16);
        az += __shfl_xor(az, 8, 16); aw += __shfl_xor(aw, 8, 16);
        int n = d0 + nd;
        if (k == 0 && n < N_NODES) {
            unsigned dg = o1 - o0;
            float sc = rsqrtf((float)(dg ? dg : 1u));
            float4 res; res.x = ax * sc; res.y = ay * sc; res.z = az * sc; res.w = aw * sc;
            out4[(size_t)n * 4 + fq] = res;
        }
    }
}

__global__ void k_relu(const float* __restrict__ aggP, const float* __restrict__ b1,
                       float* __restrict__ hout) {
    int i = blockIdx.x * 256 + threadIdx.x;
    if (i >= N_NODES * FH) return;
    int j = i & 15;
    const size_t SL = (size_t)N_NODES * FH;
    float v = aggP[i] + aggP[SL + i] + aggP[2 * SL + i]
            + b1[j] + b1[FH + j] + b1[2 * FH + j];
    hout[i] = fmaxf(v, 0.f);
}

__global__ void k_h2(const float* __restrict__ hout, const float* __restrict__ invOut,
                     const float* __restrict__ W2, float* __restrict__ hs) {
    int n = blockIdx.x * 256 + threadIdx.x;
    int r = blockIdx.y;
    if (n >= N_NODES) return;
    const float4* hp = (const float4*)(hout + (size_t)n * FH);
    const float* w = W2 + r * FH;
    float s = 0.f;
#pragma unroll
    for (int q = 0; q < 4; q++) {
        float4 hv = hp[q];
        s += hv.x * w[q * 4 + 0] + hv.y * w[q * 4 + 1] + hv.z * w[q * 4 + 2] + hv.w * w[q * 4 + 3];
    }
    hs[r * N_NODES + n] = s * invOut[r * N_NODES + n];
}

// layer-2: segmented sum over sorted src lists; one 16-lane unit per (r, node).
__global__ __launch_bounds__(256) void k_passC2(
    const unsigned short* __restrict__ srcG, const unsigned* __restrict__ rowptr,
    const float* __restrict__ hsAll, const float* __restrict__ invIn,
    float* __restrict__ outP) {
    int t = threadIdx.x;
    int unit = t >> 4, p = t & 15;
    int gid = blockIdx.x * 16 + unit;
    if (gid >= 3 * N_NODES) return;
    int r = gid / N_NODES;
    int n = gid - r * N_NODES;
    unsigned o0 = rowptr[r * (N_NODES + 1) + n];
    unsigned o1 = rowptr[r * (N_NODES + 1) + n + 1];
    const float* hs = hsAll + (size_t)r * N_NODES;
    float s = 0.f;
    for (unsigned i = o0 + (unsigned)p; i < o1; i += 16) s += hs[srcG[i]];
    s += __shfl_xor(s, 1, 16); s += __shfl_xor(s, 2, 16);
    s += __shfl_xor(s, 4, 16); s += __shfl_xor(s, 8, 16);
    if (p == 0) outP[(size_t)r * N_NODES + n] = s * invIn[r * N_NODES + n];
}

__global__ void k_final(const float* __restrict__ outP, const float* __restrict__ b2,
                        float* __restrict__ out) {
    int n = blockIdx.x * 256 + threadIdx.x;
    if (n >= N_NODES) return;
    out[n] = outP[n] + outP[N_NODES + n] + outP[2 * (size_t)N_NODES + n]
           + b2[0] + b2[1] + b2[2];
}

// =============== fallback (round-1) kernels ===============

__global__ void f_zero(float* __restrict__ p, int n) {
    int i = blockIdx.x * blockDim.x + threadIdx.x;
    if (i < n) p[i] = 0.0f;
}
__global__ void f_deg(const int* __restrict__ src, const int* __restrict__ dst, int E,
                      float* __restrict__ dout, float* __restrict__ din) {
    int i = blockIdx.x * blockDim.x + threadIdx.x;
    if (i < E) { atomicAdd(&dout[src[i]], 1.0f); atomicAdd(&din[dst[i]], 1.0f); }
}
__global__ void f_rsqrt(float* __restrict__ p, int n) {
    int i = blockIdx.x * blockDim.x + threadIdx.x;
    if (i < n) p[i] = rsqrtf(fmaxf(p[i], 1.0f));
}
__global__ void f_agg1(const int* __restrict__ src, const int* __restrict__ dst, int E,
                       const float* __restrict__ h, const float* __restrict__ invin,
                       float* __restrict__ agg) {
    int idx = blockIdx.x * blockDim.x + threadIdx.x;
    if (idx < E * FH) {
        int e = idx >> 4, j = idx & 15;
        atomicAdd(&agg[dst[e] * FH + j], h[src[e] * FH + j] * invin[dst[e]]);
    }
}
__global__ void f_relu(float* __restrict__ agg, const float* __restrict__ b1) {
    int i = blockIdx.x * blockDim.x + threadIdx.x;
    if (i < N_NODES * FH) {
        int j = i & 15;
        agg[i] = fmaxf(agg[i] + b1[j] + b1[FH + j] + b1[2 * FH + j], 0.0f);
    }
}
__global__ void f_outinit(float* __restrict__ out, const float* __restrict__ b2) {
    int i = blockIdx.x * blockDim.x + threadIdx.x;
    if (i < N_NODES) out[i] = b2[0] + b2[1] + b2[2];
}
__global__ void f_h2(const float* __restrict__ h1, const float* __restrict__ invout,
                     const float* __restrict__ W2r, float* __restrict__ hsv) {
    int n = blockIdx.x * blockDim.x + threadIdx.x;
    if (n < N_NODES) {
        const float4* hp = (const float4*)(h1 + (size_t)n * FH);
        float s = 0.0f;
#pragma unroll
        for (int q = 0; q < 4; q++) {
            float4 hv = hp[q];
            s += hv.x * W2r[q * 4] + hv.y * W2r[q * 4 + 1] + hv.z * W2r[q * 4 + 2] + hv.w * W2r[q * 4 + 3];
        }
        hsv[n] = s * invout[n];
    }
}
__global__ void f_agg2(const int* __restrict__ src, const int* __restrict__ dst, int E,
                       const float* __restrict__ hsv, const float* __restrict__ invin,
                       float* __restrict__ out) {
    int e = blockIdx.x * blockDim.x + threadIdx.x;
    if (e < E) atomicAdd(&out[dst[e]], hsv[src[e]] * invin[dst[e]]);
}

// =============== host ===============

extern "C" void kernel_launch(void* const* d_in, const int* in_sizes, int n_in,
                              void* d_out, int out_size, void* d_ws, size_t ws_size,
                              hipStream_t stream) {
    const float* x = (const float*)d_in[0];
    const int* srcs[3] = { (const int*)d_in[1], (const int*)d_in[3], (const int*)d_in[5] };
    const int* dsts[3] = { (const int*)d_in[2], (const int*)d_in[4], (const int*)d_in[6] };
    int E[3] = { in_sizes[1], in_sizes[3], in_sizes[5] };
    const float* W1 = (const float*)d_in[7];
    const float* b1 = (const float*)d_in[8];
    const float* W2 = (const float*)d_in[9];
    const float* b2 = (const float*)d_in[10];
    float* out = (float*)d_out;
    const int N = N_NODES;
    const int B = 256;
    size_t Etot = (size_t)E[0] + E[1] + E[2];
    size_t need = ((size_t)OFF_SRCSORT + (Etot + 1) / 2) * 4u;

    if (ws_size >= need) {
        unsigned* ws = (unsigned*)d_ws;
        float* invOut = (float*)(ws + OFF_INVOUT);
        float* invIn  = (float*)(ws + OFF_INVIN);
        unsigned* bukCnt = ws + OFF_BUKCNT;
        unsigned* bstart = ws + OFF_BSTART;
        unsigned* gcur   = ws + OFF_GCUR;
        unsigned* rowptr = ws + OFF_ROWPTR;
        float* hproj = (float*)(ws + OFF_HPROJ);
        float* hout  = (float*)(ws + OFF_HOUT);
        float* aggP  = (float*)(ws + OFF_AGGP);
        unsigned* srcHist = ws + OFF_SRCHIST;
        float* hs    = (float*)(ws + OFF_HS);
        float* outP  = (float*)(ws + OFF_OUTP);
        unsigned* pairs = ws + OFF_PAIRS;
        unsigned short* srcSort = (unsigned short*)(ws + OFF_SRCSORT);
        int po[3] = { 0, E[0], E[0] + E[1] };

        k_zero_u32<<<(3 * BSTRIDE + B - 1) / B, B, 0, stream>>>(bukCnt, 3 * BSTRIDE);
        k_srcDeg<<<dim3(NCH2, NRNG, 3), B, 0, stream>>>(srcs[0], srcs[1], srcs[2],
                                                        E[0], E[1], E[2], srcHist);
        k_degreduceOut<<<dim3((N + B - 1) / B, 3), B, 0, stream>>>(srcHist, invOut);
        k_bukCount<<<dim3(64, 3), B, 0, stream>>>(dsts[0], dsts[1], dsts[2], E[0], E[1], E[2], bukCnt);
        k_bucketScan<<<3, B, 0, stream>>>(bukCnt, bstart, gcur);
        k_passB<<<dim3(256, 1, 3), B, 0, stream>>>(
            srcs[0], srcs[1], srcs[2], dsts[0], dsts[1], dsts[2],
            E[0], E[1], E[2], po[0], po[1], po[2], pairs, gcur);
        k_h1<<<dim3((N + 15) / 16, 3), B, 0, stream>>>(x, invOut, W1, hproj);
        k_passC1<<<dim3(NBUK, 1, 3), B, 0, stream>>>(
            pairs, po[1], po[2], bstart,
            (const float4*)hproj, (float4*)aggP,
            srcSort, rowptr, invIn);
        k_relu<<<(N * FH + B - 1) / B, B, 0, stream>>>(aggP, b1, hout);
        k_h2<<<dim3((N + B - 1) / B, 3), B, 0, stream>>>(hout, invOut, W2, hs);
        k_passC2<<<(3 * N + 15) / 16, B, 0, stream>>>(srcSort, rowptr, hs, invIn, outP);
        k_final<<<(N + B - 1) / B, B, 0, stream>>>(outP, b2, out);
    } else {
        // fallback: round-1 atomic path
        float* wsf = (float*)d_ws;
        float* invOut = wsf;
        float* invIn = wsf + 3 * (size_t)N;
        float* h = wsf + 6 * (size_t)N;
        float* agg = wsf + 22 * (size_t)N;
        float* hsv = wsf + 38 * (size_t)N;
        f_zero<<<(6 * N + B - 1) / B, B, 0, stream>>>(invOut, 6 * N);
        f_zero<<<(16 * N + B - 1) / B, B, 0, stream>>>(agg, 16 * N);
        for (int r = 0; r < 3; r++)
            f_deg<<<(E[r] + B - 1) / B, B, 0, stream>>>(srcs[r], dsts[r], E[r],
                                                        invOut + (size_t)r * N, invIn + (size_t)r * N);
        f_rsqrt<<<(6 * N + B - 1) / B, B, 0, stream>>>(invOut, 6 * N);
        for (int r = 0; r < 3; r++) {
            k_h1<<<dim3((N + 15) / 16, 1), B, 0, stream>>>(x, invOut + (size_t)r * N,
                                                           W1 + (size_t)r * 32 * FH, h);
            f_agg1<<<(E[r] * FH + B - 1) / B, B, 0, stream>>>(srcs[r], dsts[r], E[r], h,
                                                              invIn + (size_t)r * N, agg);
        }
        f_relu<<<(N * FH + B - 1) / B, B, 0, stream>>>(agg, b1);
        f_outinit<<<(N + B - 1) / B, B, 0, stream>>>(out, b2);
        for (int r = 0; r < 3; r++) {
            f_h2<<<(N + B - 1) / B, B, 0, stream>>>(agg, invOut + (size_t)r * N,
                                                    W2 + (size_t)r * FH, hsv);
            f_agg2<<<(E[r] + B - 1) / B, B, 0, stream>>>(srcs[r], dsts[r], E[r], hsv,
                                                         invIn + (size_t)r * N, out);
        }
    }
}

// Round 10
// 243.727 us; speedup vs baseline: 4.1867x; 1.1449x over previous
//
#include <hip/hip_runtime.h>

#define N_NODES 50000
#define FH 16
#define NBUK 782          // 64-node buckets: bucket = dst >> 6
#define BSHIFT 6
#define BSTRIDE 800
#define TILE 4096
#define NCH2 64           // src-deg chunks
#define NRNG 8            // src-deg node ranges
#define RNGSZ 6250        // nodes per range (even)
#define C1CAP 4608        // passC1 max bucket size (u16 LDS)

// ---- ws layout (u32 words) ----
#define OFF_INVOUT   0u           // [3][N] f32
#define OFF_INVIN    150000u      // [3][N] f32
#define OFF_BUKCNT   300000u      // [3][800]
#define OFF_BSTART   302400u      // [3][800]
#define OFF_GCUR     304800u      // [3][800]
#define OFF_ROWPTR   307200u      // [3][N+1] u32 (absolute into srcSorted)
#define OFF_HPROJ    457216u      // [3][N][16] f32
#define OFF_HOUT     2857216u     // [N][16] f32
#define OFF_AGGP     3657216u     // [3][N][16] f32
#define OFF_SRCHIST  3657216u     // [3][64][25000] u32 = 4.8M words, ends 8457216
                                  // (alias over aggP/HS/pairs-head: srcHist is dead after
                                  //  k_degreduceOut, which runs BEFORE passB/passC1/h2 writes)
#define OFF_HS       6057216u     // [3][N] f32
#define OFF_OUTP     6207216u     // [3][N] f32
#define OFF_PAIRS    6357216u     // Etot u32 packed (dst<<16 | src)
#define OFF_SRCSORT  10557216u    // Etot u16
// need = (OFF_SRCSORT + ceil(Etot/2)) * 4  ~= 50.6 MB

__global__ void k_zero_u32(unsigned* __restrict__ p, int n) {
    int i = blockIdx.x * 256 + threadIdx.x;
    if (i < n) p[i] = 0u;
}

// src degree histogram: (chunk, range, rel), packed u16 bins, 8 edges/thread (2x int4).
__global__ __launch_bounds__(256) void k_srcDeg(const int* s0, const int* s1, const int* s2,
                                                int E0, int E1, int E2,
                                                unsigned* __restrict__ histP) {
    __shared__ unsigned bins[RNGSZ / 2];
    int c = blockIdx.x, rg = blockIdx.y, r = blockIdx.z;
    const int* arr = (r == 0) ? s0 : (r == 1) ? s1 : s2;
    int E = (r == 0) ? E0 : (r == 1) ? E1 : E2;
    for (int i = threadIdx.x; i < RNGSZ / 2; i += 256) bins[i] = 0u;
    __syncthreads();
    int lo = rg * RNGSZ;
    int per = (((E + NCH2 - 1) / NCH2) + 7) & ~7;
    int a0 = c * per, a1 = min(a0 + per, E);
    for (int i = a0 + (int)threadIdx.x * 8; i < a1; i += 2048) {
        if (i + 8 <= a1) {
            int4 v1 = *reinterpret_cast<const int4*>(arr + i);
            int4 v2 = *reinterpret_cast<const int4*>(arr + i + 4);
            unsigned d0 = (unsigned)(v1.x - lo), d1 = (unsigned)(v1.y - lo);
            unsigned d2 = (unsigned)(v1.z - lo), d3 = (unsigned)(v1.w - lo);
            unsigned d4 = (unsigned)(v2.x - lo), d5 = (unsigned)(v2.y - lo);
            unsigned d6 = (unsigned)(v2.z - lo), d7 = (unsigned)(v2.w - lo);
            if (d0 < (unsigned)RNGSZ) atomicAdd(&bins[d0 >> 1], (d0 & 1u) ? 65536u : 1u);
            if (d1 < (unsigned)RNGSZ) atomicAdd(&bins[d1 >> 1], (d1 & 1u) ? 65536u : 1u);
            if (d2 < (unsigned)RNGSZ) atomicAdd(&bins[d2 >> 1], (d2 & 1u) ? 65536u : 1u);
            if (d3 < (unsigned)RNGSZ) atomicAdd(&bins[d3 >> 1], (d3 & 1u) ? 65536u : 1u);
            if (d4 < (unsigned)RNGSZ) atomicAdd(&bins[d4 >> 1], (d4 & 1u) ? 65536u : 1u);
            if (d5 < (unsigned)RNGSZ) atomicAdd(&bins[d5 >> 1], (d5 & 1u) ? 65536u : 1u);
            if (d6 < (unsigned)RNGSZ) atomicAdd(&bins[d6 >> 1], (d6 & 1u) ? 65536u : 1u);
            if (d7 < (unsigned)RNGSZ) atomicAdd(&bins[d7 >> 1], (d7 & 1u) ? 65536u : 1u);
        } else {
            for (int k2 = i; k2 < a1; k2++) {
                unsigned d = (unsigned)(arr[k2] - lo);
                if (d < (unsigned)RNGSZ) atomicAdd(&bins[d >> 1], (d & 1u) ? 65536u : 1u);
            }
        }
    }
    __syncthreads();
    unsigned* out = histP + ((size_t)r * NCH2 + c) * 25000 + rg * (RNGSZ / 2);
    for (int i = threadIdx.x; i < RNGSZ / 2; i += 256) out[i] = bins[i];
}

__global__ void k_degreduceOut(const unsigned* __restrict__ histP, float* __restrict__ invOut) {
    int n = blockIdx.x * 256 + threadIdx.x;
    int r = blockIdx.y;
    if (n >= N_NODES) return;
    const unsigned* p = histP + (size_t)r * NCH2 * 25000 + (n >> 1);
    unsigned s = 0;
#pragma unroll
    for (int c = 0; c < NCH2; c++) {
        unsigned w = p[(size_t)c * 25000];
        s += (n & 1) ? (w >> 16) : (w & 0xFFFFu);
    }
    invOut[r * N_NODES + n] = rsqrtf((float)(s ? s : 1u));
}

// per-(relation,bucket) dst counts, int4 loads
__global__ __launch_bounds__(256) void k_bukCount(const int* d0p, const int* d1p, const int* d2p,
                                                  int E0, int E1, int E2,
                                                  unsigned* __restrict__ bukCnt) {
    __shared__ unsigned bins[NBUK];
    int c = blockIdx.x, r = blockIdx.y;
    const int* arr = (r == 0) ? d0p : (r == 1) ? d1p : d2p;
    int E = (r == 0) ? E0 : (r == 1) ? E1 : E2;
    for (int i = threadIdx.x; i < NBUK; i += 256) bins[i] = 0u;
    __syncthreads();
    int nb = gridDim.x;
    int per = (((E + nb - 1) / nb) + 3) & ~3;
    int a0 = c * per, a1 = min(a0 + per, E);
    for (int i = a0 + (int)threadIdx.x * 4; i < a1; i += 1024) {
        if (i + 4 <= a1) {
            int4 v = *reinterpret_cast<const int4*>(arr + i);
            atomicAdd(&bins[((unsigned)v.x) >> BSHIFT], 1u);
            atomicAdd(&bins[((unsigned)v.y) >> BSHIFT], 1u);
            atomicAdd(&bins[((unsigned)v.z) >> BSHIFT], 1u);
            atomicAdd(&bins[((unsigned)v.w) >> BSHIFT], 1u);
        } else {
            for (int k2 = i; k2 < a1; k2++)
                atomicAdd(&bins[((unsigned)arr[k2]) >> BSHIFT], 1u);
        }
    }
    __syncthreads();
    for (int b = threadIdx.x; b < NBUK; b += 256)
        if (bins[b]) atomicAdd(&bukCnt[r * BSTRIDE + b], bins[b]);
}

// parallel exclusive scan of bucket counts (256 threads x 4 bins, Hillis-Steele)
__global__ __launch_bounds__(256) void k_bucketScan(const unsigned* __restrict__ bukCnt,
                                                    unsigned* __restrict__ bstart,
                                                    unsigned* __restrict__ gcur) {
    __shared__ unsigned part[256];
    int r = blockIdx.x, t = threadIdx.x;
    unsigned loc[4]; unsigned s = 0;
#pragma unroll
    for (int k = 0; k < 4; k++) {
        int idx = 4 * t + k;
        loc[k] = (idx < NBUK) ? bukCnt[r * BSTRIDE + idx] : 0u;
        s += loc[k];
    }
    part[t] = s;
    __syncthreads();
    for (int d = 1; d < 256; d <<= 1) {
        unsigned v = (t >= d) ? part[t - d] : 0u;
        __syncthreads();
        part[t] += v;
        __syncthreads();
    }
    unsigned run = part[t] - s;  // exclusive prefix
#pragma unroll
    for (int k = 0; k < 4; k++) {
        int idx = 4 * t + k;
        if (idx <= NBUK) { bstart[r * BSTRIDE + idx] = run; gcur[r * BSTRIDE + idx] = run; }
        run += loc[k];
    }
}

// bucket-scatter with in-LDS tile reorder. pair = (dst<<16)|src.
__global__ __launch_bounds__(256) void k_passB(
    const int* s0p, const int* s1p, const int* s2p,
    const int* d0p, const int* d1p, const int* d2p,
    int E0, int E1, int E2, int po0, int po1, int po2,
    unsigned* __restrict__ pairsAll, unsigned* __restrict__ gcurAll) {
    __shared__ unsigned cnt[NBUK];
    __shared__ unsigned off[NBUK];
    __shared__ unsigned gbase[NBUK];
    __shared__ unsigned part[256];
    __shared__ unsigned spair[TILE];
    __shared__ unsigned saddr[TILE];
    int r = blockIdx.z;
    const int* src = (r == 0) ? s0p : (r == 1) ? s1p : s2p;
    const int* dst = (r == 0) ? d0p : (r == 1) ? d1p : d2p;
    int E = (r == 0) ? E0 : (r == 1) ? E1 : E2;
    unsigned* pairs = pairsAll + ((r == 0) ? po0 : (r == 1) ? po1 : po2);
    unsigned* gcur = gcurAll + r * BSTRIDE;
    int nb = gridDim.x;
    int chunk = (((E + nb - 1) / nb) + 15) & ~15;   // 16-aligned for int4 fast path
    int c0 = blockIdx.x * chunk;
    int c1 = min(c0 + chunk, E);
    for (int t0 = c0; t0 < c1; t0 += TILE) {
        int tn = min(TILE, c1 - t0);
        for (int i = threadIdx.x; i < NBUK; i += 256) cnt[i] = 0u;
        __syncthreads();
        unsigned pk[16], bk[16], sl[16];
        if (tn == TILE) {
            // fast path: 16 contiguous edges/thread, int4 loads
            int base = t0 + (int)threadIdx.x * 16;
#pragma unroll
            for (int q = 0; q < 4; q++) {
                int4 vs = *reinterpret_cast<const int4*>(src + base + q * 4);
                int4 vd = *reinterpret_cast<const int4*>(dst + base + q * 4);
                pk[q * 4 + 0] = ((unsigned)vd.x << 16) | (unsigned)vs.x;
                pk[q * 4 + 1] = ((unsigned)vd.y << 16) | (unsigned)vs.y;
                pk[q * 4 + 2] = ((unsigned)vd.z << 16) | (unsigned)vs.z;
                pk[q * 4 + 3] = ((unsigned)vd.w << 16) | (unsigned)vs.w;
                bk[q * 4 + 0] = (unsigned)vd.x >> BSHIFT;
                bk[q * 4 + 1] = (unsigned)vd.y >> BSHIFT;
                bk[q * 4 + 2] = (unsigned)vd.z >> BSHIFT;
                bk[q * 4 + 3] = (unsigned)vd.w >> BSHIFT;
            }
#pragma unroll
            for (int k = 0; k < 16; k++) sl[k] = atomicAdd(&cnt[bk[k]], 1u);
        } else {
#pragma unroll
            for (int k = 0; k < 16; k++) {
                int ii = k * 256 + (int)threadIdx.x;
                bk[k] = 0xFFFFFFFFu;
                if (ii < tn) {
                    int i = t0 + ii;
                    unsigned s = (unsigned)src[i], d = (unsigned)dst[i];
                    pk[k] = (d << 16) | s;
                    unsigned b = d >> BSHIFT;
                    bk[k] = b;
                    sl[k] = atomicAdd(&cnt[b], 1u);
                }
            }
        }
        __syncthreads();
        // parallel exclusive scan cnt -> off
        {
            int t = threadIdx.x;
            unsigned loc[4]; unsigned sloc = 0;
#pragma unroll
            for (int k2 = 0; k2 < 4; k2++) {
                int idx = 4 * t + k2;
                loc[k2] = (idx < NBUK) ? cnt[idx] : 0u;
                sloc += loc[k2];
            }
            part[t] = sloc;
            __syncthreads();
            for (int d = 1; d < 256; d <<= 1) {
                unsigned v = (t >= d) ? part[t - d] : 0u;
                __syncthreads();
                part[t] += v;
                __syncthreads();
            }
            unsigned run = part[t] - sloc;
#pragma unroll
            for (int k2 = 0; k2 < 4; k2++) {
                int idx = 4 * t + k2;
                if (idx < NBUK) off[idx] = run;
                run += loc[k2];
            }
        }
        __syncthreads();
        for (int b = threadIdx.x; b < NBUK; b += 256) {
            unsigned c = cnt[b];
            if (c) gbase[b] = atomicAdd(&gcur[b], c);
        }
        __syncthreads();
        if (tn == TILE) {
#pragma unroll
            for (int k = 0; k < 16; k++) {
                unsigned idx = off[bk[k]] + sl[k];
                spair[idx] = pk[k];
                saddr[idx] = gbase[bk[k]] + sl[k];
            }
        } else {
#pragma unroll
            for (int k = 0; k < 16; k++) {
                if (bk[k] != 0xFFFFFFFFu) {
                    unsigned idx = off[bk[k]] + sl[k];
                    spair[idx] = pk[k];
                    saddr[idx] = gbase[bk[k]] + sl[k];
                }
            }
        }
        __syncthreads();
#pragma unroll
        for (int k = 0; k < 16; k++) {
            int ii = k * 256 + (int)threadIdx.x;
            if (ii < tn) pairs[saddr[ii]] = spair[ii];
        }
        __syncthreads();
    }
}

// h_r[n][j] = (x[n,:] . W1[r][:,j]) * invOut_r[n]
__global__ __launch_bounds__(256) void k_h1(const float* __restrict__ x, const float* __restrict__ invOut,
                                            const float* __restrict__ W1, float* __restrict__ hproj) {
    __shared__ float sW[32 * FH];
    __shared__ float sx[16][32];
    int r = blockIdx.y;
    const float* W = W1 + r * 32 * FH;
    int t = threadIdx.x;
    for (int i = t; i < 32 * FH; i += 256) sW[i] = W[i];
    int n0 = blockIdx.x * 16;
    for (int i = t; i < 16 * 32; i += 256) {
        int nn = i >> 5, kk = i & 31;
        int n = n0 + nn;
        sx[nn][kk] = (n < N_NODES) ? x[n * 32 + kk] : 0.0f;
    }
    __syncthreads();
    int nn = t >> 4, j = t & 15;
    int n = n0 + nn;
    if (n < N_NODES) {
        float s = 0.f;
#pragma unroll
        for (int k = 0; k < 32; k++) s += sx[nn][k] * sW[k * FH + j];
        hproj[((size_t)r * N_NODES + n) * FH + j] = s * invOut[r * N_NODES + n];
    }
}

// layer-1 per-bucket (all 3 relations in one launch, z = relation):
// LDS counting sort by dst -> segmented float4 register accumulation.
__global__ __launch_bounds__(256) void k_passC1(
    const unsigned* __restrict__ pairsAll, int po1, int po2,
    const unsigned* __restrict__ bstartAll,
    const float4* __restrict__ h4All, float4* __restrict__ out4All,
    unsigned short* __restrict__ srcGAll, unsigned* __restrict__ rowptrAll,
    float* __restrict__ invInAll) {
    __shared__ unsigned cnt[64];
    __shared__ unsigned off[65];
    __shared__ unsigned cur[64];
    __shared__ unsigned short srcS[C1CAP];
    int b = blockIdx.x, t = threadIdx.x, r = blockIdx.z;
    int po = (r == 0) ? 0 : (r == 1) ? po1 : po2;
    const unsigned* pairs = pairsAll + po;
    const unsigned* bstart = bstartAll + r * BSTRIDE;
    const float4* h4 = h4All + (size_t)r * N_NODES * 4;
    float4* out4 = out4All + (size_t)r * N_NODES * 4;
    unsigned short* srcG = srcGAll + po;
    unsigned* rowptr = rowptrAll + (size_t)r * (N_NODES + 1);
    float* invIn = invInAll + (size_t)r * N_NODES;
    unsigned e0 = bstart[b], e1 = bstart[b + 1];
    if (e1 - e0 > (unsigned)C1CAP) e1 = e0 + (unsigned)C1CAP;   // statistically impossible
    int d0 = b << BSHIFT;
    if (t < 64) cnt[t] = 0u;
    __syncthreads();
    // 1) histogram (exact deg_in per node)
    for (unsigned i = e0 + t; i < e1; i += 256)
        atomicAdd(&cnt[(pairs[i] >> 16) - (unsigned)d0], 1u);
    __syncthreads();
    // 2) wave-0 shfl scan over 64 bins
    if (t < 64) {
        unsigned cv = cnt[t];
        unsigned sc = cv;
#pragma unroll
        for (int d = 1; d < 64; d <<= 1) {
            unsigned v = __shfl_up(sc, d, 64);
            if (t >= d) sc += v;
        }
        off[t] = sc - cv;
        if (t == 63) off[64] = sc;
    }
    __syncthreads();
    if (t < 64) {
        cur[t] = off[t];
        int n = d0 + t;
        if (n < N_NODES) {
            rowptr[n] = (unsigned)po + e0 + off[t];
            unsigned dg = cnt[t];
            invIn[n] = rsqrtf((float)(dg ? dg : 1u));
        }
    }
    if (b == NBUK - 1 && t == 0) rowptr[N_NODES] = (unsigned)po + e1;
    __syncthreads();
    // 3) scatter src (u16) sorted by dst
    for (unsigned i = e0 + t; i < e1; i += 256) {
        unsigned p = pairs[i];
        unsigned d = (p >> 16) - (unsigned)d0;
        unsigned pos = atomicAdd(&cur[d], 1u);
        srcS[pos] = (unsigned short)(p & 0xFFFFu);
    }
    __syncthreads();
    // 3b) persist sorted src list for layer-2
    {
        unsigned len = e1 - e0;
        for (unsigned i = t; i < len; i += 256) srcG[e0 + i] = srcS[i];
    }
    // 4) segmented aggregation: 16-lane unit, 4 lanes/edge, float4 gathers, register acc
    int unit = t >> 4, p = t & 15, k = p >> 2, fq = p & 3;
    for (int nd = unit; nd < 64; nd += 16) {
        unsigned o0 = off[nd], o1 = off[nd + 1];
        float ax = 0.f, ay = 0.f, az = 0.f, aw = 0.f;
        unsigned base = o0;
        for (; base + 8 <= o1; base += 8) {
            int s0 = srcS[base + k], s1 = srcS[base + 4 + k];
            float4 v0 = h4[(size_t)s0 * 4 + fq];
            float4 v1 = h4[(size_t)s1 * 4 + fq];
            ax += v0.x + v1.x; ay += v0.y + v1.y; az += v0.z + v1.z; aw += v0.w + v1.w;
        }
        for (; base < o1; base += 4) {
            unsigned idx = base + (unsigned)k;
            if (idx < o1) {
                int s = srcS[idx];
                float4 v = h4[(size_t)s * 4 + fq];
                ax += v.x; ay += v.y; az += v.z; aw += v.w;
            }
        }
        ax += __shfl_xor(ax, 4, 16); ay += __shfl_xor(ay, 4, 16);
        az += __shfl_xor(az, 4, 16); aw += __shfl_xor(aw, 4, 16);
        ax += __shfl_xor(ax, 8, 16); ay += __shfl_xor(ay, 8, 16);
        az += __shfl_xor(az, 8, 16); aw += __shfl_xor(aw, 8, 16);
        int n = d0 + nd;
        if (k == 0 && n < N_NODES) {
            unsigned dg = o1 - o0;
            float sc = rsqrtf((float)(dg ? dg : 1u));
            float4 res; res.x = ax * sc; res.y = ay * sc; res.z = az * sc; res.w = aw * sc;
            out4[(size_t)n * 4 + fq] = res;
        }
    }
}

__global__ void k_relu(const float* __restrict__ aggP, const float* __restrict__ b1,
                       float* __restrict__ hout) {
    int i = blockIdx.x * 256 + threadIdx.x;
    if (i >= N_NODES * FH) return;
    int j = i & 15;
    const size_t SL = (size_t)N_NODES * FH;
    float v = aggP[i] + aggP[SL + i] + aggP[2 * SL + i]
            + b1[j] + b1[FH + j] + b1[2 * FH + j];
    hout[i] = fmaxf(v, 0.f);
}

__global__ void k_h2(const float* __restrict__ hout, const float* __restrict__ invOut,
                     const float* __restrict__ W2, float* __restrict__ hs) {
    int n = blockIdx.x * 256 + threadIdx.x;
    int r = blockIdx.y;
    if (n >= N_NODES) return;
    const float4* hp = (const float4*)(hout + (size_t)n * FH);
    const float* w = W2 + r * FH;
    float s = 0.f;
#pragma unroll
    for (int q = 0; q < 4; q++) {
        float4 hv = hp[q];
        s += hv.x * w[q * 4 + 0] + hv.y * w[q * 4 + 1] + hv.z * w[q * 4 + 2] + hv.w * w[q * 4 + 3];
    }
    hs[r * N_NODES + n] = s * invOut[r * N_NODES + n];
}

// layer-2: segmented sum over sorted src lists; one 16-lane unit per (r, node).
__global__ __launch_bounds__(256) void k_passC2(
    const unsigned short* __restrict__ srcG, const unsigned* __restrict__ rowptr,
    const float* __restrict__ hsAll, const float* __restrict__ invIn,
    float* __restrict__ outP) {
    int t = threadIdx.x;
    int unit = t >> 4, p = t & 15;
    int gid = blockIdx.x * 16 + unit;
    if (gid >= 3 * N_NODES) return;
    int r = gid / N_NODES;
    int n = gid - r * N_NODES;
    unsigned o0 = rowptr[r * (N_NODES + 1) + n];
    unsigned o1 = rowptr[r * (N_NODES + 1) + n + 1];
    const float* hs = hsAll + (size_t)r * N_NODES;
    float s = 0.f;
    for (unsigned i = o0 + (unsigned)p; i < o1; i += 16) s += hs[srcG[i]];
    s += __shfl_xor(s, 1, 16); s += __shfl_xor(s, 2, 16);
    s += __shfl_xor(s, 4, 16); s += __shfl_xor(s, 8, 16);
    if (p == 0) outP[(size_t)r * N_NODES + n] = s * invIn[r * N_NODES + n];
}

__global__ void k_final(const float* __restrict__ outP, const float* __restrict__ b2,
                        float* __restrict__ out) {
    int n = blockIdx.x * 256 + threadIdx.x;
    if (n >= N_NODES) return;
    out[n] = outP[n] + outP[N_NODES + n] + outP[2 * (size_t)N_NODES + n]
           + b2[0] + b2[1] + b2[2];
}

// =============== fallback (round-1) kernels ===============

__global__ void f_zero(float* __restrict__ p, int n) {
    int i = blockIdx.x * blockDim.x + threadIdx.x;
    if (i < n) p[i] = 0.0f;
}
__global__ void f_deg(const int* __restrict__ src, const int* __restrict__ dst, int E,
                      float* __restrict__ dout, float* __restrict__ din) {
    int i = blockIdx.x * blockDim.x + threadIdx.x;
    if (i < E) { atomicAdd(&dout[src[i]], 1.0f); atomicAdd(&din[dst[i]], 1.0f); }
}
__global__ void f_rsqrt(float* __restrict__ p, int n) {
    int i = blockIdx.x * blockDim.x + threadIdx.x;
    if (i < n) p[i] = rsqrtf(fmaxf(p[i], 1.0f));
}
__global__ void f_agg1(const int* __restrict__ src, const int* __restrict__ dst, int E,
                       const float* __restrict__ h, const float* __restrict__ invin,
                       float* __restrict__ agg) {
    int idx = blockIdx.x * blockDim.x + threadIdx.x;
    if (idx < E * FH) {
        int e = idx >> 4, j = idx & 15;
        atomicAdd(&agg[dst[e] * FH + j], h[src[e] * FH + j] * invin[dst[e]]);
    }
}
__global__ void f_relu(float* __restrict__ agg, const float* __restrict__ b1) {
    int i = blockIdx.x * blockDim.x + threadIdx.x;
    if (i < N_NODES * FH) {
        int j = i & 15;
        agg[i] = fmaxf(agg[i] + b1[j] + b1[FH + j] + b1[2 * FH + j], 0.0f);
    }
}
__global__ void f_outinit(float* __restrict__ out, const float* __restrict__ b2) {
    int i = blockIdx.x * blockDim.x + threadIdx.x;
    if (i < N_NODES) out[i] = b2[0] + b2[1] + b2[2];
}
__global__ void f_h2(const float* __restrict__ h1, const float* __restrict__ invout,
                     const float* __restrict__ W2r, float* __restrict__ hsv) {
    int n = blockIdx.x * blockDim.x + threadIdx.x;
    if (n < N_NODES) {
        const float4* hp = (const float4*)(h1 + (size_t)n * FH);
        float s = 0.0f;
#pragma unroll
        for (int q = 0; q < 4; q++) {
            float4 hv = hp[q];
            s += hv.x * W2r[q * 4] + hv.y * W2r[q * 4 + 1] + hv.z * W2r[q * 4 + 2] + hv.w * W2r[q * 4 + 3];
        }
        hsv[n] = s * invout[n];
    }
}
__global__ void f_agg2(const int* __restrict__ src, const int* __restrict__ dst, int E,
                       const float* __restrict__ hsv, const float* __restrict__ invin,
                       float* __restrict__ out) {
    int e = blockIdx.x * blockDim.x + threadIdx.x;
    if (e < E) atomicAdd(&out[dst[e]], hsv[src[e]] * invin[dst[e]]);
}

// =============== host ===============

extern "C" void kernel_launch(void* const* d_in, const int* in_sizes, int n_in,
                              void* d_out, int out_size, void* d_ws, size_t ws_size,
                              hipStream_t stream) {
    const float* x = (const float*)d_in[0];
    const int* srcs[3] = { (const int*)d_in[1], (const int*)d_in[3], (const int*)d_in[5] };
    const int* dsts[3] = { (const int*)d_in[2], (const int*)d_in[4], (const int*)d_in[6] };
    int E[3] = { in_sizes[1], in_sizes[3], in_sizes[5] };
    const float* W1 = (const float*)d_in[7];
    const float* b1 = (const float*)d_in[8];
    const float* W2 = (const float*)d_in[9];
    const float* b2 = (const float*)d_in[10];
    float* out = (float*)d_out;
    const int N = N_NODES;
    const int B = 256;
    size_t Etot = (size_t)E[0] + E[1] + E[2];
    size_t need = ((size_t)OFF_SRCSORT + (Etot + 1) / 2) * 4u;

    if (ws_size >= need) {
        unsigned* ws = (unsigned*)d_ws;
        float* invOut = (float*)(ws + OFF_INVOUT);
        float* invIn  = (float*)(ws + OFF_INVIN);
        unsigned* bukCnt = ws + OFF_BUKCNT;
        unsigned* bstart = ws + OFF_BSTART;
        unsigned* gcur   = ws + OFF_GCUR;
        unsigned* rowptr = ws + OFF_ROWPTR;
        float* hproj = (float*)(ws + OFF_HPROJ);
        float* hout  = (float*)(ws + OFF_HOUT);
        float* aggP  = (float*)(ws + OFF_AGGP);
        unsigned* srcHist = ws + OFF_SRCHIST;
        float* hs    = (float*)(ws + OFF_HS);
        float* outP  = (float*)(ws + OFF_OUTP);
        unsigned* pairs = ws + OFF_PAIRS;
        unsigned short* srcSort = (unsigned short*)(ws + OFF_SRCSORT);
        int po[3] = { 0, E[0], E[0] + E[1] };

        k_zero_u32<<<(3 * BSTRIDE + B - 1) / B, B, 0, stream>>>(bukCnt, 3 * BSTRIDE);
        k_srcDeg<<<dim3(NCH2, NRNG, 3), B, 0, stream>>>(srcs[0], srcs[1], srcs[2],
                                                        E[0], E[1], E[2], srcHist);
        k_degreduceOut<<<dim3((N + B - 1) / B, 3), B, 0, stream>>>(srcHist, invOut);
        k_bukCount<<<dim3(256, 3), B, 0, stream>>>(dsts[0], dsts[1], dsts[2], E[0], E[1], E[2], bukCnt);
        k_bucketScan<<<3, B, 0, stream>>>(bukCnt, bstart, gcur);
        k_passB<<<dim3(256, 1, 3), B, 0, stream>>>(
            srcs[0], srcs[1], srcs[2], dsts[0], dsts[1], dsts[2],
            E[0], E[1], E[2], po[0], po[1], po[2], pairs, gcur);
        k_h1<<<dim3((N + 15) / 16, 3), B, 0, stream>>>(x, invOut, W1, hproj);
        k_passC1<<<dim3(NBUK, 1, 3), B, 0, stream>>>(
            pairs, po[1], po[2], bstart,
            (const float4*)hproj, (float4*)aggP,
            srcSort, rowptr, invIn);
        k_relu<<<(N * FH + B - 1) / B, B, 0, stream>>>(aggP, b1, hout);
        k_h2<<<dim3((N + B - 1) / B, 3), B, 0, stream>>>(hout, invOut, W2, hs);
        k_passC2<<<(3 * N + 15) / 16, B, 0, stream>>>(srcSort, rowptr, hs, invIn, outP);
        k_final<<<(N + B - 1) / B, B, 0, stream>>>(outP, b2, out);
    } else {
        // fallback: round-1 atomic path
        float* wsf = (float*)d_ws;
        float* invOut = wsf;
        float* invIn = wsf + 3 * (size_t)N;
        float* h = wsf + 6 * (size_t)N;
        float* agg = wsf + 22 * (size_t)N;
        float* hsv = wsf + 38 * (size_t)N;
        f_zero<<<(6 * N + B - 1) / B, B, 0, stream>>>(invOut, 6 * N);
        f_zero<<<(16 * N + B - 1) / B, B, 0, stream>>>(agg, 16 * N);
        for (int r = 0; r < 3; r++)
            f_deg<<<(E[r] + B - 1) / B, B, 0, stream>>>(srcs[r], dsts[r], E[r],
                                                        invOut + (size_t)r * N, invIn + (size_t)r * N);
        f_rsqrt<<<(6 * N + B - 1) / B, B, 0, stream>>>(invOut, 6 * N);
        for (int r = 0; r < 3; r++) {
            k_h1<<<dim3((N + 15) / 16, 1), B, 0, stream>>>(x, invOut + (size_t)r * N,
                                                           W1 + (size_t)r * 32 * FH, h);
            f_agg1<<<(E[r] * FH + B - 1) / B, B, 0, stream>>>(srcs[r], dsts[r], E[r], h,
                                                              invIn + (size_t)r * N, agg);
        }
        f_relu<<<(N * FH + B - 1) / B, B, 0, stream>>>(agg, b1);
        f_outinit<<<(N + B - 1) / B, B, 0, stream>>>(out, b2);
        for (int r = 0; r < 3; r++) {
            f_h2<<<(N + B - 1) / B, B, 0, stream>>>(agg, invOut + (size_t)r * N,
                                                    W2 + (size_t)r * FH, hsv);
            f_agg2<<<(E[r] + B - 1) / B, B, 0, stream>>>(srcs[r], dsts[r], E[r], hsv,
                                                         invIn + (size_t)r * N, out);
        }
    }
}

// Round 11
// 242.565 us; speedup vs baseline: 4.2068x; 1.0048x over previous
//
#include <hip/hip_runtime.h>

#define N_NODES 50000
#define FH 16
#define NBUK 782          // 64-node buckets: bucket = dst >> 6
#define BSHIFT 6
#define BSTRIDE 800
#define TILE 4096
#define NCH2 64           // src-deg chunks
#define NRNG 8            // src-deg node ranges
#define RNGSZ 6250        // nodes per range (even)
#define C1CAP 4608        // passC1 max bucket size (u16 LDS)

// ---- ws layout (u32 words) ----
#define OFF_INVOUT   0u           // [3][N] f32
#define OFF_INVIN    150000u      // [3][N] f32
#define OFF_BUKCNT   300000u      // [3][800]
#define OFF_BSTART   302400u      // [3][800]
#define OFF_GCUR     304800u      // [3][800]
#define OFF_ROWPTR   307200u      // [3][N+1] u32 (absolute into srcSorted)
#define OFF_HPROJ    457216u      // [3][N][16] f32
#define OFF_AGGP     3657216u     // [3][N][16] f32 (scaled by invIn already)
#define OFF_SRCHIST  3657216u     // [3][64][25000] u32 = 4.8M words, ends 8457216
                                  // (alias over aggP/HS/pairs-head: srcHist dead after k_misc,
                                  //  which completes BEFORE passB/passC1/relu_h2 writes)
#define OFF_HS       6057216u     // [3][N] f32
#define OFF_PAIRS    6357216u     // Etot u32 packed (dst<<16 | src)
#define OFF_SRCSORT  10557216u    // Etot u16
// need = (OFF_SRCSORT + ceil(Etot/2)) * 4  ~= 50.6 MB

// src degree histogram: (chunk, range, rel), packed u16 bins, 8 edges/thread (2x int4).
// Block (0,0,0) also zeroes bukCnt (consumed by k_misc, which launches after).
__global__ __launch_bounds__(256) void k_srcDeg(const int* s0, const int* s1, const int* s2,
                                                int E0, int E1, int E2,
                                                unsigned* __restrict__ histP,
                                                unsigned* __restrict__ bukCnt) {
    __shared__ unsigned bins[RNGSZ / 2];
    int c = blockIdx.x, rg = blockIdx.y, r = blockIdx.z;
    if (c == 0 && rg == 0 && r == 0) {
        for (int i = threadIdx.x; i < 3 * BSTRIDE; i += 256) bukCnt[i] = 0u;
    }
    const int* arr = (r == 0) ? s0 : (r == 1) ? s1 : s2;
    int E = (r == 0) ? E0 : (r == 1) ? E1 : E2;
    for (int i = threadIdx.x; i < RNGSZ / 2; i += 256) bins[i] = 0u;
    __syncthreads();
    int lo = rg * RNGSZ;
    int per = (((E + NCH2 - 1) / NCH2) + 7) & ~7;
    int a0 = c * per, a1 = min(a0 + per, E);
    for (int i = a0 + (int)threadIdx.x * 8; i < a1; i += 2048) {
        if (i + 8 <= a1) {
            int4 v1 = *reinterpret_cast<const int4*>(arr + i);
            int4 v2 = *reinterpret_cast<const int4*>(arr + i + 4);
            unsigned d0 = (unsigned)(v1.x - lo), d1 = (unsigned)(v1.y - lo);
            unsigned d2 = (unsigned)(v1.z - lo), d3 = (unsigned)(v1.w - lo);
            unsigned d4 = (unsigned)(v2.x - lo), d5 = (unsigned)(v2.y - lo);
            unsigned d6 = (unsigned)(v2.z - lo), d7 = (unsigned)(v2.w - lo);
            if (d0 < (unsigned)RNGSZ) atomicAdd(&bins[d0 >> 1], (d0 & 1u) ? 65536u : 1u);
            if (d1 < (unsigned)RNGSZ) atomicAdd(&bins[d1 >> 1], (d1 & 1u) ? 65536u : 1u);
            if (d2 < (unsigned)RNGSZ) atomicAdd(&bins[d2 >> 1], (d2 & 1u) ? 65536u : 1u);
            if (d3 < (unsigned)RNGSZ) atomicAdd(&bins[d3 >> 1], (d3 & 1u) ? 65536u : 1u);
            if (d4 < (unsigned)RNGSZ) atomicAdd(&bins[d4 >> 1], (d4 & 1u) ? 65536u : 1u);
            if (d5 < (unsigned)RNGSZ) atomicAdd(&bins[d5 >> 1], (d5 & 1u) ? 65536u : 1u);
            if (d6 < (unsigned)RNGSZ) atomicAdd(&bins[d6 >> 1], (d6 & 1u) ? 65536u : 1u);
            if (d7 < (unsigned)RNGSZ) atomicAdd(&bins[d7 >> 1], (d7 & 1u) ? 65536u : 1u);
        } else {
            for (int k2 = i; k2 < a1; k2++) {
                unsigned d = (unsigned)(arr[k2] - lo);
                if (d < (unsigned)RNGSZ) atomicAdd(&bins[d >> 1], (d & 1u) ? 65536u : 1u);
            }
        }
    }
    __syncthreads();
    unsigned* out = histP + ((size_t)r * NCH2 + c) * 25000 + rg * (RNGSZ / 2);
    for (int i = threadIdx.x; i < RNGSZ / 2; i += 256) out[i] = bins[i];
}

// fused: blocks x<196 reduce src-histogram -> invOut; blocks x>=196 count dst buckets.
__global__ __launch_bounds__(256) void k_misc(const unsigned* __restrict__ histP,
                                              float* __restrict__ invOut,
                                              const int* d0p, const int* d1p, const int* d2p,
                                              int E0, int E1, int E2,
                                              unsigned* __restrict__ bukCnt) {
    __shared__ unsigned bins[NBUK];
    int r = blockIdx.y;
    if (blockIdx.x < 196) {
        int n = blockIdx.x * 256 + threadIdx.x;
        if (n >= N_NODES) return;
        const unsigned* p = histP + (size_t)r * NCH2 * 25000 + (n >> 1);
        unsigned s = 0;
#pragma unroll
        for (int c = 0; c < NCH2; c++) {
            unsigned w = p[(size_t)c * 25000];
            s += (n & 1) ? (w >> 16) : (w & 0xFFFFu);
        }
        invOut[r * N_NODES + n] = rsqrtf((float)(s ? s : 1u));
        return;
    }
    int c = blockIdx.x - 196;
    const int* arr = (r == 0) ? d0p : (r == 1) ? d1p : d2p;
    int E = (r == 0) ? E0 : (r == 1) ? E1 : E2;
    for (int i = threadIdx.x; i < NBUK; i += 256) bins[i] = 0u;
    __syncthreads();
    int per = (((E + 255) / 256) + 3) & ~3;
    int a0 = c * per, a1 = min(a0 + per, E);
    for (int i = a0 + (int)threadIdx.x * 4; i < a1; i += 1024) {
        if (i + 4 <= a1) {
            int4 v = *reinterpret_cast<const int4*>(arr + i);
            atomicAdd(&bins[((unsigned)v.x) >> BSHIFT], 1u);
            atomicAdd(&bins[((unsigned)v.y) >> BSHIFT], 1u);
            atomicAdd(&bins[((unsigned)v.z) >> BSHIFT], 1u);
            atomicAdd(&bins[((unsigned)v.w) >> BSHIFT], 1u);
        } else {
            for (int k2 = i; k2 < a1; k2++)
                atomicAdd(&bins[((unsigned)arr[k2]) >> BSHIFT], 1u);
        }
    }
    __syncthreads();
    for (int b = threadIdx.x; b < NBUK; b += 256)
        if (bins[b]) atomicAdd(&bukCnt[r * BSTRIDE + b], bins[b]);
}

// parallel exclusive scan of bucket counts (256 threads x 4 bins, Hillis-Steele)
__global__ __launch_bounds__(256) void k_bucketScan(const unsigned* __restrict__ bukCnt,
                                                    unsigned* __restrict__ bstart,
                                                    unsigned* __restrict__ gcur) {
    __shared__ unsigned part[256];
    int r = blockIdx.x, t = threadIdx.x;
    unsigned loc[4]; unsigned s = 0;
#pragma unroll
    for (int k = 0; k < 4; k++) {
        int idx = 4 * t + k;
        loc[k] = (idx < NBUK) ? bukCnt[r * BSTRIDE + idx] : 0u;
        s += loc[k];
    }
    part[t] = s;
    __syncthreads();
    for (int d = 1; d < 256; d <<= 1) {
        unsigned v = (t >= d) ? part[t - d] : 0u;
        __syncthreads();
        part[t] += v;
        __syncthreads();
    }
    unsigned run = part[t] - s;  // exclusive prefix
#pragma unroll
    for (int k = 0; k < 4; k++) {
        int idx = 4 * t + k;
        if (idx <= NBUK) { bstart[r * BSTRIDE + idx] = run; gcur[r * BSTRIDE + idx] = run; }
        run += loc[k];
    }
}

// bucket-scatter with in-LDS tile reorder. pair = (dst<<16)|src.
__global__ __launch_bounds__(256) void k_passB(
    const int* s0p, const int* s1p, const int* s2p,
    const int* d0p, const int* d1p, const int* d2p,
    int E0, int E1, int E2, int po0, int po1, int po2,
    unsigned* __restrict__ pairsAll, unsigned* __restrict__ gcurAll) {
    __shared__ unsigned cnt[NBUK];
    __shared__ unsigned off[NBUK];
    __shared__ unsigned gbase[NBUK];
    __shared__ unsigned part[256];
    __shared__ unsigned spair[TILE];
    __shared__ unsigned saddr[TILE];
    int r = blockIdx.z;
    const int* src = (r == 0) ? s0p : (r == 1) ? s1p : s2p;
    const int* dst = (r == 0) ? d0p : (r == 1) ? d1p : d2p;
    int E = (r == 0) ? E0 : (r == 1) ? E1 : E2;
    unsigned* pairs = pairsAll + ((r == 0) ? po0 : (r == 1) ? po1 : po2);
    unsigned* gcur = gcurAll + r * BSTRIDE;
    int nb = gridDim.x;
    int chunk = (((E + nb - 1) / nb) + 15) & ~15;   // 16-aligned for int4 fast path
    int c0 = blockIdx.x * chunk;
    int c1 = min(c0 + chunk, E);
    for (int t0 = c0; t0 < c1; t0 += TILE) {
        int tn = min(TILE, c1 - t0);
        for (int i = threadIdx.x; i < NBUK; i += 256) cnt[i] = 0u;
        __syncthreads();
        unsigned pk[16], bk[16], sl[16];
        if (tn == TILE) {
            int base = t0 + (int)threadIdx.x * 16;
#pragma unroll
            for (int q = 0; q < 4; q++) {
                int4 vs = *reinterpret_cast<const int4*>(src + base + q * 4);
                int4 vd = *reinterpret_cast<const int4*>(dst + base + q * 4);
                pk[q * 4 + 0] = ((unsigned)vd.x << 16) | (unsigned)vs.x;
                pk[q * 4 + 1] = ((unsigned)vd.y << 16) | (unsigned)vs.y;
                pk[q * 4 + 2] = ((unsigned)vd.z << 16) | (unsigned)vs.z;
                pk[q * 4 + 3] = ((unsigned)vd.w << 16) | (unsigned)vs.w;
                bk[q * 4 + 0] = (unsigned)vd.x >> BSHIFT;
                bk[q * 4 + 1] = (unsigned)vd.y >> BSHIFT;
                bk[q * 4 + 2] = (unsigned)vd.z >> BSHIFT;
                bk[q * 4 + 3] = (unsigned)vd.w >> BSHIFT;
            }
#pragma unroll
            for (int k = 0; k < 16; k++) sl[k] = atomicAdd(&cnt[bk[k]], 1u);
        } else {
#pragma unroll
            for (int k = 0; k < 16; k++) {
                int ii = k * 256 + (int)threadIdx.x;
                bk[k] = 0xFFFFFFFFu;
                if (ii < tn) {
                    int i = t0 + ii;
                    unsigned s = (unsigned)src[i], d = (unsigned)dst[i];
                    pk[k] = (d << 16) | s;
                    unsigned b = d >> BSHIFT;
                    bk[k] = b;
                    sl[k] = atomicAdd(&cnt[b], 1u);
                }
            }
        }
        __syncthreads();
        {
            int t = threadIdx.x;
            unsigned loc[4]; unsigned sloc = 0;
#pragma unroll
            for (int k2 = 0; k2 < 4; k2++) {
                int idx = 4 * t + k2;
                loc[k2] = (idx < NBUK) ? cnt[idx] : 0u;
                sloc += loc[k2];
            }
            part[t] = sloc;
            __syncthreads();
            for (int d = 1; d < 256; d <<= 1) {
                unsigned v = (t >= d) ? part[t - d] : 0u;
                __syncthreads();
                part[t] += v;
                __syncthreads();
            }
            unsigned run = part[t] - sloc;
#pragma unroll
            for (int k2 = 0; k2 < 4; k2++) {
                int idx = 4 * t + k2;
                if (idx < NBUK) off[idx] = run;
                run += loc[k2];
            }
        }
        __syncthreads();
        for (int b = threadIdx.x; b < NBUK; b += 256) {
            unsigned c = cnt[b];
            if (c) gbase[b] = atomicAdd(&gcur[b], c);
        }
        __syncthreads();
        if (tn == TILE) {
#pragma unroll
            for (int k = 0; k < 16; k++) {
                unsigned idx = off[bk[k]] + sl[k];
                spair[idx] = pk[k];
                saddr[idx] = gbase[bk[k]] + sl[k];
            }
        } else {
#pragma unroll
            for (int k = 0; k < 16; k++) {
                if (bk[k] != 0xFFFFFFFFu) {
                    unsigned idx = off[bk[k]] + sl[k];
                    spair[idx] = pk[k];
                    saddr[idx] = gbase[bk[k]] + sl[k];
                }
            }
        }
        __syncthreads();
#pragma unroll
        for (int k = 0; k < 16; k++) {
            int ii = k * 256 + (int)threadIdx.x;
            if (ii < tn) pairs[saddr[ii]] = spair[ii];
        }
        __syncthreads();
    }
}

// h_r[n][j] = (x[n,:] . W1[r][:,j]) * invOut_r[n]
__global__ __launch_bounds__(256) void k_h1(const float* __restrict__ x, const float* __restrict__ invOut,
                                            const float* __restrict__ W1, float* __restrict__ hproj) {
    __shared__ float sW[32 * FH];
    __shared__ float sx[16][32];
    int r = blockIdx.y;
    const float* W = W1 + r * 32 * FH;
    int t = threadIdx.x;
    for (int i = t; i < 32 * FH; i += 256) sW[i] = W[i];
    int n0 = blockIdx.x * 16;
    for (int i = t; i < 16 * 32; i += 256) {
        int nn = i >> 5, kk = i & 31;
        int n = n0 + nn;
        sx[nn][kk] = (n < N_NODES) ? x[n * 32 + kk] : 0.0f;
    }
    __syncthreads();
    int nn = t >> 4, j = t & 15;
    int n = n0 + nn;
    if (n < N_NODES) {
        float s = 0.f;
#pragma unroll
        for (int k = 0; k < 32; k++) s += sx[nn][k] * sW[k * FH + j];
        hproj[((size_t)r * N_NODES + n) * FH + j] = s * invOut[r * N_NODES + n];
    }
}

// layer-1 per-bucket (all 3 relations in one launch, z = relation):
// LDS counting sort by dst -> segmented float4 register accumulation.
__global__ __launch_bounds__(256) void k_passC1(
    const unsigned* __restrict__ pairsAll, int po1, int po2,
    const unsigned* __restrict__ bstartAll,
    const float4* __restrict__ h4All, float4* __restrict__ out4All,
    unsigned short* __restrict__ srcGAll, unsigned* __restrict__ rowptrAll,
    float* __restrict__ invInAll) {
    __shared__ unsigned cnt[64];
    __shared__ unsigned off[65];
    __shared__ unsigned cur[64];
    __shared__ unsigned short srcS[C1CAP];
    int b = blockIdx.x, t = threadIdx.x, r = blockIdx.z;
    int po = (r == 0) ? 0 : (r == 1) ? po1 : po2;
    const unsigned* pairs = pairsAll + po;
    const unsigned* bstart = bstartAll + r * BSTRIDE;
    const float4* h4 = h4All + (size_t)r * N_NODES * 4;
    float4* out4 = out4All + (size_t)r * N_NODES * 4;
    unsigned short* srcG = srcGAll + po;
    unsigned* rowptr = rowptrAll + (size_t)r * (N_NODES + 1);
    float* invIn = invInAll + (size_t)r * N_NODES;
    unsigned e0 = bstart[b], e1 = bstart[b + 1];
    if (e1 - e0 > (unsigned)C1CAP) e1 = e0 + (unsigned)C1CAP;   // statistically impossible
    int d0 = b << BSHIFT;
    if (t < 64) cnt[t] = 0u;
    __syncthreads();
    for (unsigned i = e0 + t; i < e1; i += 256)
        atomicAdd(&cnt[(pairs[i] >> 16) - (unsigned)d0], 1u);
    __syncthreads();
    if (t < 64) {
        unsigned cv = cnt[t];
        unsigned sc = cv;
#pragma unroll
        for (int d = 1; d < 64; d <<= 1) {
            unsigned v = __shfl_up(sc, d, 64);
            if (t >= d) sc += v;
        }
        off[t] = sc - cv;
        if (t == 63) off[64] = sc;
    }
    __syncthreads();
    if (t < 64) {
        cur[t] = off[t];
        int n = d0 + t;
        if (n < N_NODES) {
            rowptr[n] = (unsigned)po + e0 + off[t];
            unsigned dg = cnt[t];
            invIn[n] = rsqrtf((float)(dg ? dg : 1u));
        }
    }
    if (b == NBUK - 1 && t == 0) rowptr[N_NODES] = (unsigned)po + e1;
    __syncthreads();
    for (unsigned i = e0 + t; i < e1; i += 256) {
        unsigned p = pairs[i];
        unsigned d = (p >> 16) - (unsigned)d0;
        unsigned pos = atomicAdd(&cur[d], 1u);
        srcS[pos] = (unsigned short)(p & 0xFFFFu);
    }
    __syncthreads();
    {
        unsigned len = e1 - e0;
        for (unsigned i = t; i < len; i += 256) srcG[e0 + i] = srcS[i];
    }
    int unit = t >> 4, p = t & 15, k = p >> 2, fq = p & 3;
    for (int nd = unit; nd < 64; nd += 16) {
        unsigned o0 = off[nd], o1 = off[nd + 1];
        float ax = 0.f, ay = 0.f, az = 0.f, aw = 0.f;
        unsigned base = o0;
        for (; base + 8 <= o1; base += 8) {
            int s0 = srcS[base + k], s1 = srcS[base + 4 + k];
            float4 v0 = h4[(size_t)s0 * 4 + fq];
            float4 v1 = h4[(size_t)s1 * 4 + fq];
            ax += v0.x + v1.x; ay += v0.y + v1.y; az += v0.z + v1.z; aw += v0.w + v1.w;
        }
        for (; base < o1; base += 4) {
            unsigned idx = base + (unsigned)k;
            if (idx < o1) {
                int s = srcS[idx];
                float4 v = h4[(size_t)s * 4 + fq];
                ax += v.x; ay += v.y; az += v.z; aw += v.w;
            }
        }
        ax += __shfl_xor(ax, 4, 16); ay += __shfl_xor(ay, 4, 16);
        az += __shfl_xor(az, 4, 16); aw += __shfl_xor(aw, 4, 16);
        ax += __shfl_xor(ax, 8, 16); ay += __shfl_xor(ay, 8, 16);
        az += __shfl_xor(az, 8, 16); aw += __shfl_xor(aw, 8, 16);
        int n = d0 + nd;
        if (k == 0 && n < N_NODES) {
            unsigned dg = o1 - o0;
            float sc = rsqrtf((float)(dg ? dg : 1u));
            float4 res; res.x = ax * sc; res.y = ay * sc; res.z = az * sc; res.w = aw * sc;
            out4[(size_t)n * 4 + fq] = res;
        }
    }
}

// fused: hout = relu(sum_r aggP_r + sum_r b1_r) computed in registers,
// then hs[r][n] = dot(hout, W2[r]) * invOut[r][n]. No hout buffer.
__global__ __launch_bounds__(256) void k_relu_h2(const float4* __restrict__ aggP4,
                                                 const float* __restrict__ invOut,
                                                 const float* __restrict__ b1,
                                                 const float* __restrict__ W2,
                                                 float* __restrict__ hs) {
    __shared__ float sW[3 * FH];
    __shared__ float sb[FH];
    int t = threadIdx.x;
    if (t < 48) sW[t] = W2[t];
    if (t < 16) sb[t] = b1[t] + b1[FH + t] + b1[2 * FH + t];
    __syncthreads();
    int n = blockIdx.x * 256 + t;
    if (n >= N_NODES) return;
    const size_t SL4 = (size_t)N_NODES * 4;
    float h[FH];
#pragma unroll
    for (int q = 0; q < 4; q++) {
        float4 a0 = aggP4[(size_t)n * 4 + q];
        float4 a1 = aggP4[SL4 + (size_t)n * 4 + q];
        float4 a2 = aggP4[2 * SL4 + (size_t)n * 4 + q];
        h[q * 4 + 0] = fmaxf(a0.x + a1.x + a2.x + sb[q * 4 + 0], 0.f);
        h[q * 4 + 1] = fmaxf(a0.y + a1.y + a2.y + sb[q * 4 + 1], 0.f);
        h[q * 4 + 2] = fmaxf(a0.z + a1.z + a2.z + sb[q * 4 + 2], 0.f);
        h[q * 4 + 3] = fmaxf(a0.w + a1.w + a2.w + sb[q * 4 + 3], 0.f);
    }
#pragma unroll
    for (int r = 0; r < 3; r++) {
        float s = 0.f;
#pragma unroll
        for (int j = 0; j < FH; j++) s += h[j] * sW[r * FH + j];
        hs[r * N_NODES + n] = s * invOut[r * N_NODES + n];
    }
}

// fused layer-2 + final: 16-lane unit per node, loops relations, writes out directly.
__global__ __launch_bounds__(256) void k_passC2f(
    const unsigned short* __restrict__ srcG, const unsigned* __restrict__ rowptr,
    const float* __restrict__ hsAll, const float* __restrict__ invIn,
    const float* __restrict__ b2, float* __restrict__ out) {
    int t = threadIdx.x;
    int unit = t >> 4, p = t & 15;
    int n = blockIdx.x * 16 + unit;
    if (n >= N_NODES) return;
    float tot = 0.f;
#pragma unroll
    for (int r = 0; r < 3; r++) {
        unsigned o0 = rowptr[r * (N_NODES + 1) + n];
        unsigned o1 = rowptr[r * (N_NODES + 1) + n + 1];
        const float* hs = hsAll + (size_t)r * N_NODES;
        float s = 0.f;
        for (unsigned i = o0 + (unsigned)p; i < o1; i += 16) s += hs[srcG[i]];
        tot += s * invIn[r * N_NODES + n];
    }
    tot += __shfl_xor(tot, 1, 16); tot += __shfl_xor(tot, 2, 16);
    tot += __shfl_xor(tot, 4, 16); tot += __shfl_xor(tot, 8, 16);
    if (p == 0) out[n] = tot + b2[0] + b2[1] + b2[2];
}

// =============== fallback (round-1) kernels ===============

__global__ void f_zero(float* __restrict__ p, int n) {
    int i = blockIdx.x * blockDim.x + threadIdx.x;
    if (i < n) p[i] = 0.0f;
}
__global__ void f_deg(const int* __restrict__ src, const int* __restrict__ dst, int E,
                      float* __restrict__ dout, float* __restrict__ din) {
    int i = blockIdx.x * blockDim.x + threadIdx.x;
    if (i < E) { atomicAdd(&dout[src[i]], 1.0f); atomicAdd(&din[dst[i]], 1.0f); }
}
__global__ void f_rsqrt(float* __restrict__ p, int n) {
    int i = blockIdx.x * blockDim.x + threadIdx.x;
    if (i < n) p[i] = rsqrtf(fmaxf(p[i], 1.0f));
}
__global__ void f_agg1(const int* __restrict__ src, const int* __restrict__ dst, int E,
                       const float* __restrict__ h, const float* __restrict__ invin,
                       float* __restrict__ agg) {
    int idx = blockIdx.x * blockDim.x + threadIdx.x;
    if (idx < E * FH) {
        int e = idx >> 4, j = idx & 15;
        atomicAdd(&agg[dst[e] * FH + j], h[src[e] * FH + j] * invin[dst[e]]);
    }
}
__global__ void f_relu(float* __restrict__ agg, const float* __restrict__ b1) {
    int i = blockIdx.x * blockDim.x + threadIdx.x;
    if (i < N_NODES * FH) {
        int j = i & 15;
        agg[i] = fmaxf(agg[i] + b1[j] + b1[FH + j] + b1[2 * FH + j], 0.0f);
    }
}
__global__ void f_outinit(float* __restrict__ out, const float* __restrict__ b2) {
    int i = blockIdx.x * blockDim.x + threadIdx.x;
    if (i < N_NODES) out[i] = b2[0] + b2[1] + b2[2];
}
__global__ void f_h2(const float* __restrict__ h1, const float* __restrict__ invout,
                     const float* __restrict__ W2r, float* __restrict__ hsv) {
    int n = blockIdx.x * blockDim.x + threadIdx.x;
    if (n < N_NODES) {
        const float4* hp = (const float4*)(h1 + (size_t)n * FH);
        float s = 0.0f;
#pragma unroll
        for (int q = 0; q < 4; q++) {
            float4 hv = hp[q];
            s += hv.x * W2r[q * 4] + hv.y * W2r[q * 4 + 1] + hv.z * W2r[q * 4 + 2] + hv.w * W2r[q * 4 + 3];
        }
        hsv[n] = s * invout[n];
    }
}
__global__ void f_agg2(const int* __restrict__ src, const int* __restrict__ dst, int E,
                       const float* __restrict__ hsv, const float* __restrict__ invin,
                       float* __restrict__ out) {
    int e = blockIdx.x * blockDim.x + threadIdx.x;
    if (e < E) atomicAdd(&out[dst[e]], hsv[src[e]] * invin[dst[e]]);
}

// =============== host ===============

extern "C" void kernel_launch(void* const* d_in, const int* in_sizes, int n_in,
                              void* d_out, int out_size, void* d_ws, size_t ws_size,
                              hipStream_t stream) {
    const float* x = (const float*)d_in[0];
    const int* srcs[3] = { (const int*)d_in[1], (const int*)d_in[3], (const int*)d_in[5] };
    const int* dsts[3] = { (const int*)d_in[2], (const int*)d_in[4], (const int*)d_in[6] };
    int E[3] = { in_sizes[1], in_sizes[3], in_sizes[5] };
    const float* W1 = (const float*)d_in[7];
    const float* b1 = (const float*)d_in[8];
    const float* W2 = (const float*)d_in[9];
    const float* b2 = (const float*)d_in[10];
    float* out = (float*)d_out;
    const int N = N_NODES;
    const int B = 256;
    size_t Etot = (size_t)E[0] + E[1] + E[2];
    size_t need = ((size_t)OFF_SRCSORT + (Etot + 1) / 2) * 4u;

    if (ws_size >= need) {
        unsigned* ws = (unsigned*)d_ws;
        float* invOut = (float*)(ws + OFF_INVOUT);
        float* invIn  = (float*)(ws + OFF_INVIN);
        unsigned* bukCnt = ws + OFF_BUKCNT;
        unsigned* bstart = ws + OFF_BSTART;
        unsigned* gcur   = ws + OFF_GCUR;
        unsigned* rowptr = ws + OFF_ROWPTR;
        float* hproj = (float*)(ws + OFF_HPROJ);
        float* aggP  = (float*)(ws + OFF_AGGP);
        unsigned* srcHist = ws + OFF_SRCHIST;
        float* hs    = (float*)(ws + OFF_HS);
        unsigned* pairs = ws + OFF_PAIRS;
        unsigned short* srcSort = (unsigned short*)(ws + OFF_SRCSORT);
        int po[3] = { 0, E[0], E[0] + E[1] };

        k_srcDeg<<<dim3(NCH2, NRNG, 3), B, 0, stream>>>(srcs[0], srcs[1], srcs[2],
                                                        E[0], E[1], E[2], srcHist, bukCnt);
        k_misc<<<dim3(196 + 256, 3), B, 0, stream>>>(srcHist, invOut,
                                                     dsts[0], dsts[1], dsts[2],
                                                     E[0], E[1], E[2], bukCnt);
        k_bucketScan<<<3, B, 0, stream>>>(bukCnt, bstart, gcur);
        k_passB<<<dim3(256, 1, 3), B, 0, stream>>>(
            srcs[0], srcs[1], srcs[2], dsts[0], dsts[1], dsts[2],
            E[0], E[1], E[2], po[0], po[1], po[2], pairs, gcur);
        k_h1<<<dim3((N + 15) / 16, 3), B, 0, stream>>>(x, invOut, W1, hproj);
        k_passC1<<<dim3(NBUK, 1, 3), B, 0, stream>>>(
            pairs, po[1], po[2], bstart,
            (const float4*)hproj, (float4*)aggP,
            srcSort, rowptr, invIn);
        k_relu_h2<<<(N + B - 1) / B, B, 0, stream>>>((const float4*)aggP, invOut, b1, W2, hs);
        k_passC2f<<<(N + 15) / 16, B, 0, stream>>>(srcSort, rowptr, hs, invIn, b2, out);
    } else {
        // fallback: round-1 atomic path
        float* wsf = (float*)d_ws;
        float* invOut = wsf;
        float* invIn = wsf + 3 * (size_t)N;
        float* h = wsf + 6 * (size_t)N;
        float* agg = wsf + 22 * (size_t)N;
        float* hsv = wsf + 38 * (size_t)N;
        f_zero<<<(6 * N + B - 1) / B, B, 0, stream>>>(invOut, 6 * N);
        f_zero<<<(16 * N + B - 1) / B, B, 0, stream>>>(agg, 16 * N);
        for (int r = 0; r < 3; r++)
            f_deg<<<(E[r] + B - 1) / B, B, 0, stream>>>(srcs[r], dsts[r], E[r],
                                                        invOut + (size_t)r * N, invIn + (size_t)r * N);
        f_rsqrt<<<(6 * N + B - 1) / B, B, 0, stream>>>(invOut, 6 * N);
        for (int r = 0; r < 3; r++) {
            k_h1<<<dim3((N + 15) / 16, 1), B, 0, stream>>>(x, invOut + (size_t)r * N,
                                                           W1 + (size_t)r * 32 * FH, h);
            f_agg1<<<(E[r] * FH + B - 1) / B, B, 0, stream>>>(srcs[r], dsts[r], E[r], h,
                                                              invIn + (size_t)r * N, agg);
        }
        f_relu<<<(N * FH + B - 1) / B, B, 0, stream>>>(agg, b1);
        f_outinit<<<(N + B - 1) / B, B, 0, stream>>>(out, b2);
        for (int r = 0; r < 3; r++) {
            f_h2<<<(N + B - 1) / B, B, 0, stream>>>(agg, invOut + (size_t)r * N,
                                                    W2 + (size_t)r * FH, hsv);
            f_agg2<<<(E[r] + B - 1) / B, B, 0, stream>>>(srcs[r], dsts[r], E[r], hsv,
                                                         invIn + (size_t)r * N, out);
        }
    }
}